// Round 1
// baseline (922.162 us; speedup 1.0000x reference)
//
#include <hip/hip_runtime.h>
#include <cstddef>

#define LN_EPS 1e-5f

typedef __bf16 bf16x8 __attribute__((ext_vector_type(8)));
typedef float  f32x4  __attribute__((ext_vector_type(4)));

typedef __attribute__((address_space(3))) unsigned int lds_u32;
typedef __attribute__((address_space(1))) unsigned int glb_u32;

__device__ __forceinline__ void gl2lds16(const void* g, void* l) {
    // 16B per lane DMA: LDS dest = wave-uniform base + lane*16
    __builtin_amdgcn_global_load_lds((const glb_u32*)g, (lds_u32*)l, 16, 0, 0);
}

__device__ __forceinline__ float b2f(ushort h) {
    return __uint_as_float(((unsigned)h) << 16);
}
__device__ __forceinline__ ushort f2b(float f) {   // RNE
    unsigned u = __float_as_uint(f);
    return (ushort)((u + 0x7fffu + ((u >> 16) & 1u)) >> 16);
}
__device__ __forceinline__ unsigned pack2(float lo, float hi) {
    return (unsigned)f2b(lo) | ((unsigned)f2b(hi) << 16);
}
__device__ __forceinline__ uint2 pack4(const f32x4 v) {
    return make_uint2(pack2(v[0], v[1]), pack2(v[2], v[3]));
}

// XCD-aware remap: all gridDim.x col-blocks of one row-block land on one XCD.
__device__ __forceinline__ void xcd_map(int& bx, int& by) {
    int NX = gridDim.x, MBr = gridDim.y;
    int L = blockIdx.y * NX + blockIdx.x;
    int G = NX * 8;
    int g = L / G;
    if (g * 8 + 8 <= MBr) {
        int r = L - g * G;
        by = g * 8 + (r & 7);
        bx = r >> 3;
    } else {
        by = L / NX;
        bx = L - by * NX;
    }
}

__device__ __forceinline__ float wave_reduce_sum(float v) {
    #pragma unroll
    for (int off = 32; off > 0; off >>= 1) v += __shfl_down(v, off, 64);
    return v;
}
__device__ __forceinline__ float wave_allreduce_max(float v) {
    #pragma unroll
    for (int off = 32; off > 0; off >>= 1) v = fmaxf(v, __shfl_xor(v, off, 64));
    return v;
}
__device__ __forceinline__ float wave_allreduce_sum(float v) {
    #pragma unroll
    for (int off = 32; off > 0; off >>= 1) v += __shfl_xor(v, off, 64);
    return v;
}

// ---- BK=32 TRIPLE-buffered MFMA K-loop with counted vmcnt (T4) -----------------
// Pipeline invariants (per wave, 4 global_load_lds per stage):
//   prologue issues S0,S1. Iteration t: outstanding <= {S(t), S(t+1)};
//   s_waitcnt vmcnt(4) completes everything except the newest 4 (= S(t+1)),
//   so S(t) (the buffer read this iter) is done. s_barrier makes that true
//   across all waves. S(t+2) is staged into buf[(t+2)%3] == buf[(t-1)%3];
//   safe because every wave's iter t-1 ds_reads completed before it arrived
//   at barrier(t) (compiler lgkmcnt before the consuming MFMAs).
// SWAPPED operands: acc[i][j] = mfma(bf[j], af[i], acc) so that
//   C row = m0+wr+i*16+l15 ; C col = n0+wc+j*16+quad*4+reg
__device__ __forceinline__ void stage32(const ushort* a0, const ushort* a1,
                                        const ushort* b0, const ushort* b1,
                                        ushort* __restrict__ As, ushort* __restrict__ Bs,
                                        int lb0, int lb1) {
    gl2lds16(a0, As + lb0);
    gl2lds16(a1, As + lb1);
    gl2lds16(b0, Bs + lb0);
    gl2lds16(b1, Bs + lb1);
}

__device__ __forceinline__ void mfma_loop32(const ushort* aA0, const ushort* aA1,
                                            const ushort* aB0, const ushort* aB1,
                                            ushort* __restrict__ As, ushort* __restrict__ Bs,
                                            int lb0, int lb1,
                                            int K, int wr, int wc, int cA, int l15,
                                            f32x4 acc[4][4]) {
    const int BUF = 128 * 32;          // ushorts per buffer
    const int nk = K >> 5;
    stage32(aA0, aA1, aB0, aB1, As, Bs, lb0, lb1);                               // S0
    if (nk > 1) stage32(aA0 + 32, aA1 + 32, aB0 + 32, aB1 + 32,
                        As + BUF, Bs + BUF, lb0, lb1);                            // S1
    int cur = 0;
    for (int t = 0; t < nk; t++) {
        if (t + 1 < nk) asm volatile("s_waitcnt vmcnt(4)" ::: "memory");
        else            asm volatile("s_waitcnt vmcnt(0)" ::: "memory");
        __builtin_amdgcn_s_barrier();
        __builtin_amdgcn_sched_barrier(0);   // no ds_read may hoist above barrier
        int kn = (t + 2) * 32;
        if (kn < K) {
            int nb = cur + 2; if (nb >= 3) nb -= 3;
            stage32(aA0 + kn, aA1 + kn, aB0 + kn, aB1 + kn,
                    As + nb * BUF, Bs + nb * BUF, lb0, lb1);
        }
        const ushort* Ac = As + cur * BUF;
        const ushort* Bc = Bs + cur * BUF;
        bf16x8 af[4], bf[4];
        #pragma unroll
        for (int i = 0; i < 4; i++)
            af[i] = *reinterpret_cast<const bf16x8*>(&Ac[(wr + i * 16 + l15) * 32 + cA]);
        #pragma unroll
        for (int j = 0; j < 4; j++)
            bf[j] = *reinterpret_cast<const bf16x8*>(&Bc[(wc + j * 16 + l15) * 32 + cA]);
        #pragma unroll
        for (int i = 0; i < 4; i++)
            #pragma unroll
            for (int j = 0; j < 4; j++)
                acc[i][j] = __builtin_amdgcn_mfma_f32_16x16x32_bf16(bf[j], af[i], acc[i][j], 0, 0, 0);
        cur++; if (cur >= 3) cur -= 3;
    }
    __syncthreads();   // protect LDS reuse (phase 2 / epilogue)
}

// ============== bf16 MFMA GEMM: C = A[M,K]@B  (B given as BT[Npad,K] bf16) =======
// EPI 0: fp32 out = acc (+bias if non-null)        (full-col grids only)
// EPI 4: mlp head: v=relu(acc+bias) (cols 0..63); out[row,0:2]=v@Rf[64,2]+Sf[0:2]
// EPI 5: split: col<Fs -> bf16 out; col<2Fs -> fp32 Rf; else fp32 Sf (elem guard).
template<int EPI>
__global__ __launch_bounds__(256) void bgemm(const ushort* __restrict__ A,
                                             const ushort* __restrict__ BT,
                                             const float* __restrict__ bias,
                                             void* __restrict__ out, int ldc,
                                             float* __restrict__ Rf,
                                             float* __restrict__ Sf, int Fs,
                                             int M, int Ncols, int K, int lda) {
    __shared__ ushort As[3][128 * 32];
    __shared__ ushort Bs[3][128 * 32];
    const int tid = threadIdx.x;
    int bx, by; xcd_map(bx, by);
    const int m0 = by * 128, n0 = bx * 128;
    const int w = tid >> 6, lane = tid & 63;
    const int wr = (w >> 1) * 64, wc = (w & 1) * 64;
    const int quad = lane >> 4, l15 = lane & 15;
    const int cA = (quad ^ ((l15 >> 1) & 3)) * 8;
    const int lb0 = w * 512, lb1 = lb0 + 2048;

    const int s0 = tid, s1 = tid + 256;
    const int r0 = s0 >> 2, g0 = ((s0 & 3) ^ ((s0 >> 3) & 3)) * 8;
    const int r1 = s1 >> 2, g1 = ((s1 & 3) ^ ((s1 >> 3) & 3)) * 8;
    int ga0 = m0 + r0; if (ga0 >= M) ga0 = M - 1;
    int ga1 = m0 + r1; if (ga1 >= M) ga1 = M - 1;
    const ushort* aA0 = A + (size_t)ga0 * lda + g0;
    const ushort* aA1 = A + (size_t)ga1 * lda + g1;
    const ushort* aB0 = BT + (size_t)(n0 + r0) * K + g0;
    const ushort* aB1 = BT + (size_t)(n0 + r1) * K + g1;

    f32x4 acc[4][4] = {};
    mfma_loop32(aA0, aA1, aB0, aB1, As[0], Bs[0], lb0, lb1,
                K, wr, wc, cA, l15, acc);

    if (EPI == 4) {
        // cols 0..63 valid (B rows 64..127 are zero-padded); wc==64 waves idle.
        if (wc == 0) {
            #pragma unroll
            for (int i = 0; i < 4; i++) {
                float o0 = 0.f, o1 = 0.f;
                #pragma unroll
                for (int j = 0; j < 4; j++) {
                    int colbase = j * 16 + quad * 4;
                    float4 bv = *reinterpret_cast<const float4*>(&bias[colbase]);
                    float bb[4] = { bv.x, bv.y, bv.z, bv.w };
                    #pragma unroll
                    for (int r = 0; r < 4; r++) {
                        float vv = fmaxf(acc[i][j][r] + bb[r], 0.f);
                        int c = colbase + r;
                        o0 += vv * Rf[2 * c];
                        o1 += vv * Rf[2 * c + 1];
                    }
                }
                // reduce across the 4 quads holding the same row (lanes l15+16q)
                o0 += __shfl_xor(o0, 16, 64); o0 += __shfl_xor(o0, 32, 64);
                o1 += __shfl_xor(o1, 16, 64); o1 += __shfl_xor(o1, 32, 64);
                int row = m0 + wr + i * 16 + l15;
                if (quad == 0 && row < M) {
                    ((float*)out)[(size_t)row * 2]     = o0 + Sf[0];
                    ((float*)out)[(size_t)row * 2 + 1] = o1 + Sf[1];
                }
            }
        }
        return;
    }

    const int twoH = Ncols - 2 * Fs;
    #pragma unroll
    for (int i = 0; i < 4; i++) {
        int row = m0 + wr + i * 16 + l15;
        if (row >= M) continue;
        #pragma unroll
        for (int j = 0; j < 4; j++) {
            int colbase = n0 + wc + j * 16 + quad * 4;
            if (EPI == 0) {
                f32x4 v = acc[i][j];
                if (bias) {
                    float4 bv = *reinterpret_cast<const float4*>(&bias[colbase]);
                    v[0] += bv.x; v[1] += bv.y; v[2] += bv.z; v[3] += bv.w;
                }
                *reinterpret_cast<f32x4*>(&((float*)out)[(size_t)row * ldc + colbase]) = v;
            } else if (EPI == 5) {
                if (colbase + 3 < Fs) {
                    *reinterpret_cast<uint2*>(&((ushort*)out)[(size_t)row * Fs + colbase]) = pack4(acc[i][j]);
                } else if (colbase >= Fs && colbase + 3 < 2 * Fs) {
                    *reinterpret_cast<f32x4*>(&Rf[(size_t)row * Fs + (colbase - Fs)]) = acc[i][j];
                } else {
                    #pragma unroll
                    for (int r = 0; r < 4; r++) {
                        int col = colbase + r;
                        if (col < 2 * Fs || col >= Ncols) continue;
                        Sf[(size_t)row * twoH + (col - 2 * Fs)] = acc[i][j][r];
                    }
                }
            }
        }
    }
}

// ===== fused block-1: H2 = elu(acc_h@W_h + bias1) + h1@res1_w + res1_b (bf16) ====
__global__ __launch_bounds__(256) void bgemm_b1(const ushort* __restrict__ accb,  // N x 1024
                                                const ushort* __restrict__ w1T,   // 1024 x 256
                                                const ushort* __restrict__ h1b,   // N x 256
                                                const ushort* __restrict__ res1T, // 1024 x 256
                                                const float* __restrict__ bias1,
                                                const float* __restrict__ res1b,
                                                ushort* __restrict__ H2b, int M) {
    __shared__ ushort As[3][128 * 32];
    __shared__ ushort Bs[3][128 * 32];
    const int tid = threadIdx.x;
    int bx, by; xcd_map(bx, by);
    const int m0 = by * 128, n0 = bx * 128;
    const int h = n0 >> 8;
    const int w = tid >> 6, lane = tid & 63;
    const int wr = (w >> 1) * 64, wc = (w & 1) * 64;
    const int quad = lane >> 4, l15 = lane & 15;
    const int cA = (quad ^ ((l15 >> 1) & 3)) * 8;
    const int lb0 = w * 512, lb1 = lb0 + 2048;

    const int s0 = tid, s1 = tid + 256;
    const int r0 = s0 >> 2, g0 = ((s0 & 3) ^ ((s0 >> 3) & 3)) * 8;
    const int r1 = s1 >> 2, g1 = ((s1 & 3) ^ ((s1 >> 3) & 3)) * 8;
    int ga0 = m0 + r0; if (ga0 >= M) ga0 = M - 1;
    int ga1 = m0 + r1; if (ga1 >= M) ga1 = M - 1;

    f32x4 acc[4][4] = {};

    // phase 1: acc_h @ W_h
    mfma_loop32(accb + (size_t)ga0 * 1024 + h * 256 + g0,
                accb + (size_t)ga1 * 1024 + h * 256 + g1,
                w1T + (size_t)(n0 + r0) * 256 + g0,
                w1T + (size_t)(n0 + r1) * 256 + g1,
                As[0], Bs[0], lb0, lb1, 256, wr, wc, cA, l15, acc);

    // in-register: acc = elu(acc + bias1) + res1_b
    #pragma unroll
    for (int i = 0; i < 4; i++) {
        #pragma unroll
        for (int j = 0; j < 4; j++) {
            int colbase = n0 + wc + j * 16 + quad * 4;
            float4 bv = *reinterpret_cast<const float4*>(&bias1[colbase]);
            float4 rv = *reinterpret_cast<const float4*>(&res1b[colbase]);
            float bb[4] = { bv.x, bv.y, bv.z, bv.w };
            float rr[4] = { rv.x, rv.y, rv.z, rv.w };
            #pragma unroll
            for (int r = 0; r < 4; r++) {
                float t = acc[i][j][r] + bb[r];
                t = t > 0.f ? t : (__expf(t) - 1.f);
                acc[i][j][r] = t + rr[r];
            }
        }
    }

    // phase 2: += h1 @ res1_w
    mfma_loop32(h1b + (size_t)ga0 * 256 + g0,
                h1b + (size_t)ga1 * 256 + g1,
                res1T + (size_t)(n0 + r0) * 256 + g0,
                res1T + (size_t)(n0 + r1) * 256 + g1,
                As[0], Bs[0], lb0, lb1, 256, wr, wc, cA, l15, acc);

    #pragma unroll
    for (int i = 0; i < 4; i++) {
        int row = m0 + wr + i * 16 + l15;
        if (row >= M) continue;
        #pragma unroll
        for (int j = 0; j < 4; j++) {
            int colbase = n0 + wc + j * 16 + quad * 4;
            *reinterpret_cast<uint2*>(&H2b[(size_t)row * 1024 + colbase]) = pack4(acc[i][j]);
        }
    }
}

// ---------------- conversions / weight prep ----------------
__global__ void conv_pad_x_kernel(const float* __restrict__ x, ushort* __restrict__ xb, int N) {
    int t = blockIdx.x * 256 + threadIdx.x;
    if (t >= N * 448) return;
    int n = t / 448, k = t - n * 448;
    xb[t] = f2b(k < 405 ? x[(size_t)n * 405 + k] : 0.f);
}

// ---- ALL weight preps in ONE launch (bf16 transpose+pad, segment table) ----
__device__ __forceinline__ void prep_seg(int t, const float* src, ushort* dst,
                                         int K, int Nreal, int Kpad, int ldsrc) {
    int n = t / Kpad, k = t - n * Kpad;
    float v = (k < K && n < Nreal) ? src[(size_t)k * ldsrc + n] : 0.f;
    dst[t] = f2b(v);
}

__global__ void prep_all_kernel(const float* __restrict__ enc_w1, const float* __restrict__ enc_w2,
                                const float* __restrict__ w1, const float* __restrict__ res1_w,
                                const float* __restrict__ w2, const float* __restrict__ res2_w,
                                const float* __restrict__ w3, const float* __restrict__ res3_w,
                                const float* __restrict__ mlp_w1,
                                ushort* __restrict__ enc_w1T, ushort* __restrict__ enc_w2T,
                                ushort* __restrict__ w1T, ushort* __restrict__ res1T,
                                ushort* __restrict__ Bcat2T, ushort* __restrict__ Bcat3T,
                                ushort* __restrict__ mlpw1T) {
    int t = blockIdx.x * 256 + threadIdx.x;
    // cumulative boundaries
    const int c0 = 114688;            // enc_w1T 256x448
    const int c1 = c0 + 65536;        // enc_w2T 256x256
    const int c2 = c1 + 262144;       // w1T 1024x256
    const int c3 = c2 + 262144;       // res1T 1024x256
    const int c4 = c3 + 196608;       // Bcat2T rows 0-191 (w2)
    const int c5 = c4 + 196608;       // Bcat2T rows 192-383 (res2)
    const int c6 = c5 + 126976;       // Bcat2T rows 388-511 zero
    const int c7 = c6 + 24576;        // Bcat3T rows 0-127 (w3)
    const int c8 = c7 + 24576;        // Bcat3T rows 128-255 (res3)
    const int c9 = c8 + 24192;        // Bcat3T rows 258-383 zero
    const int c10 = c9 + 16384;       // mlpw1T 128x128
    if (t < c0)      prep_seg(t,        enc_w1, enc_w1T, 405, 256, 448, 256);
    else if (t < c1) prep_seg(t - c0,   enc_w2, enc_w2T, 256, 256, 256, 256);
    else if (t < c2) prep_seg(t - c1,   w1,     w1T,     256, 1024, 256, 1024);
    else if (t < c3) prep_seg(t - c2,   res1_w, res1T,   256, 1024, 256, 1024);
    else if (t < c4) prep_seg(t - c3,   w2,     Bcat2T,  1024, 192, 1024, 192);
    else if (t < c5) prep_seg(t - c4,   res2_w, Bcat2T + (size_t)192 * 1024, 1024, 192, 1024, 192);
    else if (t < c6) Bcat2T[(size_t)388 * 1024 + (t - c5)] = 0;
    else if (t < c7) prep_seg(t - c6,   w3,     Bcat3T,  192, 128, 192, 128);
    else if (t < c8) prep_seg(t - c7,   res3_w, Bcat3T + (size_t)128 * 192, 192, 128, 192, 128);
    else if (t < c9) Bcat3T[(size_t)258 * 192 + (t - c8)] = 0;
    else if (t < c10) prep_seg(t - c9,  mlp_w1, mlpw1T,  128, 64, 128, 64);
}

// ------- LayerNorm(+ReLU) fp32 in, bf16 out; C == 256; optional fused scores ----
// H>0: also writes a_s[row*H+h] = sum(relu_out * qs[h]), a_d likewise (block-1
// attention scores) — removes the separate att_scores4 kernel + its 25.6MB re-read.
template<int H>
__global__ __launch_bounds__(256) void ln_relu_score_kernel(const float* __restrict__ x,
                                                            const float* __restrict__ g,
                                                            const float* __restrict__ b,
                                                            const float* __restrict__ qs,
                                                            const float* __restrict__ qd,
                                                            ushort* __restrict__ out,
                                                            float* __restrict__ a_s,
                                                            float* __restrict__ a_d) {
    const int C = 256;
    int row = blockIdx.x;
    int tid = threadIdx.x;
    int lane = tid & 63, wid = tid >> 6;
    __shared__ float red[4];
    __shared__ float sred[8][4];
    float v = x[(size_t)row * C + tid];
    float s = wave_reduce_sum(v);
    if (lane == 0) red[wid] = s;
    __syncthreads();
    float m = (red[0] + red[1] + red[2] + red[3]) * (1.f / C);
    __syncthreads();
    float d = v - m;
    float s2 = wave_reduce_sum(d * d);
    if (lane == 0) red[wid] = s2;
    __syncthreads();
    float var = (red[0] + red[1] + red[2] + red[3]) * (1.f / C);
    float rs = rsqrtf(var + LN_EPS);
    float o = fmaxf(d * rs * g[tid] + b[tid], 0.f);
    out[(size_t)row * C + tid] = f2b(o);
    if (H > 0) {
        #pragma unroll
        for (int hh = 0; hh < H; hh++) {
            float ss = wave_reduce_sum(o * qs[hh * 256 + tid]);
            float sd = wave_reduce_sum(o * qd[hh * 256 + tid]);
            if (lane == 0) { sred[hh][wid] = ss; sred[H + hh][wid] = sd; }
        }
        __syncthreads();
        if (tid < 2 * H) {
            float t = sred[tid][0] + sred[tid][1] + sred[tid][2] + sred[tid][3];
            if (tid < H) a_s[(size_t)row * H + tid] = t;
            else         a_d[(size_t)row * H + (tid - H)] = t;
        }
    }
}

// ---- fold attention vectors through W (fp32 out, block1) ----
__global__ void fold_att_kernel(const float* __restrict__ W,
                                const float* __restrict__ att_s,
                                const float* __restrict__ att_d,
                                float* __restrict__ qs, float* __restrict__ qd,
                                int Cin, int Cout, int H) {
    int t = blockIdx.x * blockDim.x + threadIdx.x;
    if (t >= H * Cin) return;
    int h = t / Cin, k = t - h * Cin;
    const float* wrow = W + (size_t)k * (H * Cout) + (size_t)h * Cout;
    const float* as = att_s + (size_t)h * Cout;
    const float* ad = att_d + (size_t)h * Cout;
    float ss = 0.f, sd = 0.f;
    for (int c = 0; c < Cout; c++) { float wv = wrow[c]; ss += wv * as[c]; sd += wv * ad[c]; }
    qs[t] = ss;
    qd[t] = sd;
}

// ---- fold attention vectors through W, bf16 out (blocks 2/3 -> Bcat rows) ----
__global__ void fold_att_b16_kernel(const float* __restrict__ W,
                                    const float* __restrict__ att_s,
                                    const float* __restrict__ att_d,
                                    ushort* __restrict__ qs_b, ushort* __restrict__ qd_b,
                                    int Cin, int Cout, int H) {
    int t = blockIdx.x * blockDim.x + threadIdx.x;
    if (t >= H * Cin) return;
    int h = t / Cin, k = t - h * Cin;
    const float* wrow = W + (size_t)k * (H * Cout) + (size_t)h * Cout;
    const float* as = att_s + (size_t)h * Cout;
    const float* ad = att_d + (size_t)h * Cout;
    float ss = 0.f, sd = 0.f;
    for (int c = 0; c < Cout; c++) { float wv = wrow[c]; ss += wv * as[c]; sd += wv * ad[c]; }
    qs_b[t] = f2b(ss);
    qd_b[t] = f2b(sd);
}

// ================= CSR construction (dst-grouped) =========
__device__ __forceinline__ void edge_sd(const int* ei, int e, int E, int& s, int& d) {
    if (e < E) { s = ei[e]; d = ei[E + e]; } else { s = d = e - E; }
}

__global__ void deg_kernel(const int* __restrict__ ei, int* __restrict__ deg, int E, int Et) {
    int e = blockIdx.x * blockDim.x + threadIdx.x;
    if (e >= Et) return;
    int s, d; edge_sd(ei, e, E, s, d);
    atomicAdd(&deg[d], 1);
}

__global__ __launch_bounds__(256) void scan1_kernel(const int* __restrict__ deg,
                                                    int* __restrict__ incl,
                                                    int* __restrict__ part, int N) {
    __shared__ int sd[256];
    int t = threadIdx.x;
    int i = blockIdx.x * 256 + t;
    int v = (i < N) ? deg[i] : 0;
    sd[t] = v; __syncthreads();
    #pragma unroll
    for (int o = 1; o < 256; o <<= 1) {
        int x = (t >= o) ? sd[t - o] : 0;
        __syncthreads();
        sd[t] += x;
        __syncthreads();
    }
    if (i < N) incl[i] = sd[t];
    if (t == 255) part[blockIdx.x] = sd[255];
}

__global__ __launch_bounds__(256) void scan2_kernel(int* __restrict__ part, int nb) {
    __shared__ int sd[256];
    int t = threadIdx.x;
    int v = (t < nb) ? part[t] : 0;
    sd[t] = v; __syncthreads();
    #pragma unroll
    for (int o = 1; o < 256; o <<= 1) {
        int x = (t >= o) ? sd[t - o] : 0;
        __syncthreads();
        sd[t] += x;
        __syncthreads();
    }
    if (t < nb) part[t] = sd[t];
}

__global__ void scan3_kernel(const int* __restrict__ incl, const int* __restrict__ deg,
                             const int* __restrict__ part, int* __restrict__ row_ptr, int N) {
    int i = blockIdx.x * blockDim.x + threadIdx.x;
    if (i >= N) return;
    int off = (blockIdx.x > 0) ? part[blockIdx.x - 1] : 0;
    row_ptr[i] = incl[i] - deg[i] + off;
}

__global__ void fill_kernel(const int* __restrict__ ei, const int* __restrict__ row_ptr,
                            int* __restrict__ cur, int* __restrict__ csr_src, int E, int Et) {
    int e = blockIdx.x * blockDim.x + threadIdx.x;
    if (e >= Et) return;
    int s, d; edge_sd(ei, e, E, s, d);
    int pos = row_ptr[d] + atomicAdd(&cur[d], 1);
    csr_src[pos] = s;
}

// Max per-dst edges cached in LDS by the fused stats+aggr kernels; degrees above
// this fall back to on-the-fly alpha recompute (random graph max-deg ~40 << 256).
#define ACAP 256

// ==== block1: FUSED softmax-stats + gather-aggregate (all 4 heads) ==============
// wave0 computes per-dst max/sum (exp stash in LDS); both waves then gather.
__global__ __launch_bounds__(128) void aggr_b1_fused_kernel(const int* __restrict__ row_ptr,
                                                            const int* __restrict__ deg,
                                                            const int* __restrict__ csr_src,
                                                            const float* __restrict__ a_s,
                                                            const float* __restrict__ a_d,
                                                            const ushort* __restrict__ h1b,
                                                            ushort* __restrict__ accb) {
    __shared__ float alf[ACAP][4];
    __shared__ float sstat[8];     // mx[0..3], rd[4..7]
    int d = blockIdx.x, t = threadIdx.x;
    int base = row_ptr[d], dg = deg[d];
    float4 ad = *reinterpret_cast<const float4*>(&a_d[(size_t)d * 4]);
    if (t < 64) {
        float m0 = -1e30f, m1 = -1e30f, m2 = -1e30f, m3 = -1e30f;
        for (int j = t; j < dg; j += 64) {
            int s = csr_src[base + j];
            float4 sv = *reinterpret_cast<const float4*>(&a_s[(size_t)s * 4]);
            float c0 = sv.x + ad.x; c0 = c0 > 0.f ? c0 : 0.2f * c0; m0 = fmaxf(m0, c0);
            float c1 = sv.y + ad.y; c1 = c1 > 0.f ? c1 : 0.2f * c1; m1 = fmaxf(m1, c1);
            float c2 = sv.z + ad.z; c2 = c2 > 0.f ? c2 : 0.2f * c2; m2 = fmaxf(m2, c2);
            float c3 = sv.w + ad.w; c3 = c3 > 0.f ? c3 : 0.2f * c3; m3 = fmaxf(m3, c3);
        }
        m0 = wave_allreduce_max(m0); m1 = wave_allreduce_max(m1);
        m2 = wave_allreduce_max(m2); m3 = wave_allreduce_max(m3);
        float s0 = 0.f, s1 = 0.f, s2 = 0.f, s3 = 0.f;
        for (int j = t; j < dg; j += 64) {
            int s = csr_src[base + j];
            float4 sv = *reinterpret_cast<const float4*>(&a_s[(size_t)s * 4]);
            float c0 = sv.x + ad.x; c0 = c0 > 0.f ? c0 : 0.2f * c0; float e0 = __expf(c0 - m0); s0 += e0;
            float c1 = sv.y + ad.y; c1 = c1 > 0.f ? c1 : 0.2f * c1; float e1 = __expf(c1 - m1); s1 += e1;
            float c2 = sv.z + ad.z; c2 = c2 > 0.f ? c2 : 0.2f * c2; float e2 = __expf(c2 - m2); s2 += e2;
            float c3 = sv.w + ad.w; c3 = c3 > 0.f ? c3 : 0.2f * c3; float e3 = __expf(c3 - m3); s3 += e3;
            if (j < ACAP) { alf[j][0] = e0; alf[j][1] = e1; alf[j][2] = e2; alf[j][3] = e3; }
        }
        s0 = wave_allreduce_sum(s0); s1 = wave_allreduce_sum(s1);
        s2 = wave_allreduce_sum(s2); s3 = wave_allreduce_sum(s3);
        if (t == 0) {
            sstat[0] = m0; sstat[1] = m1; sstat[2] = m2; sstat[3] = m3;
            sstat[4] = 1.f / (s0 + 1e-16f); sstat[5] = 1.f / (s1 + 1e-16f);
            sstat[6] = 1.f / (s2 + 1e-16f); sstat[7] = 1.f / (s3 + 1e-16f);
        }
    }
    __syncthreads();
    float r0 = sstat[4], r1 = sstat[5], r2 = sstat[6], r3 = sstat[7];
    float a00 = 0, a01 = 0, a10 = 0, a11 = 0, a20 = 0, a21 = 0, a30 = 0, a31 = 0;
    for (int j = 0; j < dg; j++) {
        int s = csr_src[base + j];
        float al0, al1, al2, al3;
        if (j < ACAP) {
            al0 = alf[j][0] * r0; al1 = alf[j][1] * r1;
            al2 = alf[j][2] * r2; al3 = alf[j][3] * r3;
        } else {
            float4 sv = *reinterpret_cast<const float4*>(&a_s[(size_t)s * 4]);
            float c0 = sv.x + ad.x; c0 = c0 > 0.f ? c0 : 0.2f * c0; al0 = __expf(c0 - sstat[0]) * r0;
            float c1 = sv.y + ad.y; c1 = c1 > 0.f ? c1 : 0.2f * c1; al1 = __expf(c1 - sstat[1]) * r1;
            float c2 = sv.z + ad.z; c2 = c2 > 0.f ? c2 : 0.2f * c2; al2 = __expf(c2 - sstat[2]) * r2;
            float c3 = sv.w + ad.w; c3 = c3 > 0.f ? c3 : 0.2f * c3; al3 = __expf(c3 - sstat[3]) * r3;
        }
        unsigned v = reinterpret_cast<const unsigned*>(h1b + (size_t)s * 256)[t];
        float lo = b2f((ushort)(v & 0xffff)), hi = b2f((ushort)(v >> 16));
        a00 += al0 * lo; a01 += al0 * hi;
        a10 += al1 * lo; a11 += al1 * hi;
        a20 += al2 * lo; a21 += al2 * hi;
        a30 += al3 * lo; a31 += al3 * hi;
    }
    unsigned* o = reinterpret_cast<unsigned*>(accb + (size_t)d * 1024);
    o[t]       = pack2(a00, a01);
    o[t + 128] = pack2(a10, a11);
    o[t + 256] = pack2(a20, a21);
    o[t + 384] = pack2(a30, a31);
}

// ==== blocks 2/3: FUSED stats + gather-aggregate + elu/residual epilogue ========
// scores layout: src_h = as[s*2H+h], dst_h = as[d*2H+H+h].
// NOTE: outb must NOT alias g (gather source) — blocks read arbitrary g rows.
template<int H, int C, int F, int NT>
__global__ __launch_bounds__(NT) void aggr_comb_fused_kernel(const int* __restrict__ row_ptr,
                                                             const int* __restrict__ deg,
                                                             const int* __restrict__ csr_src,
                                                             const float* __restrict__ as,
                                                             const ushort* __restrict__ g,
                                                             const float* __restrict__ Rf,
                                                             const float* __restrict__ gb,
                                                             const float* __restrict__ rb,
                                                             ushort* __restrict__ outb) {
    __shared__ float alf[ACAP][H];
    __shared__ float sstat[2 * H];   // mx[0..H), rd[H..2H)
    int d = blockIdx.x;
    int t = threadIdx.x;               // 0..F/2-1
    int base = row_ptr[d], dg = deg[d];
    if (t < 64) {
        float ad[H], mx[H];
        #pragma unroll
        for (int h = 0; h < H; h++) { ad[h] = as[(size_t)d * 2 * H + H + h]; mx[h] = -1e30f; }
        for (int j = t; j < dg; j += 64) {
            int s = csr_src[base + j];
            #pragma unroll
            for (int h = 0; h < H; h++) {
                float c = as[(size_t)s * 2 * H + h] + ad[h];
                c = c > 0.f ? c : 0.2f * c;
                mx[h] = fmaxf(mx[h], c);
            }
        }
        #pragma unroll
        for (int h = 0; h < H; h++) mx[h] = wave_allreduce_max(mx[h]);
        float sm[H];
        #pragma unroll
        for (int h = 0; h < H; h++) sm[h] = 0.f;
        for (int j = t; j < dg; j += 64) {
            int s = csr_src[base + j];
            #pragma unroll
            for (int h = 0; h < H; h++) {
                float c = as[(size_t)s * 2 * H + h] + ad[h];
                c = c > 0.f ? c : 0.2f * c;
                float e = __expf(c - mx[h]);
                sm[h] += e;
                if (j < ACAP) alf[j][h] = e;
            }
        }
        #pragma unroll
        for (int h = 0; h < H; h++) sm[h] = wave_allreduce_sum(sm[h]);
        if (t == 0) {
            #pragma unroll
            for (int h = 0; h < H; h++) { sstat[h] = mx[h]; sstat[H + h] = 1.f / (sm[h] + 1e-16f); }
        }
    }
    __syncthreads();
    int hd = (2 * t) / C;
    float mxv = sstat[hd], rdv = sstat[H + hd];
    float adv = as[(size_t)d * 2 * H + H + hd];
    float lo = 0.f, hi = 0.f;
    for (int j = 0; j < dg; j++) {
        int s = csr_src[base + j];
        float al;
        if (j < ACAP) al = alf[j][hd] * rdv;
        else {
            float c = as[(size_t)s * 2 * H + hd] + adv;
            c = c > 0.f ? c : 0.2f * c;
            al = __expf(c - mxv) * rdv;
        }
        unsigned v = reinterpret_cast<const unsigned*>(g + (size_t)s * F)[t];
        lo += al * b2f((ushort)(v & 0xffff));
        hi += al * b2f((ushort)(v >> 16));
    }
    int c0 = 2 * t, c1 = 2 * t + 1;
    float o0 = lo + gb[c0]; o0 = o0 > 0.f ? o0 : (__expf(o0) - 1.f);
    float o1 = hi + gb[c1]; o1 = o1 > 0.f ? o1 : (__expf(o1) - 1.f);
    o0 += Rf[(size_t)d * F + c0] + rb[c0];
    o1 += Rf[(size_t)d * F + c1] + rb[c1];
    reinterpret_cast<unsigned*>(outb)[(size_t)d * (F / 2) + t] = pack2(o0, o1);
}

extern "C" void kernel_launch(void* const* d_in, const int* in_sizes, int n_in,
                              void* d_out, int out_size, void* d_ws, size_t ws_size,
                              hipStream_t stream) {
    const float* x        = (const float*)d_in[0];
    const int*   ei       = (const int*)d_in[1];
    const float* enc_w1   = (const float*)d_in[2];
    const float* enc_b1   = (const float*)d_in[3];
    const float* ln1_g    = (const float*)d_in[4];
    const float* ln1_b    = (const float*)d_in[5];
    const float* enc_w2   = (const float*)d_in[6];
    const float* enc_b2   = (const float*)d_in[7];
    const float* ln2_g    = (const float*)d_in[8];
    const float* ln2_b    = (const float*)d_in[9];
    const float* w1       = (const float*)d_in[10];
    const float* att_src1 = (const float*)d_in[11];
    const float* att_dst1 = (const float*)d_in[12];
    const float* bias1    = (const float*)d_in[13];
    const float* res1_w   = (const float*)d_in[14];
    const float* res1_b   = (const float*)d_in[15];
    const float* w2       = (const float*)d_in[16];
    const float* att_src2 = (const float*)d_in[17];
    const float* att_dst2 = (const float*)d_in[18];
    const float* bias2    = (const float*)d_in[19];
    const float* res2_w   = (const float*)d_in[20];
    const float* res2_b   = (const float*)d_in[21];
    const float* w3       = (const float*)d_in[22];
    const float* att_src3 = (const float*)d_in[23];
    const float* att_dst3 = (const float*)d_in[24];
    const float* bias3    = (const float*)d_in[25];
    const float* res3_w   = (const float*)d_in[26];
    const float* res3_b   = (const float*)d_in[27];
    const float* mlp_w1   = (const float*)d_in[28];
    const float* mlp_b1   = (const float*)d_in[29];
    const float* mlp_w2   = (const float*)d_in[30];
    const float* mlp_b2   = (const float*)d_in[31];

    const int N  = in_sizes[0] / 405;   // 50000
    const int E  = in_sizes[1] / 2;     // 300000
    const int Et = E + N;
    const int NB = (N + 255) / 256;

    // ---------- workspace layout (bytes) ----------
    char* p = (char*)d_ws;
    char* R0 = p;                       // N*896 B : xb(448 b16) | H3b(b16 192)
    char* R1 = R0 + (size_t)N * 896;    // N*512 B : h0b | G2b
    char* R2 = R1 + (size_t)N * 512;    // N*512 B : h1b | G3b , H4b(@+N*256B)
    char* R3 = R2 + (size_t)N * 512;    // N*2048 B: F1(f32 256) | H2b(b16 1024)
    char* R4 = R3 + (size_t)N * 2048;   // N*2048 B: accb(b16 1024) | Rf(f32 192/128)
    char* T  = R4 + (size_t)N * 2048;   // tail

    ushort* xb   = (ushort*)R0;
    ushort* H3b  = (ushort*)R0;          // lives after xb is dead (enc1 done)
    ushort* h0b  = (ushort*)R1;
    ushort* G2b  = (ushort*)R1;
    ushort* h1b  = (ushort*)R2;
    ushort* G3b  = (ushort*)R2;
    ushort* H4b  = (ushort*)(R2 + (size_t)N * 256);
    float*  F1   = (float*)R3;
    ushort* H2b  = (ushort*)R3;
    ushort* accb = (ushort*)R4;
    float*  Rf   = (float*)R4;

    float* a_s   = (float*)T;                         T += (size_t)N * 4 * 4;   // also Sf2/Sf3
    float* a_d   = (float*)T;                         T += (size_t)N * 4 * 4;
    float* qs    = (float*)T;                         T += 2048 * 4;
    float* qd    = (float*)T;                         T += 2048 * 4;
    int* deg     = (int*)T;                           T += (size_t)N * 4;
    int* cur     = (int*)T;                           T += (size_t)N * 4;
    int* row_ptr = (int*)T;                           T += (size_t)N * 4;
    int* incl    = (int*)T;                           T += (size_t)N * 4;
    int* part    = (int*)T;                           T += 256 * 4;
    int* csr_src = (int*)T;                           T += (size_t)Et * 4;
    ushort* enc_w1T = (ushort*)T;                     T += (size_t)256 * 448 * 2;
    ushort* enc_w2T = (ushort*)T;                     T += (size_t)256 * 256 * 2;
    ushort* w1T     = (ushort*)T;                     T += (size_t)1024 * 256 * 2;
    ushort* res1T   = (ushort*)T;                     T += (size_t)1024 * 256 * 2;
    ushort* Bcat2T  = (ushort*)T;                     T += (size_t)512 * 1024 * 2;
    ushort* Bcat3T  = (ushort*)T;                     T += (size_t)384 * 192 * 2;
    ushort* mlpw1T  = (ushort*)T;                     T += (size_t)128 * 128 * 2;

    auto cdiv = [](int a, int b) { return (a + b - 1) / b; };
    const int MB = cdiv(N, 128);

    // ---- CSR build ----
    hipMemsetAsync(deg, 0, (size_t)N * 8, stream);   // deg + cur
    deg_kernel<<<cdiv(Et, 256), 256, 0, stream>>>(ei, deg, E, Et);
    scan1_kernel<<<NB, 256, 0, stream>>>(deg, incl, part, N);
    scan2_kernel<<<1, 256, 0, stream>>>(part, NB);
    scan3_kernel<<<NB, 256, 0, stream>>>(incl, deg, part, row_ptr, N);
    fill_kernel<<<cdiv(Et, 256), 256, 0, stream>>>(ei, row_ptr, cur, csr_src, E, Et);

    // ---- weight prep: ONE launch ----
    prep_all_kernel<<<cdiv(1314432, 256), 256, 0, stream>>>(
        enc_w1, enc_w2, w1, res1_w, w2, res2_w, w3, res3_w, mlp_w1,
        enc_w1T, enc_w2T, w1T, res1T, Bcat2T, Bcat3T, mlpw1T);

    // block-1 att fold (needed by ln_relu_score<4>)
    fold_att_kernel<<<cdiv(4 * 256, 256), 256, 0, stream>>>(w1, att_src1, att_dst1, qs, qd, 256, 256, 4);

    // ---- JointEncoder ----
    conv_pad_x_kernel<<<cdiv(N * 448, 256), 256, 0, stream>>>(x, xb, N);
    bgemm<0><<<dim3(2, MB), 256, 0, stream>>>(xb, enc_w1T, enc_b1, F1, 256, nullptr, nullptr, 0, N, 256, 448, 448);
    ln_relu_score_kernel<0><<<N, 256, 0, stream>>>(F1, ln1_g, ln1_b, nullptr, nullptr, h0b, nullptr, nullptr);
    bgemm<0><<<dim3(2, MB), 256, 0, stream>>>(h0b, enc_w2T, enc_b2, F1, 256, nullptr, nullptr, 0, N, 256, 256, 256);
    // LN2 + fused block-1 attention scores (fp32, more accurate than bf16 path)
    ln_relu_score_kernel<4><<<N, 256, 0, stream>>>(F1, ln2_g, ln2_b, qs, qd, h1b, a_s, a_d);

    // ---- Block 1: GAT 256 -> 4x256 concat (fused stats+aggr, fused head GEMMs) --
    aggr_b1_fused_kernel<<<N, 128, 0, stream>>>(row_ptr, deg, csr_src, a_s, a_d, h1b, accb);
    bgemm_b1<<<dim3(8, MB), 256, 0, stream>>>(accb, w1T, h1b, res1T, bias1, res1_b, H2b, N);

    // ---- Block 2: GAT 1024 -> 2x96 concat (G/R/scores in one split-epilogue GEMM)
    {
        fold_att_b16_kernel<<<cdiv(2 * 1024, 256), 256, 0, stream>>>(w2, att_src2, att_dst2,
            Bcat2T + (size_t)384 * 1024, Bcat2T + (size_t)386 * 1024, 1024, 96, 2);
        // cols: [0,192)=G2b bf16, [192,384)=Rf fp32, [384,388)=scores -> a_s[N,4]
        bgemm<5><<<dim3(4, MB), 256, 0, stream>>>(H2b, Bcat2T, nullptr, G2b, 0, Rf, a_s, 192, N, 388, 1024, 1024);
        // H3b (R0) does NOT alias G2b (R1) -> fused gather+epilogue is safe
        aggr_comb_fused_kernel<2, 96, 192, 96><<<N, 96, 0, stream>>>(row_ptr, deg, csr_src, a_s,
                                                                     G2b, Rf, bias2, res2_b, H3b);
    }

    // ---- Block 3: GAT 192 -> 1x128 (no concat) ----
    {
        fold_att_b16_kernel<<<1, 256, 0, stream>>>(w3, att_src3, att_dst3,
            Bcat3T + (size_t)256 * 192, Bcat3T + (size_t)257 * 192, 192, 128, 1);
        // cols: [0,128)=G3b bf16, [128,256)=Rf fp32, [256,258)=scores -> a_s[N,2]
        bgemm<5><<<dim3(3, MB), 256, 0, stream>>>(H3b, Bcat3T, nullptr, G3b, 0, Rf, a_s, 128, N, 258, 192, 192);
        // H4b (R2 + N*256B) does NOT alias G3b (R2, N*256B) -> safe
        aggr_comb_fused_kernel<1, 128, 128, 64><<<N, 64, 0, stream>>>(row_ptr, deg, csr_src, a_s,
                                                                      G3b, Rf, bias3, res3_b, H4b);
    }

    // ---- MLP head: relu(H4b@mlp_w1+b1)@mlp_w2+b2 fused into ONE GEMM epilogue ---
    bgemm<4><<<dim3(1, MB), 256, 0, stream>>>(H4b, mlpw1T, mlp_b1, d_out, 2,
                                              (float*)mlp_w2, (float*)mlp_b2, 0, N, 64, 128, 128);
}

// Round 3
// 809.141 us; speedup vs baseline: 1.1397x; 1.1397x over previous
//
#include <hip/hip_runtime.h>
#include <cstddef>

#define LN_EPS 1e-5f

typedef __bf16 bf16x8 __attribute__((ext_vector_type(8)));
typedef float  f32x4  __attribute__((ext_vector_type(4)));

typedef __attribute__((address_space(3))) unsigned int lds_u32;
typedef __attribute__((address_space(1))) unsigned int glb_u32;

__device__ __forceinline__ void gl2lds16(const void* g, void* l) {
    // 16B per lane DMA: LDS dest = wave-uniform base + lane*16
    __builtin_amdgcn_global_load_lds((const glb_u32*)g, (lds_u32*)l, 16, 0, 0);
}

__device__ __forceinline__ float b2f(ushort h) {
    return __uint_as_float(((unsigned)h) << 16);
}
__device__ __forceinline__ ushort f2b(float f) {   // RNE
    unsigned u = __float_as_uint(f);
    return (ushort)((u + 0x7fffu + ((u >> 16) & 1u)) >> 16);
}
__device__ __forceinline__ unsigned pack2(float lo, float hi) {
    return (unsigned)f2b(lo) | ((unsigned)f2b(hi) << 16);
}
__device__ __forceinline__ uint2 pack4(const f32x4 v) {
    return make_uint2(pack2(v[0], v[1]), pack2(v[2], v[3]));
}

// XCD-aware remap: all gridDim.x col-blocks of one row-block land on one XCD.
__device__ __forceinline__ void xcd_map(int& bx, int& by) {
    int NX = gridDim.x, MBr = gridDim.y;
    int L = blockIdx.y * NX + blockIdx.x;
    int G = NX * 8;
    int g = L / G;
    if (g * 8 + 8 <= MBr) {
        int r = L - g * G;
        by = g * 8 + (r & 7);
        bx = r >> 3;
    } else {
        by = L / NX;
        bx = L - by * NX;
    }
}

__device__ __forceinline__ float wave_allreduce_max(float v) {
    #pragma unroll
    for (int off = 32; off > 0; off >>= 1) v = fmaxf(v, __shfl_xor(v, off, 64));
    return v;
}
__device__ __forceinline__ float wave_allreduce_sum(float v) {
    #pragma unroll
    for (int off = 32; off > 0; off >>= 1) v += __shfl_xor(v, off, 64);
    return v;
}

// ---- BK=32 TRIPLE-buffered MFMA K-loop with counted vmcnt (T4) -----------------
// Pipeline invariants (per wave, 4 global_load_lds per stage):
//   prologue issues S0,S1. Iteration t: outstanding <= {S(t), S(t+1)};
//   s_waitcnt vmcnt(4) completes everything except the newest 4 (= S(t+1)),
//   so S(t) (the buffer read this iter) is done. s_barrier makes that true
//   across all waves. S(t+2) is staged into buf[(t+2)%3] == buf[(t-1)%3];
//   safe because every wave's iter t-1 ds_reads completed before it arrived
//   at barrier(t) (compiler lgkmcnt before the consuming MFMAs).
// SWAPPED operands: acc[i][j] = mfma(bf[j], af[i], acc) so that
//   C row = m0+wr+i*16+l15 ; C col = n0+wc+j*16+quad*4+reg
__device__ __forceinline__ void stage32(const ushort* a0, const ushort* a1,
                                        const ushort* b0, const ushort* b1,
                                        ushort* __restrict__ As, ushort* __restrict__ Bs,
                                        int lb0, int lb1) {
    gl2lds16(a0, As + lb0);
    gl2lds16(a1, As + lb1);
    gl2lds16(b0, Bs + lb0);
    gl2lds16(b1, Bs + lb1);
}

__device__ __forceinline__ void mfma_loop32(const ushort* aA0, const ushort* aA1,
                                            const ushort* aB0, const ushort* aB1,
                                            ushort* __restrict__ As, ushort* __restrict__ Bs,
                                            int lb0, int lb1,
                                            int K, int wr, int wc, int cA, int l15,
                                            f32x4 acc[4][4]) {
    const int BUF = 128 * 32;          // ushorts per buffer
    const int nk = K >> 5;
    stage32(aA0, aA1, aB0, aB1, As, Bs, lb0, lb1);                               // S0
    if (nk > 1) stage32(aA0 + 32, aA1 + 32, aB0 + 32, aB1 + 32,
                        As + BUF, Bs + BUF, lb0, lb1);                            // S1
    int cur = 0;
    for (int t = 0; t < nk; t++) {
        if (t + 1 < nk) asm volatile("s_waitcnt vmcnt(4)" ::: "memory");
        else            asm volatile("s_waitcnt vmcnt(0)" ::: "memory");
        __builtin_amdgcn_s_barrier();
        __builtin_amdgcn_sched_barrier(0);   // no ds_read may hoist above barrier
        int kn = (t + 2) * 32;
        if (kn < K) {
            int nb = cur + 2; if (nb >= 3) nb -= 3;
            stage32(aA0 + kn, aA1 + kn, aB0 + kn, aB1 + kn,
                    As + nb * BUF, Bs + nb * BUF, lb0, lb1);
        }
        const ushort* Ac = As + cur * BUF;
        const ushort* Bc = Bs + cur * BUF;
        bf16x8 af[4], bf[4];
        #pragma unroll
        for (int i = 0; i < 4; i++)
            af[i] = *reinterpret_cast<const bf16x8*>(&Ac[(wr + i * 16 + l15) * 32 + cA]);
        #pragma unroll
        for (int j = 0; j < 4; j++)
            bf[j] = *reinterpret_cast<const bf16x8*>(&Bc[(wc + j * 16 + l15) * 32 + cA]);
        #pragma unroll
        for (int i = 0; i < 4; i++)
            #pragma unroll
            for (int j = 0; j < 4; j++)
                acc[i][j] = __builtin_amdgcn_mfma_f32_16x16x32_bf16(bf[j], af[i], acc[i][j], 0, 0, 0);
        cur++; if (cur >= 3) cur -= 3;
    }
    __syncthreads();   // protect LDS reuse (phase 2 / epilogue)
}

// ============== bf16 MFMA GEMM: C = A[M,K]@B  (B given as BT[Npad,K] bf16) =======
// EPI 0: fp32 out = acc (+bias if non-null)        (full-col grids only)
// EPI 4: mlp head: v=relu(acc+bias) (cols 0..63); out[row,0:2]=v@Rf[64,2]+Sf[0:2]
// EPI 5: split: col<Fs -> bf16 out; col<2Fs -> fp32 Rf; else fp32 Sf (elem guard).
template<int EPI>
__global__ __launch_bounds__(256) void bgemm(const ushort* __restrict__ A,
                                             const ushort* __restrict__ BT,
                                             const float* __restrict__ bias,
                                             void* __restrict__ out, int ldc,
                                             float* __restrict__ Rf,
                                             float* __restrict__ Sf, int Fs,
                                             int M, int Ncols, int K, int lda) {
    __shared__ ushort As[3][128 * 32];
    __shared__ ushort Bs[3][128 * 32];
    const int tid = threadIdx.x;
    int bx, by; xcd_map(bx, by);
    const int m0 = by * 128, n0 = bx * 128;
    const int w = tid >> 6, lane = tid & 63;
    const int wr = (w >> 1) * 64, wc = (w & 1) * 64;
    const int quad = lane >> 4, l15 = lane & 15;
    const int cA = (quad ^ ((l15 >> 1) & 3)) * 8;
    const int lb0 = w * 512, lb1 = lb0 + 2048;

    const int s0 = tid, s1 = tid + 256;
    const int r0 = s0 >> 2, g0 = ((s0 & 3) ^ ((s0 >> 3) & 3)) * 8;
    const int r1 = s1 >> 2, g1 = ((s1 & 3) ^ ((s1 >> 3) & 3)) * 8;
    int ga0 = m0 + r0; if (ga0 >= M) ga0 = M - 1;
    int ga1 = m0 + r1; if (ga1 >= M) ga1 = M - 1;
    const ushort* aA0 = A + (size_t)ga0 * lda + g0;
    const ushort* aA1 = A + (size_t)ga1 * lda + g1;
    const ushort* aB0 = BT + (size_t)(n0 + r0) * K + g0;
    const ushort* aB1 = BT + (size_t)(n0 + r1) * K + g1;

    f32x4 acc[4][4] = {};
    mfma_loop32(aA0, aA1, aB0, aB1, As[0], Bs[0], lb0, lb1,
                K, wr, wc, cA, l15, acc);

    if (EPI == 4) {
        // cols 0..63 valid (B rows 64..127 are zero-padded); wc==64 waves idle.
        if (wc == 0) {
            #pragma unroll
            for (int i = 0; i < 4; i++) {
                float o0 = 0.f, o1 = 0.f;
                #pragma unroll
                for (int j = 0; j < 4; j++) {
                    int colbase = j * 16 + quad * 4;
                    float4 bv = *reinterpret_cast<const float4*>(&bias[colbase]);
                    float bb[4] = { bv.x, bv.y, bv.z, bv.w };
                    #pragma unroll
                    for (int r = 0; r < 4; r++) {
                        float vv = fmaxf(acc[i][j][r] + bb[r], 0.f);
                        int c = colbase + r;
                        o0 += vv * Rf[2 * c];
                        o1 += vv * Rf[2 * c + 1];
                    }
                }
                // reduce across the 4 quads holding the same row (lanes l15+16q)
                o0 += __shfl_xor(o0, 16, 64); o0 += __shfl_xor(o0, 32, 64);
                o1 += __shfl_xor(o1, 16, 64); o1 += __shfl_xor(o1, 32, 64);
                int row = m0 + wr + i * 16 + l15;
                if (quad == 0 && row < M) {
                    ((float*)out)[(size_t)row * 2]     = o0 + Sf[0];
                    ((float*)out)[(size_t)row * 2 + 1] = o1 + Sf[1];
                }
            }
        }
        return;
    }

    const int twoH = Ncols - 2 * Fs;
    #pragma unroll
    for (int i = 0; i < 4; i++) {
        int row = m0 + wr + i * 16 + l15;
        if (row >= M) continue;
        #pragma unroll
        for (int j = 0; j < 4; j++) {
            int colbase = n0 + wc + j * 16 + quad * 4;
            if (EPI == 0) {
                f32x4 v = acc[i][j];
                if (bias) {
                    float4 bv = *reinterpret_cast<const float4*>(&bias[colbase]);
                    v[0] += bv.x; v[1] += bv.y; v[2] += bv.z; v[3] += bv.w;
                }
                *reinterpret_cast<f32x4*>(&((float*)out)[(size_t)row * ldc + colbase]) = v;
            } else if (EPI == 5) {
                if (colbase + 3 < Fs) {
                    *reinterpret_cast<uint2*>(&((ushort*)out)[(size_t)row * Fs + colbase]) = pack4(acc[i][j]);
                } else if (colbase >= Fs && colbase + 3 < 2 * Fs) {
                    *reinterpret_cast<f32x4*>(&Rf[(size_t)row * Fs + (colbase - Fs)]) = acc[i][j];
                } else {
                    #pragma unroll
                    for (int r = 0; r < 4; r++) {
                        int col = colbase + r;
                        if (col < 2 * Fs || col >= Ncols) continue;
                        Sf[(size_t)row * twoH + (col - 2 * Fs)] = acc[i][j][r];
                    }
                }
            }
        }
    }
}

// ===== fused block-1: H2 = elu(acc_h@W_h + bias1) + h1@res1_w + res1_b (bf16) ====
__global__ __launch_bounds__(256) void bgemm_b1(const ushort* __restrict__ accb,  // N x 1024
                                                const ushort* __restrict__ w1T,   // 1024 x 256
                                                const ushort* __restrict__ h1b,   // N x 256
                                                const ushort* __restrict__ res1T, // 1024 x 256
                                                const float* __restrict__ bias1,
                                                const float* __restrict__ res1b,
                                                ushort* __restrict__ H2b, int M) {
    __shared__ ushort As[3][128 * 32];
    __shared__ ushort Bs[3][128 * 32];
    const int tid = threadIdx.x;
    int bx, by; xcd_map(bx, by);
    const int m0 = by * 128, n0 = bx * 128;
    const int h = n0 >> 8;
    const int w = tid >> 6, lane = tid & 63;
    const int wr = (w >> 1) * 64, wc = (w & 1) * 64;
    const int quad = lane >> 4, l15 = lane & 15;
    const int cA = (quad ^ ((l15 >> 1) & 3)) * 8;
    const int lb0 = w * 512, lb1 = lb0 + 2048;

    const int s0 = tid, s1 = tid + 256;
    const int r0 = s0 >> 2, g0 = ((s0 & 3) ^ ((s0 >> 3) & 3)) * 8;
    const int r1 = s1 >> 2, g1 = ((s1 & 3) ^ ((s1 >> 3) & 3)) * 8;
    int ga0 = m0 + r0; if (ga0 >= M) ga0 = M - 1;
    int ga1 = m0 + r1; if (ga1 >= M) ga1 = M - 1;

    f32x4 acc[4][4] = {};

    // phase 1: acc_h @ W_h
    mfma_loop32(accb + (size_t)ga0 * 1024 + h * 256 + g0,
                accb + (size_t)ga1 * 1024 + h * 256 + g1,
                w1T + (size_t)(n0 + r0) * 256 + g0,
                w1T + (size_t)(n0 + r1) * 256 + g1,
                As[0], Bs[0], lb0, lb1, 256, wr, wc, cA, l15, acc);

    // in-register: acc = elu(acc + bias1) + res1_b
    #pragma unroll
    for (int i = 0; i < 4; i++) {
        #pragma unroll
        for (int j = 0; j < 4; j++) {
            int colbase = n0 + wc + j * 16 + quad * 4;
            float4 bv = *reinterpret_cast<const float4*>(&bias1[colbase]);
            float4 rv = *reinterpret_cast<const float4*>(&res1b[colbase]);
            float bb[4] = { bv.x, bv.y, bv.z, bv.w };
            float rr[4] = { rv.x, rv.y, rv.z, rv.w };
            #pragma unroll
            for (int r = 0; r < 4; r++) {
                float t = acc[i][j][r] + bb[r];
                t = t > 0.f ? t : (__expf(t) - 1.f);
                acc[i][j][r] = t + rr[r];
            }
        }
    }

    // phase 2: += h1 @ res1_w
    mfma_loop32(h1b + (size_t)ga0 * 256 + g0,
                h1b + (size_t)ga1 * 256 + g1,
                res1T + (size_t)(n0 + r0) * 256 + g0,
                res1T + (size_t)(n0 + r1) * 256 + g1,
                As[0], Bs[0], lb0, lb1, 256, wr, wc, cA, l15, acc);

    #pragma unroll
    for (int i = 0; i < 4; i++) {
        int row = m0 + wr + i * 16 + l15;
        if (row >= M) continue;
        #pragma unroll
        for (int j = 0; j < 4; j++) {
            int colbase = n0 + wc + j * 16 + quad * 4;
            *reinterpret_cast<uint2*>(&H2b[(size_t)row * 1024 + colbase]) = pack4(acc[i][j]);
        }
    }
}

// ---------------- conversions / weight prep ----------------
__global__ void conv_pad_x_kernel(const float* __restrict__ x, ushort* __restrict__ xb, int N) {
    int t = blockIdx.x * 256 + threadIdx.x;
    if (t >= N * 448) return;
    int n = t / 448, k = t - n * 448;
    xb[t] = f2b(k < 405 ? x[(size_t)n * 405 + k] : 0.f);
}

// ---- ALL weight preps in ONE launch (bf16 transpose+pad, segment table) ----
__device__ __forceinline__ void prep_seg(int t, const float* src, ushort* dst,
                                         int K, int Nreal, int Kpad, int ldsrc) {
    int n = t / Kpad, k = t - n * Kpad;
    float v = (k < K && n < Nreal) ? src[(size_t)k * ldsrc + n] : 0.f;
    dst[t] = f2b(v);
}

__global__ void prep_all_kernel(const float* __restrict__ enc_w1, const float* __restrict__ enc_w2,
                                const float* __restrict__ w1, const float* __restrict__ res1_w,
                                const float* __restrict__ w2, const float* __restrict__ res2_w,
                                const float* __restrict__ w3, const float* __restrict__ res3_w,
                                const float* __restrict__ mlp_w1,
                                ushort* __restrict__ enc_w1T, ushort* __restrict__ enc_w2T,
                                ushort* __restrict__ w1T, ushort* __restrict__ res1T,
                                ushort* __restrict__ Bcat2T, ushort* __restrict__ Bcat3T,
                                ushort* __restrict__ mlpw1T) {
    int t = blockIdx.x * 256 + threadIdx.x;
    // cumulative boundaries
    const int c0 = 114688;            // enc_w1T 256x448
    const int c1 = c0 + 65536;        // enc_w2T 256x256
    const int c2 = c1 + 262144;       // w1T 1024x256
    const int c3 = c2 + 262144;       // res1T 1024x256
    const int c4 = c3 + 196608;       // Bcat2T rows 0-191 (w2)
    const int c5 = c4 + 196608;       // Bcat2T rows 192-383 (res2)
    const int c6 = c5 + 126976;       // Bcat2T rows 388-511 zero
    const int c7 = c6 + 24576;        // Bcat3T rows 0-127 (w3)
    const int c8 = c7 + 24576;        // Bcat3T rows 128-255 (res3)
    const int c9 = c8 + 24192;        // Bcat3T rows 258-383 zero
    const int c10 = c9 + 16384;       // mlpw1T 128x128
    if (t < c0)      prep_seg(t,        enc_w1, enc_w1T, 405, 256, 448, 256);
    else if (t < c1) prep_seg(t - c0,   enc_w2, enc_w2T, 256, 256, 256, 256);
    else if (t < c2) prep_seg(t - c1,   w1,     w1T,     256, 1024, 256, 1024);
    else if (t < c3) prep_seg(t - c2,   res1_w, res1T,   256, 1024, 256, 1024);
    else if (t < c4) prep_seg(t - c3,   w2,     Bcat2T,  1024, 192, 1024, 192);
    else if (t < c5) prep_seg(t - c4,   res2_w, Bcat2T + (size_t)192 * 1024, 1024, 192, 1024, 192);
    else if (t < c6) Bcat2T[(size_t)388 * 1024 + (t - c5)] = 0;
    else if (t < c7) prep_seg(t - c6,   w3,     Bcat3T,  192, 128, 192, 128);
    else if (t < c8) prep_seg(t - c7,   res3_w, Bcat3T + (size_t)128 * 192, 192, 128, 192, 128);
    else if (t < c9) Bcat3T[(size_t)258 * 192 + (t - c8)] = 0;
    else if (t < c10) prep_seg(t - c9,  mlp_w1, mlpw1T,  128, 64, 128, 64);
}

// ------- LayerNorm(+ReLU), WAVE-PER-ROW: fp32 in, bf16 out; C == 256 -----------
// One 64-lane wave owns a row: f32x4/lane, single-pass sum+sumsq butterfly,
// no __syncthreads, no LDS. H>0 additionally computes block-1 attention scores
// (qs/qd hoisted to registers once per wave, 8 in-lane dots + 8-value butterfly).
template<int H>
__global__ __launch_bounds__(256) void ln_relu_w_kernel(const float* __restrict__ x,
                                                        const float* __restrict__ g,
                                                        const float* __restrict__ b,
                                                        const float* __restrict__ qs,
                                                        const float* __restrict__ qd,
                                                        ushort* __restrict__ out,
                                                        float* __restrict__ a_s,
                                                        float* __restrict__ a_d,
                                                        int N) {
    const int lane = threadIdx.x & 63;
    int wid = blockIdx.x * 4 + (threadIdx.x >> 6);
    const int nw = gridDim.x * 4;
    const int c4 = lane * 4;

    f32x4 gv = *reinterpret_cast<const f32x4*>(&g[c4]);
    f32x4 bv = *reinterpret_cast<const f32x4*>(&b[c4]);
    f32x4 qsv[H > 0 ? H : 1], qdv[H > 0 ? H : 1];
    if (H > 0) {
        #pragma unroll
        for (int hh = 0; hh < H; hh++) {
            qsv[hh] = *reinterpret_cast<const f32x4*>(&qs[hh * 256 + c4]);
            qdv[hh] = *reinterpret_cast<const f32x4*>(&qd[hh * 256 + c4]);
        }
    }

    for (int row = wid; row < N; row += nw) {
        f32x4 v = *reinterpret_cast<const f32x4*>(&x[(size_t)row * 256 + c4]);
        float s  = v[0] + v[1] + v[2] + v[3];
        float s2 = v[0] * v[0] + v[1] * v[1] + v[2] * v[2] + v[3] * v[3];
        #pragma unroll
        for (int off = 32; off > 0; off >>= 1) {
            s  += __shfl_xor(s,  off, 64);
            s2 += __shfl_xor(s2, off, 64);
        }
        float m   = s * (1.f / 256.f);
        float var = s2 * (1.f / 256.f) - m * m;
        float rs  = rsqrtf(var + LN_EPS);
        f32x4 o;
        #pragma unroll
        for (int k = 0; k < 4; k++) o[k] = fmaxf((v[k] - m) * rs * gv[k] + bv[k], 0.f);
        *reinterpret_cast<uint2*>(&out[(size_t)row * 256 + c4]) =
            make_uint2(pack2(o[0], o[1]), pack2(o[2], o[3]));
        if (H > 0) {
            float sc[H > 0 ? 2 * H : 1];
            #pragma unroll
            for (int hh = 0; hh < H; hh++) {
                sc[hh]     = o[0] * qsv[hh][0] + o[1] * qsv[hh][1] + o[2] * qsv[hh][2] + o[3] * qsv[hh][3];
                sc[H + hh] = o[0] * qdv[hh][0] + o[1] * qdv[hh][1] + o[2] * qdv[hh][2] + o[3] * qdv[hh][3];
            }
            #pragma unroll
            for (int off = 32; off > 0; off >>= 1)
                #pragma unroll
                for (int k = 0; k < 2 * H; k++) sc[k] += __shfl_xor(sc[k], off, 64);
            if (lane == 0) {
                #pragma unroll
                for (int k = 0; k < H; k++) a_s[(size_t)row * H + k] = sc[k];
            } else if (lane == 1) {
                #pragma unroll
                for (int k = 0; k < H; k++) a_d[(size_t)row * H + k] = sc[H + k];
            }
        }
    }
}

// ---- fold attention vectors through W (fp32 out, block1) ----
__global__ void fold_att_kernel(const float* __restrict__ W,
                                const float* __restrict__ att_s,
                                const float* __restrict__ att_d,
                                float* __restrict__ qs, float* __restrict__ qd,
                                int Cin, int Cout, int H) {
    int t = blockIdx.x * blockDim.x + threadIdx.x;
    if (t >= H * Cin) return;
    int h = t / Cin, k = t - h * Cin;
    const float* wrow = W + (size_t)k * (H * Cout) + (size_t)h * Cout;
    const float* as = att_s + (size_t)h * Cout;
    const float* ad = att_d + (size_t)h * Cout;
    float ss = 0.f, sd = 0.f;
    for (int c = 0; c < Cout; c++) { float wv = wrow[c]; ss += wv * as[c]; sd += wv * ad[c]; }
    qs[t] = ss;
    qd[t] = sd;
}

// ---- fold attention vectors through W, bf16 out (blocks 2/3 -> Bcat rows) ----
__global__ void fold_att_b16_kernel(const float* __restrict__ W,
                                    const float* __restrict__ att_s,
                                    const float* __restrict__ att_d,
                                    ushort* __restrict__ qs_b, ushort* __restrict__ qd_b,
                                    int Cin, int Cout, int H) {
    int t = blockIdx.x * blockDim.x + threadIdx.x;
    if (t >= H * Cin) return;
    int h = t / Cin, k = t - h * Cin;
    const float* wrow = W + (size_t)k * (H * Cout) + (size_t)h * Cout;
    const float* as = att_s + (size_t)h * Cout;
    const float* ad = att_d + (size_t)h * Cout;
    float ss = 0.f, sd = 0.f;
    for (int c = 0; c < Cout; c++) { float wv = wrow[c]; ss += wv * as[c]; sd += wv * ad[c]; }
    qs_b[t] = f2b(ss);
    qd_b[t] = f2b(sd);
}

// ================= CSR construction (dst-grouped) =========
__device__ __forceinline__ void edge_sd(const int* ei, int e, int E, int& s, int& d) {
    if (e < E) { s = ei[e]; d = ei[E + e]; } else { s = d = e - E; }
}

__global__ void deg_kernel(const int* __restrict__ ei, int* __restrict__ deg, int E, int Et) {
    int e = blockIdx.x * blockDim.x + threadIdx.x;
    if (e >= Et) return;
    int s, d; edge_sd(ei, e, E, s, d);
    atomicAdd(&deg[d], 1);
}

__global__ __launch_bounds__(256) void scan1_kernel(const int* __restrict__ deg,
                                                    int* __restrict__ incl,
                                                    int* __restrict__ part, int N) {
    __shared__ int sd[256];
    int t = threadIdx.x;
    int i = blockIdx.x * 256 + t;
    int v = (i < N) ? deg[i] : 0;
    sd[t] = v; __syncthreads();
    #pragma unroll
    for (int o = 1; o < 256; o <<= 1) {
        int x = (t >= o) ? sd[t - o] : 0;
        __syncthreads();
        sd[t] += x;
        __syncthreads();
    }
    if (i < N) incl[i] = sd[t];
    if (t == 255) part[blockIdx.x] = sd[255];
}

__global__ __launch_bounds__(256) void scan2_kernel(int* __restrict__ part, int nb) {
    __shared__ int sd[256];
    int t = threadIdx.x;
    int v = (t < nb) ? part[t] : 0;
    sd[t] = v; __syncthreads();
    #pragma unroll
    for (int o = 1; o < 256; o <<= 1) {
        int x = (t >= o) ? sd[t - o] : 0;
        __syncthreads();
        sd[t] += x;
        __syncthreads();
    }
    if (t < nb) part[t] = sd[t];
}

__global__ void scan3_kernel(const int* __restrict__ incl, const int* __restrict__ deg,
                             const int* __restrict__ part, int* __restrict__ row_ptr, int N) {
    int i = blockIdx.x * blockDim.x + threadIdx.x;
    if (i >= N) return;
    int off = (blockIdx.x > 0) ? part[blockIdx.x - 1] : 0;
    row_ptr[i] = incl[i] - deg[i] + off;
}

__global__ void fill_kernel(const int* __restrict__ ei, const int* __restrict__ row_ptr,
                            int* __restrict__ cur, int* __restrict__ csr_src, int E, int Et) {
    int e = blockIdx.x * blockDim.x + threadIdx.x;
    if (e >= Et) return;
    int s, d; edge_sd(ei, e, E, s, d);
    int pos = row_ptr[d] + atomicAdd(&cur[d], 1);
    csr_src[pos] = s;
}

// Max per-dst edges cached in LDS by the fused stats+aggr kernels; degrees above
// this fall back to on-the-fly alpha recompute (random graph max-deg ~40 << 256).
#define ACAP 256

// ==== block1: FUSED softmax-stats + gather-aggregate (all 4 heads) ==============
// wave0 computes per-dst max/sum (exp stash in LDS); both waves then gather.
__global__ __launch_bounds__(128) void aggr_b1_fused_kernel(const int* __restrict__ row_ptr,
                                                            const int* __restrict__ deg,
                                                            const int* __restrict__ csr_src,
                                                            const float* __restrict__ a_s,
                                                            const float* __restrict__ a_d,
                                                            const ushort* __restrict__ h1b,
                                                            ushort* __restrict__ accb) {
    __shared__ float alf[ACAP][4];
    __shared__ float sstat[8];     // mx[0..3], rd[4..7]
    int d = blockIdx.x, t = threadIdx.x;
    int base = row_ptr[d], dg = deg[d];
    float4 ad = *reinterpret_cast<const float4*>(&a_d[(size_t)d * 4]);
    if (t < 64) {
        float m0 = -1e30f, m1 = -1e30f, m2 = -1e30f, m3 = -1e30f;
        for (int j = t; j < dg; j += 64) {
            int s = csr_src[base + j];
            float4 sv = *reinterpret_cast<const float4*>(&a_s[(size_t)s * 4]);
            float c0 = sv.x + ad.x; c0 = c0 > 0.f ? c0 : 0.2f * c0; m0 = fmaxf(m0, c0);
            float c1 = sv.y + ad.y; c1 = c1 > 0.f ? c1 : 0.2f * c1; m1 = fmaxf(m1, c1);
            float c2 = sv.z + ad.z; c2 = c2 > 0.f ? c2 : 0.2f * c2; m2 = fmaxf(m2, c2);
            float c3 = sv.w + ad.w; c3 = c3 > 0.f ? c3 : 0.2f * c3; m3 = fmaxf(m3, c3);
        }
        m0 = wave_allreduce_max(m0); m1 = wave_allreduce_max(m1);
        m2 = wave_allreduce_max(m2); m3 = wave_allreduce_max(m3);
        float s0 = 0.f, s1 = 0.f, s2 = 0.f, s3 = 0.f;
        for (int j = t; j < dg; j += 64) {
            int s = csr_src[base + j];
            float4 sv = *reinterpret_cast<const float4*>(&a_s[(size_t)s * 4]);
            float c0 = sv.x + ad.x; c0 = c0 > 0.f ? c0 : 0.2f * c0; float e0 = __expf(c0 - m0); s0 += e0;
            float c1 = sv.y + ad.y; c1 = c1 > 0.f ? c1 : 0.2f * c1; float e1 = __expf(c1 - m1); s1 += e1;
            float c2 = sv.z + ad.z; c2 = c2 > 0.f ? c2 : 0.2f * c2; float e2 = __expf(c2 - m2); s2 += e2;
            float c3 = sv.w + ad.w; c3 = c3 > 0.f ? c3 : 0.2f * c3; float e3 = __expf(c3 - m3); s3 += e3;
            if (j < ACAP) { alf[j][0] = e0; alf[j][1] = e1; alf[j][2] = e2; alf[j][3] = e3; }
        }
        s0 = wave_allreduce_sum(s0); s1 = wave_allreduce_sum(s1);
        s2 = wave_allreduce_sum(s2); s3 = wave_allreduce_sum(s3);
        if (t == 0) {
            sstat[0] = m0; sstat[1] = m1; sstat[2] = m2; sstat[3] = m3;
            sstat[4] = 1.f / (s0 + 1e-16f); sstat[5] = 1.f / (s1 + 1e-16f);
            sstat[6] = 1.f / (s2 + 1e-16f); sstat[7] = 1.f / (s3 + 1e-16f);
        }
    }
    __syncthreads();
    float r0 = sstat[4], r1 = sstat[5], r2 = sstat[6], r3 = sstat[7];
    float a00 = 0, a01 = 0, a10 = 0, a11 = 0, a20 = 0, a21 = 0, a30 = 0, a31 = 0;
    for (int j = 0; j < dg; j++) {
        int s = csr_src[base + j];
        float al0, al1, al2, al3;
        if (j < ACAP) {
            al0 = alf[j][0] * r0; al1 = alf[j][1] * r1;
            al2 = alf[j][2] * r2; al3 = alf[j][3] * r3;
        } else {
            float4 sv = *reinterpret_cast<const float4*>(&a_s[(size_t)s * 4]);
            float c0 = sv.x + ad.x; c0 = c0 > 0.f ? c0 : 0.2f * c0; al0 = __expf(c0 - sstat[0]) * r0;
            float c1 = sv.y + ad.y; c1 = c1 > 0.f ? c1 : 0.2f * c1; al1 = __expf(c1 - sstat[1]) * r1;
            float c2 = sv.z + ad.z; c2 = c2 > 0.f ? c2 : 0.2f * c2; al2 = __expf(c2 - sstat[2]) * r2;
            float c3 = sv.w + ad.w; c3 = c3 > 0.f ? c3 : 0.2f * c3; al3 = __expf(c3 - sstat[3]) * r3;
        }
        unsigned v = reinterpret_cast<const unsigned*>(h1b + (size_t)s * 256)[t];
        float lo = b2f((ushort)(v & 0xffff)), hi = b2f((ushort)(v >> 16));
        a00 += al0 * lo; a01 += al0 * hi;
        a10 += al1 * lo; a11 += al1 * hi;
        a20 += al2 * lo; a21 += al2 * hi;
        a30 += al3 * lo; a31 += al3 * hi;
    }
    unsigned* o = reinterpret_cast<unsigned*>(accb + (size_t)d * 1024);
    o[t]       = pack2(a00, a01);
    o[t + 128] = pack2(a10, a11);
    o[t + 256] = pack2(a20, a21);
    o[t + 384] = pack2(a30, a31);
}

// ==== blocks 2/3: FUSED stats + gather-aggregate + elu/residual epilogue ========
// scores layout: src_h = as[s*2H+h], dst_h = as[d*2H+H+h].
// NOTE: outb must NOT alias g (gather source) — blocks read arbitrary g rows.
template<int H, int C, int F, int NT>
__global__ __launch_bounds__(NT) void aggr_comb_fused_kernel(const int* __restrict__ row_ptr,
                                                             const int* __restrict__ deg,
                                                             const int* __restrict__ csr_src,
                                                             const float* __restrict__ as,
                                                             const ushort* __restrict__ g,
                                                             const float* __restrict__ Rf,
                                                             const float* __restrict__ gb,
                                                             const float* __restrict__ rb,
                                                             ushort* __restrict__ outb) {
    __shared__ float alf[ACAP][H];
    __shared__ float sstat[2 * H];   // mx[0..H), rd[H..2H)
    int d = blockIdx.x;
    int t = threadIdx.x;               // 0..F/2-1
    int base = row_ptr[d], dg = deg[d];
    if (t < 64) {
        float ad[H], mx[H];
        #pragma unroll
        for (int h = 0; h < H; h++) { ad[h] = as[(size_t)d * 2 * H + H + h]; mx[h] = -1e30f; }
        for (int j = t; j < dg; j += 64) {
            int s = csr_src[base + j];
            #pragma unroll
            for (int h = 0; h < H; h++) {
                float c = as[(size_t)s * 2 * H + h] + ad[h];
                c = c > 0.f ? c : 0.2f * c;
                mx[h] = fmaxf(mx[h], c);
            }
        }
        #pragma unroll
        for (int h = 0; h < H; h++) mx[h] = wave_allreduce_max(mx[h]);
        float sm[H];
        #pragma unroll
        for (int h = 0; h < H; h++) sm[h] = 0.f;
        for (int j = t; j < dg; j += 64) {
            int s = csr_src[base + j];
            #pragma unroll
            for (int h = 0; h < H; h++) {
                float c = as[(size_t)s * 2 * H + h] + ad[h];
                c = c > 0.f ? c : 0.2f * c;
                float e = __expf(c - mx[h]);
                sm[h] += e;
                if (j < ACAP) alf[j][h] = e;
            }
        }
        #pragma unroll
        for (int h = 0; h < H; h++) sm[h] = wave_allreduce_sum(sm[h]);
        if (t == 0) {
            #pragma unroll
            for (int h = 0; h < H; h++) { sstat[h] = mx[h]; sstat[H + h] = 1.f / (sm[h] + 1e-16f); }
        }
    }
    __syncthreads();
    int hd = (2 * t) / C;
    float mxv = sstat[hd], rdv = sstat[H + hd];
    float adv = as[(size_t)d * 2 * H + H + hd];
    float lo = 0.f, hi = 0.f;
    for (int j = 0; j < dg; j++) {
        int s = csr_src[base + j];
        float al;
        if (j < ACAP) al = alf[j][hd] * rdv;
        else {
            float c = as[(size_t)s * 2 * H + hd] + adv;
            c = c > 0.f ? c : 0.2f * c;
            al = __expf(c - mxv) * rdv;
        }
        unsigned v = reinterpret_cast<const unsigned*>(g + (size_t)s * F)[t];
        lo += al * b2f((ushort)(v & 0xffff));
        hi += al * b2f((ushort)(v >> 16));
    }
    int c0 = 2 * t, c1 = 2 * t + 1;
    float o0 = lo + gb[c0]; o0 = o0 > 0.f ? o0 : (__expf(o0) - 1.f);
    float o1 = hi + gb[c1]; o1 = o1 > 0.f ? o1 : (__expf(o1) - 1.f);
    o0 += Rf[(size_t)d * F + c0] + rb[c0];
    o1 += Rf[(size_t)d * F + c1] + rb[c1];
    reinterpret_cast<unsigned*>(outb)[(size_t)d * (F / 2) + t] = pack2(o0, o1);
}

extern "C" void kernel_launch(void* const* d_in, const int* in_sizes, int n_in,
                              void* d_out, int out_size, void* d_ws, size_t ws_size,
                              hipStream_t stream) {
    const float* x        = (const float*)d_in[0];
    const int*   ei       = (const int*)d_in[1];
    const float* enc_w1   = (const float*)d_in[2];
    const float* enc_b1   = (const float*)d_in[3];
    const float* ln1_g    = (const float*)d_in[4];
    const float* ln1_b    = (const float*)d_in[5];
    const float* enc_w2   = (const float*)d_in[6];
    const float* enc_b2   = (const float*)d_in[7];
    const float* ln2_g    = (const float*)d_in[8];
    const float* ln2_b    = (const float*)d_in[9];
    const float* w1       = (const float*)d_in[10];
    const float* att_src1 = (const float*)d_in[11];
    const float* att_dst1 = (const float*)d_in[12];
    const float* bias1    = (const float*)d_in[13];
    const float* res1_w   = (const float*)d_in[14];
    const float* res1_b   = (const float*)d_in[15];
    const float* w2       = (const float*)d_in[16];
    const float* att_src2 = (const float*)d_in[17];
    const float* att_dst2 = (const float*)d_in[18];
    const float* bias2    = (const float*)d_in[19];
    const float* res2_w   = (const float*)d_in[20];
    const float* res2_b   = (const float*)d_in[21];
    const float* w3       = (const float*)d_in[22];
    const float* att_src3 = (const float*)d_in[23];
    const float* att_dst3 = (const float*)d_in[24];
    const float* bias3    = (const float*)d_in[25];
    const float* res3_w   = (const float*)d_in[26];
    const float* res3_b   = (const float*)d_in[27];
    const float* mlp_w1   = (const float*)d_in[28];
    const float* mlp_b1   = (const float*)d_in[29];
    const float* mlp_w2   = (const float*)d_in[30];
    const float* mlp_b2   = (const float*)d_in[31];

    const int N  = in_sizes[0] / 405;   // 50000
    const int E  = in_sizes[1] / 2;     // 300000
    const int Et = E + N;
    const int NB = (N + 255) / 256;

    // ---------- workspace layout (bytes) ----------
    char* p = (char*)d_ws;
    char* R0 = p;                       // N*896 B : xb(448 b16) | H3b(b16 192)
    char* R1 = R0 + (size_t)N * 896;    // N*512 B : h0b | G2b
    char* R2 = R1 + (size_t)N * 512;    // N*512 B : h1b | G3b , H4b(@+N*256B)
    char* R3 = R2 + (size_t)N * 512;    // N*2048 B: F1(f32 256) | H2b(b16 1024)
    char* R4 = R3 + (size_t)N * 2048;   // N*2048 B: accb(b16 1024) | Rf(f32 192/128)
    char* T  = R4 + (size_t)N * 2048;   // tail

    ushort* xb   = (ushort*)R0;
    ushort* H3b  = (ushort*)R0;          // lives after xb is dead (enc1 done)
    ushort* h0b  = (ushort*)R1;
    ushort* G2b  = (ushort*)R1;
    ushort* h1b  = (ushort*)R2;
    ushort* G3b  = (ushort*)R2;
    ushort* H4b  = (ushort*)(R2 + (size_t)N * 256);
    float*  F1   = (float*)R3;
    ushort* H2b  = (ushort*)R3;
    ushort* accb = (ushort*)R4;
    float*  Rf   = (float*)R4;

    float* a_s   = (float*)T;                         T += (size_t)N * 4 * 4;   // also Sf2/Sf3
    float* a_d   = (float*)T;                         T += (size_t)N * 4 * 4;
    float* qs    = (float*)T;                         T += 2048 * 4;
    float* qd    = (float*)T;                         T += 2048 * 4;
    int* deg     = (int*)T;                           T += (size_t)N * 4;
    int* cur     = (int*)T;                           T += (size_t)N * 4;
    int* row_ptr = (int*)T;                           T += (size_t)N * 4;
    int* incl    = (int*)T;                           T += (size_t)N * 4;
    int* part    = (int*)T;                           T += 256 * 4;
    int* csr_src = (int*)T;                           T += (size_t)Et * 4;
    ushort* enc_w1T = (ushort*)T;                     T += (size_t)256 * 448 * 2;
    ushort* enc_w2T = (ushort*)T;                     T += (size_t)256 * 256 * 2;
    ushort* w1T     = (ushort*)T;                     T += (size_t)1024 * 256 * 2;
    ushort* res1T   = (ushort*)T;                     T += (size_t)1024 * 256 * 2;
    ushort* Bcat2T  = (ushort*)T;                     T += (size_t)512 * 1024 * 2;
    ushort* Bcat3T  = (ushort*)T;                     T += (size_t)384 * 192 * 2;
    ushort* mlpw1T  = (ushort*)T;                     T += (size_t)128 * 128 * 2;

    auto cdiv = [](int a, int b) { return (a + b - 1) / b; };
    const int MB = cdiv(N, 128);

    // ---- CSR build ----
    hipMemsetAsync(deg, 0, (size_t)N * 8, stream);   // deg + cur
    deg_kernel<<<cdiv(Et, 256), 256, 0, stream>>>(ei, deg, E, Et);
    scan1_kernel<<<NB, 256, 0, stream>>>(deg, incl, part, N);
    scan2_kernel<<<1, 256, 0, stream>>>(part, NB);
    scan3_kernel<<<NB, 256, 0, stream>>>(incl, deg, part, row_ptr, N);
    fill_kernel<<<cdiv(Et, 256), 256, 0, stream>>>(ei, row_ptr, cur, csr_src, E, Et);

    // ---- weight prep: ONE launch ----
    prep_all_kernel<<<cdiv(1314432, 256), 256, 0, stream>>>(
        enc_w1, enc_w2, w1, res1_w, w2, res2_w, w3, res3_w, mlp_w1,
        enc_w1T, enc_w2T, w1T, res1T, Bcat2T, Bcat3T, mlpw1T);

    // block-1 att fold (needed by ln_relu_w<4>)
    fold_att_kernel<<<cdiv(4 * 256, 256), 256, 0, stream>>>(w1, att_src1, att_dst1, qs, qd, 256, 256, 4);

    // ---- JointEncoder ----
    conv_pad_x_kernel<<<cdiv(N * 448, 256), 256, 0, stream>>>(x, xb, N);
    bgemm<0><<<dim3(2, MB), 256, 0, stream>>>(xb, enc_w1T, enc_b1, F1, 256, nullptr, nullptr, 0, N, 256, 448, 448);
    ln_relu_w_kernel<0><<<1024, 256, 0, stream>>>(F1, ln1_g, ln1_b, nullptr, nullptr, h0b, nullptr, nullptr, N);
    bgemm<0><<<dim3(2, MB), 256, 0, stream>>>(h0b, enc_w2T, enc_b2, F1, 256, nullptr, nullptr, 0, N, 256, 256, 256);
    // LN2 + fused block-1 attention scores (fp32, wave-per-row)
    ln_relu_w_kernel<4><<<1024, 256, 0, stream>>>(F1, ln2_g, ln2_b, qs, qd, h1b, a_s, a_d, N);

    // ---- Block 1: GAT 256 -> 4x256 concat (fused stats+aggr, fused head GEMMs) --
    aggr_b1_fused_kernel<<<N, 128, 0, stream>>>(row_ptr, deg, csr_src, a_s, a_d, h1b, accb);
    bgemm_b1<<<dim3(8, MB), 256, 0, stream>>>(accb, w1T, h1b, res1T, bias1, res1_b, H2b, N);

    // ---- Block 2: GAT 1024 -> 2x96 concat (G/R/scores in one split-epilogue GEMM)
    {
        fold_att_b16_kernel<<<cdiv(2 * 1024, 256), 256, 0, stream>>>(w2, att_src2, att_dst2,
            Bcat2T + (size_t)384 * 1024, Bcat2T + (size_t)386 * 1024, 1024, 96, 2);
        // cols: [0,192)=G2b bf16, [192,384)=Rf fp32, [384,388)=scores -> a_s[N,4]
        bgemm<5><<<dim3(4, MB), 256, 0, stream>>>(H2b, Bcat2T, nullptr, G2b, 0, Rf, a_s, 192, N, 388, 1024, 1024);
        // H3b (R0) does NOT alias G2b (R1) -> fused gather+epilogue is safe
        aggr_comb_fused_kernel<2, 96, 192, 96><<<N, 96, 0, stream>>>(row_ptr, deg, csr_src, a_s,
                                                                     G2b, Rf, bias2, res2_b, H3b);
    }

    // ---- Block 3: GAT 192 -> 1x128 (no concat) ----
    {
        fold_att_b16_kernel<<<1, 256, 0, stream>>>(w3, att_src3, att_dst3,
            Bcat3T + (size_t)256 * 192, Bcat3T + (size_t)257 * 192, 192, 128, 1);
        // cols: [0,128)=G3b bf16, [128,256)=Rf fp32, [256,258)=scores -> a_s[N,2]
        bgemm<5><<<dim3(3, MB), 256, 0, stream>>>(H3b, Bcat3T, nullptr, G3b, 0, Rf, a_s, 128, N, 258, 192, 192);
        // H4b (R2 + N*256B) does NOT alias G3b (R2, N*256B) -> safe
        aggr_comb_fused_kernel<1, 128, 128, 64><<<N, 64, 0, stream>>>(row_ptr, deg, csr_src, a_s,
                                                                      G3b, Rf, bias3, res3_b, H4b);
    }

    // ---- MLP head: relu(H4b@mlp_w1+b1)@mlp_w2+b2 fused into ONE GEMM epilogue ---
    bgemm<4><<<dim3(1, MB), 256, 0, stream>>>(H4b, mlpw1T, mlp_b1, d_out, 2,
                                              (float*)mlp_w2, (float*)mlp_b2, 0, N, 64, 128, 128);
}

// Round 4
// 803.090 us; speedup vs baseline: 1.1483x; 1.0075x over previous
//
#include <hip/hip_runtime.h>
#include <cstddef>

#define LN_EPS 1e-5f

typedef __bf16 bf16x8 __attribute__((ext_vector_type(8)));
typedef float  f32x4  __attribute__((ext_vector_type(4)));

typedef __attribute__((address_space(3))) unsigned int lds_u32;
typedef __attribute__((address_space(1))) unsigned int glb_u32;

__device__ __forceinline__ void gl2lds16(const void* g, void* l) {
    // 16B per lane DMA: LDS dest = wave-uniform base + lane*16
    __builtin_amdgcn_global_load_lds((const glb_u32*)g, (lds_u32*)l, 16, 0, 0);
}

__device__ __forceinline__ float b2f(ushort h) {
    return __uint_as_float(((unsigned)h) << 16);
}
__device__ __forceinline__ ushort f2b(float f) {   // RNE
    unsigned u = __float_as_uint(f);
    return (ushort)((u + 0x7fffu + ((u >> 16) & 1u)) >> 16);
}
__device__ __forceinline__ unsigned pack2(float lo, float hi) {
    return (unsigned)f2b(lo) | ((unsigned)f2b(hi) << 16);
}
__device__ __forceinline__ uint2 pack4(const f32x4 v) {
    return make_uint2(pack2(v[0], v[1]), pack2(v[2], v[3]));
}

// XCD-aware remap: all gridDim.x col-blocks of one row-block land on one XCD.
__device__ __forceinline__ void xcd_map(int& bx, int& by) {
    int NX = gridDim.x, MBr = gridDim.y;
    int L = blockIdx.y * NX + blockIdx.x;
    int G = NX * 8;
    int g = L / G;
    if (g * 8 + 8 <= MBr) {
        int r = L - g * G;
        by = g * 8 + (r & 7);
        bx = r >> 3;
    } else {
        by = L / NX;
        bx = L - by * NX;
    }
}

__device__ __forceinline__ float wave_allreduce_max(float v) {
    #pragma unroll
    for (int off = 32; off > 0; off >>= 1) v = fmaxf(v, __shfl_xor(v, off, 64));
    return v;
}
__device__ __forceinline__ float wave_allreduce_sum(float v) {
    #pragma unroll
    for (int off = 32; off > 0; off >>= 1) v += __shfl_xor(v, off, 64);
    return v;
}

// ---- BM=256 x BN=128, BK=32, 8-wave (512 thr) MFMA K-loop, 2-buffer ------------
// Fat-step rationale: per-step sync overhead is ~constant; 256-row tiles halve
// total block-steps per GEMM vs the 128-row version (measured 17.5% MfmaUtil,
// lockstep-bound). Per-wave profile unchanged: acc[4][4], 8 ds_read, 16 MFMA.
// Staging: 3 gl2lds/thread/stage (A rows r and 128+r; B rows r), 16B lanes.
// XOR swizzle key is row-local ((row>>1)&3) -> identical formula both halves.
// SWAPPED operands: acc[i][j] = mfma(bf[j], af[i], acc) so that
//   C row = m0+wr+i*16+l15 ; C col = n0+wc+j*16+quad*4+reg
__device__ __forceinline__ void stage3(const ushort* a0, const ushort* a1, const ushort* b0,
                                       ushort* __restrict__ As, ushort* __restrict__ Bs,
                                       int lb) {
    gl2lds16(a0, As + lb);           // A rows 0..127 of tile
    gl2lds16(a1, As + lb + 4096);    // A rows 128..255
    gl2lds16(b0, Bs + lb);           // B rows 0..127
}

__device__ __forceinline__ void mfma_loop256(const ushort* aA0, const ushort* aA1,
                                             const ushort* aB0,
                                             ushort* __restrict__ As, ushort* __restrict__ Bs,
                                             int lb,
                                             int K, int wr, int wc, int cA, int l15,
                                             f32x4 acc[4][4]) {
    const int BUFA = 256 * 32;         // ushorts per A buffer
    const int BUFB = 128 * 32;         // ushorts per B buffer
    const int nk = K >> 5;
    stage3(aA0, aA1, aB0, As, Bs, lb);                    // S0 -> buf0
    int p = 0;
    for (int t = 0; t < nk; t++) {
        // Only this wave's own S(t) loads are outstanding here (S(t+1) is issued
        // after the wait); vmcnt(0) + barrier => buf_p fully staged block-wide.
        asm volatile("s_waitcnt vmcnt(0)" ::: "memory");
        __builtin_amdgcn_s_barrier();
        __builtin_amdgcn_sched_barrier(0);   // no ds_read may hoist above barrier
        int kn = (t + 1) * 32;
        if (kn < K) stage3(aA0 + kn, aA1 + kn, aB0 + kn,
                           As + (p ^ 1) * BUFA, Bs + (p ^ 1) * BUFB, lb);
        const ushort* Ac = As + p * BUFA;
        const ushort* Bc = Bs + p * BUFB;
        bf16x8 af[4], bf[4];
        #pragma unroll
        for (int i = 0; i < 4; i++)
            af[i] = *reinterpret_cast<const bf16x8*>(&Ac[(wr + i * 16 + l15) * 32 + cA]);
        #pragma unroll
        for (int j = 0; j < 4; j++)
            bf[j] = *reinterpret_cast<const bf16x8*>(&Bc[(wc + j * 16 + l15) * 32 + cA]);
        #pragma unroll
        for (int i = 0; i < 4; i++)
            #pragma unroll
            for (int j = 0; j < 4; j++)
                acc[i][j] = __builtin_amdgcn_mfma_f32_16x16x32_bf16(bf[j], af[i], acc[i][j], 0, 0, 0);
        p ^= 1;
    }
    __syncthreads();   // protect LDS reuse (phase 2 / epilogue)
}

// ============== bf16 MFMA GEMM: C = A[M,K]@B  (B given as BT[Npad,K] bf16) =======
// 512 threads, 8 waves as 4(M) x 2(N); per-wave 64x64 out; block tile 256x128.
// EPI 0: fp32 out = acc (+bias if non-null)        (full-col grids only)
// EPI 4: mlp head: v=relu(acc+bias) (cols 0..63); out[row,0:2]=v@Rf[64,2]+Sf[0:2]
// EPI 5: split: col<Fs -> bf16 out; col<2Fs -> fp32 Rf; else fp32 Sf (elem guard).
template<int EPI>
__global__ __launch_bounds__(512, 4) void bgemm(const ushort* __restrict__ A,
                                                const ushort* __restrict__ BT,
                                                const float* __restrict__ bias,
                                                void* __restrict__ out, int ldc,
                                                float* __restrict__ Rf,
                                                float* __restrict__ Sf, int Fs,
                                                int M, int Ncols, int K, int lda) {
    __shared__ ushort As[2][256 * 32];
    __shared__ ushort Bs[2][128 * 32];
    const int tid = threadIdx.x;
    int bx, by; xcd_map(bx, by);
    const int m0 = by * 256, n0 = bx * 128;
    const int w = tid >> 6, lane = tid & 63;
    const int wr = (w >> 1) * 64, wc = (w & 1) * 64;
    const int quad = lane >> 4, l15 = lane & 15;
    const int cA = (quad ^ ((l15 >> 1) & 3)) * 8;
    const int lb = w * 512;

    const int r = tid >> 2, g = ((tid & 3) ^ ((tid >> 3) & 3)) * 8;
    int ga0 = m0 + r;       if (ga0 >= M) ga0 = M - 1;
    int ga1 = m0 + 128 + r; if (ga1 >= M) ga1 = M - 1;
    const ushort* aA0 = A + (size_t)ga0 * lda + g;
    const ushort* aA1 = A + (size_t)ga1 * lda + g;
    const ushort* aB0 = BT + (size_t)(n0 + r) * K + g;

    f32x4 acc[4][4] = {};
    mfma_loop256(aA0, aA1, aB0, As[0], Bs[0], lb, K, wr, wc, cA, l15, acc);

    if (EPI == 4) {
        // cols 0..63 valid (B rows 64..127 are zero-padded); wc==64 waves idle.
        if (wc == 0) {
            #pragma unroll
            for (int i = 0; i < 4; i++) {
                float o0 = 0.f, o1 = 0.f;
                #pragma unroll
                for (int j = 0; j < 4; j++) {
                    int colbase = j * 16 + quad * 4;
                    float4 bv = *reinterpret_cast<const float4*>(&bias[colbase]);
                    float bb[4] = { bv.x, bv.y, bv.z, bv.w };
                    #pragma unroll
                    for (int rr = 0; rr < 4; rr++) {
                        float vv = fmaxf(acc[i][j][rr] + bb[rr], 0.f);
                        int c = colbase + rr;
                        o0 += vv * Rf[2 * c];
                        o1 += vv * Rf[2 * c + 1];
                    }
                }
                // reduce across the 4 quads holding the same row (lanes l15+16q)
                o0 += __shfl_xor(o0, 16, 64); o0 += __shfl_xor(o0, 32, 64);
                o1 += __shfl_xor(o1, 16, 64); o1 += __shfl_xor(o1, 32, 64);
                int row = m0 + wr + i * 16 + l15;
                if (quad == 0 && row < M) {
                    ((float*)out)[(size_t)row * 2]     = o0 + Sf[0];
                    ((float*)out)[(size_t)row * 2 + 1] = o1 + Sf[1];
                }
            }
        }
        return;
    }

    const int twoH = Ncols - 2 * Fs;
    #pragma unroll
    for (int i = 0; i < 4; i++) {
        int row = m0 + wr + i * 16 + l15;
        if (row >= M) continue;
        #pragma unroll
        for (int j = 0; j < 4; j++) {
            int colbase = n0 + wc + j * 16 + quad * 4;
            if (EPI == 0) {
                f32x4 v = acc[i][j];
                if (bias) {
                    float4 bv = *reinterpret_cast<const float4*>(&bias[colbase]);
                    v[0] += bv.x; v[1] += bv.y; v[2] += bv.z; v[3] += bv.w;
                }
                *reinterpret_cast<f32x4*>(&((float*)out)[(size_t)row * ldc + colbase]) = v;
            } else if (EPI == 5) {
                if (colbase + 3 < Fs) {
                    *reinterpret_cast<uint2*>(&((ushort*)out)[(size_t)row * Fs + colbase]) = pack4(acc[i][j]);
                } else if (colbase >= Fs && colbase + 3 < 2 * Fs) {
                    *reinterpret_cast<f32x4*>(&Rf[(size_t)row * Fs + (colbase - Fs)]) = acc[i][j];
                } else {
                    #pragma unroll
                    for (int rr = 0; rr < 4; rr++) {
                        int col = colbase + rr;
                        if (col < 2 * Fs || col >= Ncols) continue;
                        Sf[(size_t)row * twoH + (col - 2 * Fs)] = acc[i][j][rr];
                    }
                }
            }
        }
    }
}

// ===== fused block-1: H2 = elu(acc_h@W_h + bias1) + h1@res1_w + res1_b (bf16) ====
__global__ __launch_bounds__(512, 4) void bgemm_b1(const ushort* __restrict__ accb,  // N x 1024
                                                   const ushort* __restrict__ w1T,   // 1024 x 256
                                                   const ushort* __restrict__ h1b,   // N x 256
                                                   const ushort* __restrict__ res1T, // 1024 x 256
                                                   const float* __restrict__ bias1,
                                                   const float* __restrict__ res1b,
                                                   ushort* __restrict__ H2b, int M) {
    __shared__ ushort As[2][256 * 32];
    __shared__ ushort Bs[2][128 * 32];
    const int tid = threadIdx.x;
    int bx, by; xcd_map(bx, by);
    const int m0 = by * 256, n0 = bx * 128;
    const int h = n0 >> 8;
    const int w = tid >> 6, lane = tid & 63;
    const int wr = (w >> 1) * 64, wc = (w & 1) * 64;
    const int quad = lane >> 4, l15 = lane & 15;
    const int cA = (quad ^ ((l15 >> 1) & 3)) * 8;
    const int lb = w * 512;

    const int r = tid >> 2, g = ((tid & 3) ^ ((tid >> 3) & 3)) * 8;
    int ga0 = m0 + r;       if (ga0 >= M) ga0 = M - 1;
    int ga1 = m0 + 128 + r; if (ga1 >= M) ga1 = M - 1;

    f32x4 acc[4][4] = {};

    // phase 1: acc_h @ W_h
    mfma_loop256(accb + (size_t)ga0 * 1024 + h * 256 + g,
                 accb + (size_t)ga1 * 1024 + h * 256 + g,
                 w1T + (size_t)(n0 + r) * 256 + g,
                 As[0], Bs[0], lb, 256, wr, wc, cA, l15, acc);

    // in-register: acc = elu(acc + bias1) + res1_b
    #pragma unroll
    for (int i = 0; i < 4; i++) {
        #pragma unroll
        for (int j = 0; j < 4; j++) {
            int colbase = n0 + wc + j * 16 + quad * 4;
            float4 bv = *reinterpret_cast<const float4*>(&bias1[colbase]);
            float4 rv = *reinterpret_cast<const float4*>(&res1b[colbase]);
            float bb[4] = { bv.x, bv.y, bv.z, bv.w };
            float rr[4] = { rv.x, rv.y, rv.z, rv.w };
            #pragma unroll
            for (int q = 0; q < 4; q++) {
                float t = acc[i][j][q] + bb[q];
                t = t > 0.f ? t : (__expf(t) - 1.f);
                acc[i][j][q] = t + rr[q];
            }
        }
    }

    // phase 2: += h1 @ res1_w
    mfma_loop256(h1b + (size_t)ga0 * 256 + g,
                 h1b + (size_t)ga1 * 256 + g,
                 res1T + (size_t)(n0 + r) * 256 + g,
                 As[0], Bs[0], lb, 256, wr, wc, cA, l15, acc);

    #pragma unroll
    for (int i = 0; i < 4; i++) {
        int row = m0 + wr + i * 16 + l15;
        if (row >= M) continue;
        #pragma unroll
        for (int j = 0; j < 4; j++) {
            int colbase = n0 + wc + j * 16 + quad * 4;
            *reinterpret_cast<uint2*>(&H2b[(size_t)row * 1024 + colbase]) = pack4(acc[i][j]);
        }
    }
}

// ---------------- conversions / weight prep ----------------
__global__ void conv_pad_x_kernel(const float* __restrict__ x, ushort* __restrict__ xb, int N) {
    int t = blockIdx.x * 256 + threadIdx.x;
    if (t >= N * 448) return;
    int n = t / 448, k = t - n * 448;
    xb[t] = f2b(k < 405 ? x[(size_t)n * 405 + k] : 0.f);
}

// ---- ALL weight preps in ONE launch (bf16 transpose+pad, segment table) ----
__device__ __forceinline__ void prep_seg(int t, const float* src, ushort* dst,
                                         int K, int Nreal, int Kpad, int ldsrc) {
    int n = t / Kpad, k = t - n * Kpad;
    float v = (k < K && n < Nreal) ? src[(size_t)k * ldsrc + n] : 0.f;
    dst[t] = f2b(v);
}

__global__ void prep_all_kernel(const float* __restrict__ enc_w1, const float* __restrict__ enc_w2,
                                const float* __restrict__ w1, const float* __restrict__ res1_w,
                                const float* __restrict__ w2, const float* __restrict__ res2_w,
                                const float* __restrict__ w3, const float* __restrict__ res3_w,
                                const float* __restrict__ mlp_w1,
                                ushort* __restrict__ enc_w1T, ushort* __restrict__ enc_w2T,
                                ushort* __restrict__ w1T, ushort* __restrict__ res1T,
                                ushort* __restrict__ Bcat2T, ushort* __restrict__ Bcat3T,
                                ushort* __restrict__ mlpw1T) {
    int t = blockIdx.x * 256 + threadIdx.x;
    // cumulative boundaries
    const int c0 = 114688;            // enc_w1T 256x448
    const int c1 = c0 + 65536;        // enc_w2T 256x256
    const int c2 = c1 + 262144;       // w1T 1024x256
    const int c3 = c2 + 262144;       // res1T 1024x256
    const int c4 = c3 + 196608;       // Bcat2T rows 0-191 (w2)
    const int c5 = c4 + 196608;       // Bcat2T rows 192-383 (res2)
    const int c6 = c5 + 126976;       // Bcat2T rows 388-511 zero
    const int c7 = c6 + 24576;        // Bcat3T rows 0-127 (w3)
    const int c8 = c7 + 24576;        // Bcat3T rows 128-255 (res3)
    const int c9 = c8 + 24192;        // Bcat3T rows 258-383 zero
    const int c10 = c9 + 16384;       // mlpw1T 128x128
    if (t < c0)      prep_seg(t,        enc_w1, enc_w1T, 405, 256, 448, 256);
    else if (t < c1) prep_seg(t - c0,   enc_w2, enc_w2T, 256, 256, 256, 256);
    else if (t < c2) prep_seg(t - c1,   w1,     w1T,     256, 1024, 256, 1024);
    else if (t < c3) prep_seg(t - c2,   res1_w, res1T,   256, 1024, 256, 1024);
    else if (t < c4) prep_seg(t - c3,   w2,     Bcat2T,  1024, 192, 1024, 192);
    else if (t < c5) prep_seg(t - c4,   res2_w, Bcat2T + (size_t)192 * 1024, 1024, 192, 1024, 192);
    else if (t < c6) Bcat2T[(size_t)388 * 1024 + (t - c5)] = 0;
    else if (t < c7) prep_seg(t - c6,   w3,     Bcat3T,  192, 128, 192, 128);
    else if (t < c8) prep_seg(t - c7,   res3_w, Bcat3T + (size_t)128 * 192, 192, 128, 192, 128);
    else if (t < c9) Bcat3T[(size_t)258 * 192 + (t - c8)] = 0;
    else if (t < c10) prep_seg(t - c9,  mlp_w1, mlpw1T,  128, 64, 128, 64);
}

// ------- LayerNorm(+ReLU), WAVE-PER-ROW: fp32 in, bf16 out; C == 256 -----------
// One 64-lane wave owns a row: f32x4/lane, single-pass sum+sumsq butterfly,
// no __syncthreads, no LDS. H>0 additionally computes block-1 attention scores
// (qs/qd hoisted to registers once per wave, 8 in-lane dots + 8-value butterfly).
template<int H>
__global__ __launch_bounds__(256) void ln_relu_w_kernel(const float* __restrict__ x,
                                                        const float* __restrict__ g,
                                                        const float* __restrict__ b,
                                                        const float* __restrict__ qs,
                                                        const float* __restrict__ qd,
                                                        ushort* __restrict__ out,
                                                        float* __restrict__ a_s,
                                                        float* __restrict__ a_d,
                                                        int N) {
    const int lane = threadIdx.x & 63;
    int wid = blockIdx.x * 4 + (threadIdx.x >> 6);
    const int nw = gridDim.x * 4;
    const int c4 = lane * 4;

    f32x4 gv = *reinterpret_cast<const f32x4*>(&g[c4]);
    f32x4 bv = *reinterpret_cast<const f32x4*>(&b[c4]);
    f32x4 qsv[H > 0 ? H : 1], qdv[H > 0 ? H : 1];
    if (H > 0) {
        #pragma unroll
        for (int hh = 0; hh < H; hh++) {
            qsv[hh] = *reinterpret_cast<const f32x4*>(&qs[hh * 256 + c4]);
            qdv[hh] = *reinterpret_cast<const f32x4*>(&qd[hh * 256 + c4]);
        }
    }

    for (int row = wid; row < N; row += nw) {
        f32x4 v = *reinterpret_cast<const f32x4*>(&x[(size_t)row * 256 + c4]);
        float s  = v[0] + v[1] + v[2] + v[3];
        float s2 = v[0] * v[0] + v[1] * v[1] + v[2] * v[2] + v[3] * v[3];
        #pragma unroll
        for (int off = 32; off > 0; off >>= 1) {
            s  += __shfl_xor(s,  off, 64);
            s2 += __shfl_xor(s2, off, 64);
        }
        float m   = s * (1.f / 256.f);
        float var = s2 * (1.f / 256.f) - m * m;
        float rs  = rsqrtf(var + LN_EPS);
        f32x4 o;
        #pragma unroll
        for (int k = 0; k < 4; k++) o[k] = fmaxf((v[k] - m) * rs * gv[k] + bv[k], 0.f);
        *reinterpret_cast<uint2*>(&out[(size_t)row * 256 + c4]) =
            make_uint2(pack2(o[0], o[1]), pack2(o[2], o[3]));
        if (H > 0) {
            float sc[H > 0 ? 2 * H : 1];
            #pragma unroll
            for (int hh = 0; hh < H; hh++) {
                sc[hh]     = o[0] * qsv[hh][0] + o[1] * qsv[hh][1] + o[2] * qsv[hh][2] + o[3] * qsv[hh][3];
                sc[H + hh] = o[0] * qdv[hh][0] + o[1] * qdv[hh][1] + o[2] * qdv[hh][2] + o[3] * qdv[hh][3];
            }
            #pragma unroll
            for (int off = 32; off > 0; off >>= 1)
                #pragma unroll
                for (int k = 0; k < 2 * H; k++) sc[k] += __shfl_xor(sc[k], off, 64);
            if (lane == 0) {
                #pragma unroll
                for (int k = 0; k < H; k++) a_s[(size_t)row * H + k] = sc[k];
            } else if (lane == 1) {
                #pragma unroll
                for (int k = 0; k < H; k++) a_d[(size_t)row * H + k] = sc[H + k];
            }
        }
    }
}

// ---- fold attention vectors through W (fp32 out, block1) ----
__global__ void fold_att_kernel(const float* __restrict__ W,
                                const float* __restrict__ att_s,
                                const float* __restrict__ att_d,
                                float* __restrict__ qs, float* __restrict__ qd,
                                int Cin, int Cout, int H) {
    int t = blockIdx.x * blockDim.x + threadIdx.x;
    if (t >= H * Cin) return;
    int h = t / Cin, k = t - h * Cin;
    const float* wrow = W + (size_t)k * (H * Cout) + (size_t)h * Cout;
    const float* as = att_s + (size_t)h * Cout;
    const float* ad = att_d + (size_t)h * Cout;
    float ss = 0.f, sd = 0.f;
    for (int c = 0; c < Cout; c++) { float wv = wrow[c]; ss += wv * as[c]; sd += wv * ad[c]; }
    qs[t] = ss;
    qd[t] = sd;
}

// ---- fold attention vectors through W, bf16 out (blocks 2/3 -> Bcat rows) ----
__global__ void fold_att_b16_kernel(const float* __restrict__ W,
                                    const float* __restrict__ att_s,
                                    const float* __restrict__ att_d,
                                    ushort* __restrict__ qs_b, ushort* __restrict__ qd_b,
                                    int Cin, int Cout, int H) {
    int t = blockIdx.x * blockDim.x + threadIdx.x;
    if (t >= H * Cin) return;
    int h = t / Cin, k = t - h * Cin;
    const float* wrow = W + (size_t)k * (H * Cout) + (size_t)h * Cout;
    const float* as = att_s + (size_t)h * Cout;
    const float* ad = att_d + (size_t)h * Cout;
    float ss = 0.f, sd = 0.f;
    for (int c = 0; c < Cout; c++) { float wv = wrow[c]; ss += wv * as[c]; sd += wv * ad[c]; }
    qs_b[t] = f2b(ss);
    qd_b[t] = f2b(sd);
}

// ================= CSR construction (dst-grouped) =========
__device__ __forceinline__ void edge_sd(const int* ei, int e, int E, int& s, int& d) {
    if (e < E) { s = ei[e]; d = ei[E + e]; } else { s = d = e - E; }
}

__global__ void deg_kernel(const int* __restrict__ ei, int* __restrict__ deg, int E, int Et) {
    int e = blockIdx.x * blockDim.x + threadIdx.x;
    if (e >= Et) return;
    int s, d; edge_sd(ei, e, E, s, d);
    atomicAdd(&deg[d], 1);
}

__global__ __launch_bounds__(256) void scan1_kernel(const int* __restrict__ deg,
                                                    int* __restrict__ incl,
                                                    int* __restrict__ part, int N) {
    __shared__ int sd[256];
    int t = threadIdx.x;
    int i = blockIdx.x * 256 + t;
    int v = (i < N) ? deg[i] : 0;
    sd[t] = v; __syncthreads();
    #pragma unroll
    for (int o = 1; o < 256; o <<= 1) {
        int x = (t >= o) ? sd[t - o] : 0;
        __syncthreads();
        sd[t] += x;
        __syncthreads();
    }
    if (i < N) incl[i] = sd[t];
    if (t == 255) part[blockIdx.x] = sd[255];
}

__global__ __launch_bounds__(256) void scan2_kernel(int* __restrict__ part, int nb) {
    __shared__ int sd[256];
    int t = threadIdx.x;
    int v = (t < nb) ? part[t] : 0;
    sd[t] = v; __syncthreads();
    #pragma unroll
    for (int o = 1; o < 256; o <<= 1) {
        int x = (t >= o) ? sd[t - o] : 0;
        __syncthreads();
        sd[t] += x;
        __syncthreads();
    }
    if (t < nb) part[t] = sd[t];
}

__global__ void scan3_kernel(const int* __restrict__ incl, const int* __restrict__ deg,
                             const int* __restrict__ part, int* __restrict__ row_ptr, int N) {
    int i = blockIdx.x * blockDim.x + threadIdx.x;
    if (i >= N) return;
    int off = (blockIdx.x > 0) ? part[blockIdx.x - 1] : 0;
    row_ptr[i] = incl[i] - deg[i] + off;
}

__global__ void fill_kernel(const int* __restrict__ ei, const int* __restrict__ row_ptr,
                            int* __restrict__ cur, int* __restrict__ csr_src, int E, int Et) {
    int e = blockIdx.x * blockDim.x + threadIdx.x;
    if (e >= Et) return;
    int s, d; edge_sd(ei, e, E, s, d);
    int pos = row_ptr[d] + atomicAdd(&cur[d], 1);
    csr_src[pos] = s;
}

// Max per-dst edges cached in LDS by the fused stats+aggr kernels; degrees above
// this fall back to on-the-fly alpha recompute (random graph max-deg ~40 << 256).
#define ACAP 256

// ==== block1: FUSED softmax-stats + gather-aggregate (all 4 heads) ==============
// wave0 computes per-dst max/sum (exp stash in LDS); both waves then gather.
__global__ __launch_bounds__(128) void aggr_b1_fused_kernel(const int* __restrict__ row_ptr,
                                                            const int* __restrict__ deg,
                                                            const int* __restrict__ csr_src,
                                                            const float* __restrict__ a_s,
                                                            const float* __restrict__ a_d,
                                                            const ushort* __restrict__ h1b,
                                                            ushort* __restrict__ accb) {
    __shared__ float alf[ACAP][4];
    __shared__ float sstat[8];     // mx[0..3], rd[4..7]
    int d = blockIdx.x, t = threadIdx.x;
    int base = row_ptr[d], dg = deg[d];
    float4 ad = *reinterpret_cast<const float4*>(&a_d[(size_t)d * 4]);
    if (t < 64) {
        float m0 = -1e30f, m1 = -1e30f, m2 = -1e30f, m3 = -1e30f;
        for (int j = t; j < dg; j += 64) {
            int s = csr_src[base + j];
            float4 sv = *reinterpret_cast<const float4*>(&a_s[(size_t)s * 4]);
            float c0 = sv.x + ad.x; c0 = c0 > 0.f ? c0 : 0.2f * c0; m0 = fmaxf(m0, c0);
            float c1 = sv.y + ad.y; c1 = c1 > 0.f ? c1 : 0.2f * c1; m1 = fmaxf(m1, c1);
            float c2 = sv.z + ad.z; c2 = c2 > 0.f ? c2 : 0.2f * c2; m2 = fmaxf(m2, c2);
            float c3 = sv.w + ad.w; c3 = c3 > 0.f ? c3 : 0.2f * c3; m3 = fmaxf(m3, c3);
        }
        m0 = wave_allreduce_max(m0); m1 = wave_allreduce_max(m1);
        m2 = wave_allreduce_max(m2); m3 = wave_allreduce_max(m3);
        float s0 = 0.f, s1 = 0.f, s2 = 0.f, s3 = 0.f;
        for (int j = t; j < dg; j += 64) {
            int s = csr_src[base + j];
            float4 sv = *reinterpret_cast<const float4*>(&a_s[(size_t)s * 4]);
            float c0 = sv.x + ad.x; c0 = c0 > 0.f ? c0 : 0.2f * c0; float e0 = __expf(c0 - m0); s0 += e0;
            float c1 = sv.y + ad.y; c1 = c1 > 0.f ? c1 : 0.2f * c1; float e1 = __expf(c1 - m1); s1 += e1;
            float c2 = sv.z + ad.z; c2 = c2 > 0.f ? c2 : 0.2f * c2; float e2 = __expf(c2 - m2); s2 += e2;
            float c3 = sv.w + ad.w; c3 = c3 > 0.f ? c3 : 0.2f * c3; float e3 = __expf(c3 - m3); s3 += e3;
            if (j < ACAP) { alf[j][0] = e0; alf[j][1] = e1; alf[j][2] = e2; alf[j][3] = e3; }
        }
        s0 = wave_allreduce_sum(s0); s1 = wave_allreduce_sum(s1);
        s2 = wave_allreduce_sum(s2); s3 = wave_allreduce_sum(s3);
        if (t == 0) {
            sstat[0] = m0; sstat[1] = m1; sstat[2] = m2; sstat[3] = m3;
            sstat[4] = 1.f / (s0 + 1e-16f); sstat[5] = 1.f / (s1 + 1e-16f);
            sstat[6] = 1.f / (s2 + 1e-16f); sstat[7] = 1.f / (s3 + 1e-16f);
        }
    }
    __syncthreads();
    float r0 = sstat[4], r1 = sstat[5], r2 = sstat[6], r3 = sstat[7];
    float a00 = 0, a01 = 0, a10 = 0, a11 = 0, a20 = 0, a21 = 0, a30 = 0, a31 = 0;
    for (int j = 0; j < dg; j++) {
        int s = csr_src[base + j];
        float al0, al1, al2, al3;
        if (j < ACAP) {
            al0 = alf[j][0] * r0; al1 = alf[j][1] * r1;
            al2 = alf[j][2] * r2; al3 = alf[j][3] * r3;
        } else {
            float4 sv = *reinterpret_cast<const float4*>(&a_s[(size_t)s * 4]);
            float c0 = sv.x + ad.x; c0 = c0 > 0.f ? c0 : 0.2f * c0; al0 = __expf(c0 - sstat[0]) * r0;
            float c1 = sv.y + ad.y; c1 = c1 > 0.f ? c1 : 0.2f * c1; al1 = __expf(c1 - sstat[1]) * r1;
            float c2 = sv.z + ad.z; c2 = c2 > 0.f ? c2 : 0.2f * c2; al2 = __expf(c2 - sstat[2]) * r2;
            float c3 = sv.w + ad.w; c3 = c3 > 0.f ? c3 : 0.2f * c3; al3 = __expf(c3 - sstat[3]) * r3;
        }
        unsigned v = reinterpret_cast<const unsigned*>(h1b + (size_t)s * 256)[t];
        float lo = b2f((ushort)(v & 0xffff)), hi = b2f((ushort)(v >> 16));
        a00 += al0 * lo; a01 += al0 * hi;
        a10 += al1 * lo; a11 += al1 * hi;
        a20 += al2 * lo; a21 += al2 * hi;
        a30 += al3 * lo; a31 += al3 * hi;
    }
    unsigned* o = reinterpret_cast<unsigned*>(accb + (size_t)d * 1024);
    o[t]       = pack2(a00, a01);
    o[t + 128] = pack2(a10, a11);
    o[t + 256] = pack2(a20, a21);
    o[t + 384] = pack2(a30, a31);
}

// ==== blocks 2/3: FUSED stats + gather-aggregate + elu/residual epilogue ========
// scores layout: src_h = as[s*2H+h], dst_h = as[d*2H+H+h].
// NOTE: outb must NOT alias g (gather source) — blocks read arbitrary g rows.
template<int H, int C, int F, int NT>
__global__ __launch_bounds__(NT) void aggr_comb_fused_kernel(const int* __restrict__ row_ptr,
                                                             const int* __restrict__ deg,
                                                             const int* __restrict__ csr_src,
                                                             const float* __restrict__ as,
                                                             const ushort* __restrict__ g,
                                                             const float* __restrict__ Rf,
                                                             const float* __restrict__ gb,
                                                             const float* __restrict__ rb,
                                                             ushort* __restrict__ outb) {
    __shared__ float alf[ACAP][H];
    __shared__ float sstat[2 * H];   // mx[0..H), rd[H..2H)
    int d = blockIdx.x;
    int t = threadIdx.x;               // 0..F/2-1
    int base = row_ptr[d], dg = deg[d];
    if (t < 64) {
        float ad[H], mx[H];
        #pragma unroll
        for (int h = 0; h < H; h++) { ad[h] = as[(size_t)d * 2 * H + H + h]; mx[h] = -1e30f; }
        for (int j = t; j < dg; j += 64) {
            int s = csr_src[base + j];
            #pragma unroll
            for (int h = 0; h < H; h++) {
                float c = as[(size_t)s * 2 * H + h] + ad[h];
                c = c > 0.f ? c : 0.2f * c;
                mx[h] = fmaxf(mx[h], c);
            }
        }
        #pragma unroll
        for (int h = 0; h < H; h++) mx[h] = wave_allreduce_max(mx[h]);
        float sm[H];
        #pragma unroll
        for (int h = 0; h < H; h++) sm[h] = 0.f;
        for (int j = t; j < dg; j += 64) {
            int s = csr_src[base + j];
            #pragma unroll
            for (int h = 0; h < H; h++) {
                float c = as[(size_t)s * 2 * H + h] + ad[h];
                c = c > 0.f ? c : 0.2f * c;
                float e = __expf(c - mx[h]);
                sm[h] += e;
                if (j < ACAP) alf[j][h] = e;
            }
        }
        #pragma unroll
        for (int h = 0; h < H; h++) sm[h] = wave_allreduce_sum(sm[h]);
        if (t == 0) {
            #pragma unroll
            for (int h = 0; h < H; h++) { sstat[h] = mx[h]; sstat[H + h] = 1.f / (sm[h] + 1e-16f); }
        }
    }
    __syncthreads();
    int hd = (2 * t) / C;
    float mxv = sstat[hd], rdv = sstat[H + hd];
    float adv = as[(size_t)d * 2 * H + H + hd];
    float lo = 0.f, hi = 0.f;
    for (int j = 0; j < dg; j++) {
        int s = csr_src[base + j];
        float al;
        if (j < ACAP) al = alf[j][hd] * rdv;
        else {
            float c = as[(size_t)s * 2 * H + hd] + adv;
            c = c > 0.f ? c : 0.2f * c;
            al = __expf(c - mxv) * rdv;
        }
        unsigned v = reinterpret_cast<const unsigned*>(g + (size_t)s * F)[t];
        lo += al * b2f((ushort)(v & 0xffff));
        hi += al * b2f((ushort)(v >> 16));
    }
    int c0 = 2 * t, c1 = 2 * t + 1;
    float o0 = lo + gb[c0]; o0 = o0 > 0.f ? o0 : (__expf(o0) - 1.f);
    float o1 = hi + gb[c1]; o1 = o1 > 0.f ? o1 : (__expf(o1) - 1.f);
    o0 += Rf[(size_t)d * F + c0] + rb[c0];
    o1 += Rf[(size_t)d * F + c1] + rb[c1];
    reinterpret_cast<unsigned*>(outb)[(size_t)d * (F / 2) + t] = pack2(o0, o1);
}

extern "C" void kernel_launch(void* const* d_in, const int* in_sizes, int n_in,
                              void* d_out, int out_size, void* d_ws, size_t ws_size,
                              hipStream_t stream) {
    const float* x        = (const float*)d_in[0];
    const int*   ei       = (const int*)d_in[1];
    const float* enc_w1   = (const float*)d_in[2];
    const float* enc_b1   = (const float*)d_in[3];
    const float* ln1_g    = (const float*)d_in[4];
    const float* ln1_b    = (const float*)d_in[5];
    const float* enc_w2   = (const float*)d_in[6];
    const float* enc_b2   = (const float*)d_in[7];
    const float* ln2_g    = (const float*)d_in[8];
    const float* ln2_b    = (const float*)d_in[9];
    const float* w1       = (const float*)d_in[10];
    const float* att_src1 = (const float*)d_in[11];
    const float* att_dst1 = (const float*)d_in[12];
    const float* bias1    = (const float*)d_in[13];
    const float* res1_w   = (const float*)d_in[14];
    const float* res1_b   = (const float*)d_in[15];
    const float* w2       = (const float*)d_in[16];
    const float* att_src2 = (const float*)d_in[17];
    const float* att_dst2 = (const float*)d_in[18];
    const float* bias2    = (const float*)d_in[19];
    const float* res2_b_  = (const float*)d_in[21];
    const float* res2_w   = (const float*)d_in[20];
    const float* w3       = (const float*)d_in[22];
    const float* att_src3 = (const float*)d_in[23];
    const float* att_dst3 = (const float*)d_in[24];
    const float* bias3    = (const float*)d_in[25];
    const float* res3_w   = (const float*)d_in[26];
    const float* res3_b   = (const float*)d_in[27];
    const float* mlp_w1   = (const float*)d_in[28];
    const float* mlp_b1   = (const float*)d_in[29];
    const float* mlp_w2   = (const float*)d_in[30];
    const float* mlp_b2   = (const float*)d_in[31];
    const float* res2_b   = res2_b_;

    const int N  = in_sizes[0] / 405;   // 50000
    const int E  = in_sizes[1] / 2;     // 300000
    const int Et = E + N;
    const int NB = (N + 255) / 256;

    // ---------- workspace layout (bytes) ----------
    char* p = (char*)d_ws;
    char* R0 = p;                       // N*896 B : xb(448 b16) | H3b(b16 192)
    char* R1 = R0 + (size_t)N * 896;    // N*512 B : h0b | G2b
    char* R2 = R1 + (size_t)N * 512;    // N*512 B : h1b | G3b , H4b(@+N*256B)
    char* R3 = R2 + (size_t)N * 512;    // N*2048 B: F1(f32 256) | H2b(b16 1024)
    char* R4 = R3 + (size_t)N * 2048;   // N*2048 B: accb(b16 1024) | Rf(f32 192/128)
    char* T  = R4 + (size_t)N * 2048;   // tail

    ushort* xb   = (ushort*)R0;
    ushort* H3b  = (ushort*)R0;          // lives after xb is dead (enc1 done)
    ushort* h0b  = (ushort*)R1;
    ushort* G2b  = (ushort*)R1;
    ushort* h1b  = (ushort*)R2;
    ushort* G3b  = (ushort*)R2;
    ushort* H4b  = (ushort*)(R2 + (size_t)N * 256);
    float*  F1   = (float*)R3;
    ushort* H2b  = (ushort*)R3;
    ushort* accb = (ushort*)R4;
    float*  Rf   = (float*)R4;

    float* a_s   = (float*)T;                         T += (size_t)N * 4 * 4;   // also Sf2/Sf3
    float* a_d   = (float*)T;                         T += (size_t)N * 4 * 4;
    float* qs    = (float*)T;                         T += 2048 * 4;
    float* qd    = (float*)T;                         T += 2048 * 4;
    int* deg     = (int*)T;                           T += (size_t)N * 4;
    int* cur     = (int*)T;                           T += (size_t)N * 4;
    int* row_ptr = (int*)T;                           T += (size_t)N * 4;
    int* incl    = (int*)T;                           T += (size_t)N * 4;
    int* part    = (int*)T;                           T += 256 * 4;
    int* csr_src = (int*)T;                           T += (size_t)Et * 4;
    ushort* enc_w1T = (ushort*)T;                     T += (size_t)256 * 448 * 2;
    ushort* enc_w2T = (ushort*)T;                     T += (size_t)256 * 256 * 2;
    ushort* w1T     = (ushort*)T;                     T += (size_t)1024 * 256 * 2;
    ushort* res1T   = (ushort*)T;                     T += (size_t)1024 * 256 * 2;
    ushort* Bcat2T  = (ushort*)T;                     T += (size_t)512 * 1024 * 2;
    ushort* Bcat3T  = (ushort*)T;                     T += (size_t)384 * 192 * 2;
    ushort* mlpw1T  = (ushort*)T;                     T += (size_t)128 * 128 * 2;

    auto cdiv = [](int a, int b) { return (a + b - 1) / b; };
    const int MBr = cdiv(N, 256);      // 256-row blocks for all MFMA GEMMs

    // ---- CSR build ----
    hipMemsetAsync(deg, 0, (size_t)N * 8, stream);   // deg + cur
    deg_kernel<<<cdiv(Et, 256), 256, 0, stream>>>(ei, deg, E, Et);
    scan1_kernel<<<NB, 256, 0, stream>>>(deg, incl, part, N);
    scan2_kernel<<<1, 256, 0, stream>>>(part, NB);
    scan3_kernel<<<NB, 256, 0, stream>>>(incl, deg, part, row_ptr, N);
    fill_kernel<<<cdiv(Et, 256), 256, 0, stream>>>(ei, row_ptr, cur, csr_src, E, Et);

    // ---- weight prep: ONE launch ----
    prep_all_kernel<<<cdiv(1314432, 256), 256, 0, stream>>>(
        enc_w1, enc_w2, w1, res1_w, w2, res2_w, w3, res3_w, mlp_w1,
        enc_w1T, enc_w2T, w1T, res1T, Bcat2T, Bcat3T, mlpw1T);

    // block-1 att fold (needed by ln_relu_w<4>)
    fold_att_kernel<<<cdiv(4 * 256, 256), 256, 0, stream>>>(w1, att_src1, att_dst1, qs, qd, 256, 256, 4);

    // ---- JointEncoder ----
    conv_pad_x_kernel<<<cdiv(N * 448, 256), 256, 0, stream>>>(x, xb, N);
    bgemm<0><<<dim3(2, MBr), 512, 0, stream>>>(xb, enc_w1T, enc_b1, F1, 256, nullptr, nullptr, 0, N, 256, 448, 448);
    ln_relu_w_kernel<0><<<1024, 256, 0, stream>>>(F1, ln1_g, ln1_b, nullptr, nullptr, h0b, nullptr, nullptr, N);
    bgemm<0><<<dim3(2, MBr), 512, 0, stream>>>(h0b, enc_w2T, enc_b2, F1, 256, nullptr, nullptr, 0, N, 256, 256, 256);
    // LN2 + fused block-1 attention scores (fp32, wave-per-row)
    ln_relu_w_kernel<4><<<1024, 256, 0, stream>>>(F1, ln2_g, ln2_b, qs, qd, h1b, a_s, a_d, N);

    // ---- Block 1: GAT 256 -> 4x256 concat (fused stats+aggr, fused head GEMMs) --
    aggr_b1_fused_kernel<<<N, 128, 0, stream>>>(row_ptr, deg, csr_src, a_s, a_d, h1b, accb);
    bgemm_b1<<<dim3(8, MBr), 512, 0, stream>>>(accb, w1T, h1b, res1T, bias1, res1_b, H2b, N);

    // ---- Block 2: GAT 1024 -> 2x96 concat (G/R/scores in one split-epilogue GEMM)
    {
        fold_att_b16_kernel<<<cdiv(2 * 1024, 256), 256, 0, stream>>>(w2, att_src2, att_dst2,
            Bcat2T + (size_t)384 * 1024, Bcat2T + (size_t)386 * 1024, 1024, 96, 2);
        // cols: [0,192)=G2b bf16, [192,384)=Rf fp32, [384,388)=scores -> a_s[N,4]
        bgemm<5><<<dim3(4, MBr), 512, 0, stream>>>(H2b, Bcat2T, nullptr, G2b, 0, Rf, a_s, 192, N, 388, 1024, 1024);
        // H3b (R0) does NOT alias G2b (R1) -> fused gather+epilogue is safe
        aggr_comb_fused_kernel<2, 96, 192, 96><<<N, 96, 0, stream>>>(row_ptr, deg, csr_src, a_s,
                                                                     G2b, Rf, bias2, res2_b, H3b);
    }

    // ---- Block 3: GAT 192 -> 1x128 (no concat) ----
    {
        fold_att_b16_kernel<<<1, 256, 0, stream>>>(w3, att_src3, att_dst3,
            Bcat3T + (size_t)256 * 192, Bcat3T + (size_t)257 * 192, 192, 128, 1);
        // cols: [0,128)=G3b bf16, [128,256)=Rf fp32, [256,258)=scores -> a_s[N,2]
        bgemm<5><<<dim3(3, MBr), 512, 0, stream>>>(H3b, Bcat3T, nullptr, G3b, 0, Rf, a_s, 128, N, 258, 192, 192);
        // H4b (R2 + N*256B) does NOT alias G3b (R2, N*256B) -> safe
        aggr_comb_fused_kernel<1, 128, 128, 64><<<N, 64, 0, stream>>>(row_ptr, deg, csr_src, a_s,
                                                                      G3b, Rf, bias3, res3_b, H4b);
    }

    // ---- MLP head: relu(H4b@mlp_w1+b1)@mlp_w2+b2 fused into ONE GEMM epilogue ---
    bgemm<4><<<dim3(1, MBr), 512, 0, stream>>>(H4b, mlpw1T, mlp_b1, d_out, 2,
                                               (float*)mlp_w2, (float*)mlp_b2, 0, N, 64, 128, 128);
}

// Round 5
// 724.254 us; speedup vs baseline: 1.2733x; 1.1089x over previous
//
#include <hip/hip_runtime.h>
#include <cstddef>

#define LN_EPS 1e-5f

typedef __bf16 bf16x8 __attribute__((ext_vector_type(8)));
typedef float  f32x4  __attribute__((ext_vector_type(4)));

typedef __attribute__((address_space(3))) unsigned int lds_u32;
typedef __attribute__((address_space(1))) unsigned int glb_u32;

__device__ __forceinline__ void gl2lds16(const void* g, void* l) {
    // 16B per lane DMA: LDS dest = wave-uniform base + lane*16
    __builtin_amdgcn_global_load_lds((const glb_u32*)g, (lds_u32*)l, 16, 0, 0);
}

__device__ __forceinline__ float b2f(ushort h) {
    return __uint_as_float(((unsigned)h) << 16);
}
__device__ __forceinline__ ushort f2b(float f) {   // RNE
    unsigned u = __float_as_uint(f);
    return (ushort)((u + 0x7fffu + ((u >> 16) & 1u)) >> 16);
}
__device__ __forceinline__ unsigned pack2(float lo, float hi) {
    return (unsigned)f2b(lo) | ((unsigned)f2b(hi) << 16);
}
__device__ __forceinline__ uint2 pack4(const f32x4 v) {
    return make_uint2(pack2(v[0], v[1]), pack2(v[2], v[3]));
}

// XCD-aware remap: all gridDim.x col-blocks of one row-block land on one XCD.
__device__ __forceinline__ void xcd_map(int& bx, int& by) {
    int NX = gridDim.x, MBr = gridDim.y;
    int L = blockIdx.y * NX + blockIdx.x;
    int G = NX * 8;
    int g = L / G;
    if (g * 8 + 8 <= MBr) {
        int r = L - g * G;
        by = g * 8 + (r & 7);
        bx = r >> 3;
    } else {
        by = L / NX;
        bx = L - by * NX;
    }
}

__device__ __forceinline__ float wave_allreduce_max(float v) {
    #pragma unroll
    for (int off = 32; off > 0; off >>= 1) v = fmaxf(v, __shfl_xor(v, off, 64));
    return v;
}
__device__ __forceinline__ float wave_allreduce_sum(float v) {
    #pragma unroll
    for (int off = 32; off > 0; off >>= 1) v += __shfl_xor(v, off, 64);
    return v;
}

// ---- BM=256 x BN=128, BK=32, 8-wave (512 thr) MFMA K-loop, 2-buffer ------------
// (GEMM core unchanged from round 4 — three structure nulls say the 2-phase
//  cadence is the ceiling; do not perturb while tail is being optimized.)
__device__ __forceinline__ void stage3(const ushort* a0, const ushort* a1, const ushort* b0,
                                       ushort* __restrict__ As, ushort* __restrict__ Bs,
                                       int lb) {
    gl2lds16(a0, As + lb);           // A rows 0..127 of tile
    gl2lds16(a1, As + lb + 4096);    // A rows 128..255
    gl2lds16(b0, Bs + lb);           // B rows 0..127
}

__device__ __forceinline__ void mfma_loop256(const ushort* aA0, const ushort* aA1,
                                             const ushort* aB0,
                                             ushort* __restrict__ As, ushort* __restrict__ Bs,
                                             int lb,
                                             int K, int wr, int wc, int cA, int l15,
                                             f32x4 acc[4][4]) {
    const int BUFA = 256 * 32;         // ushorts per A buffer
    const int BUFB = 128 * 32;         // ushorts per B buffer
    const int nk = K >> 5;
    stage3(aA0, aA1, aB0, As, Bs, lb);                    // S0 -> buf0
    int p = 0;
    for (int t = 0; t < nk; t++) {
        asm volatile("s_waitcnt vmcnt(0)" ::: "memory");
        __builtin_amdgcn_s_barrier();
        __builtin_amdgcn_sched_barrier(0);   // no ds_read may hoist above barrier
        int kn = (t + 1) * 32;
        if (kn < K) stage3(aA0 + kn, aA1 + kn, aB0 + kn,
                           As + (p ^ 1) * BUFA, Bs + (p ^ 1) * BUFB, lb);
        const ushort* Ac = As + p * BUFA;
        const ushort* Bc = Bs + p * BUFB;
        bf16x8 af[4], bf[4];
        #pragma unroll
        for (int i = 0; i < 4; i++)
            af[i] = *reinterpret_cast<const bf16x8*>(&Ac[(wr + i * 16 + l15) * 32 + cA]);
        #pragma unroll
        for (int j = 0; j < 4; j++)
            bf[j] = *reinterpret_cast<const bf16x8*>(&Bc[(wc + j * 16 + l15) * 32 + cA]);
        #pragma unroll
        for (int i = 0; i < 4; i++)
            #pragma unroll
            for (int j = 0; j < 4; j++)
                acc[i][j] = __builtin_amdgcn_mfma_f32_16x16x32_bf16(bf[j], af[i], acc[i][j], 0, 0, 0);
        p ^= 1;
    }
    __syncthreads();   // protect LDS reuse (phase 2 / epilogue)
}

// ============== bf16 MFMA GEMM: C = A[M,K]@B  (B given as BT[Npad,K] bf16) =======
template<int EPI>
__global__ __launch_bounds__(512, 4) void bgemm(const ushort* __restrict__ A,
                                                const ushort* __restrict__ BT,
                                                const float* __restrict__ bias,
                                                void* __restrict__ out, int ldc,
                                                float* __restrict__ Rf,
                                                float* __restrict__ Sf, int Fs,
                                                int M, int Ncols, int K, int lda) {
    __shared__ ushort As[2][256 * 32];
    __shared__ ushort Bs[2][128 * 32];
    const int tid = threadIdx.x;
    int bx, by; xcd_map(bx, by);
    const int m0 = by * 256, n0 = bx * 128;
    const int w = tid >> 6, lane = tid & 63;
    const int wr = (w >> 1) * 64, wc = (w & 1) * 64;
    const int quad = lane >> 4, l15 = lane & 15;
    const int cA = (quad ^ ((l15 >> 1) & 3)) * 8;
    const int lb = w * 512;

    const int r = tid >> 2, g = ((tid & 3) ^ ((tid >> 3) & 3)) * 8;
    int ga0 = m0 + r;       if (ga0 >= M) ga0 = M - 1;
    int ga1 = m0 + 128 + r; if (ga1 >= M) ga1 = M - 1;
    const ushort* aA0 = A + (size_t)ga0 * lda + g;
    const ushort* aA1 = A + (size_t)ga1 * lda + g;
    const ushort* aB0 = BT + (size_t)(n0 + r) * K + g;

    f32x4 acc[4][4] = {};
    mfma_loop256(aA0, aA1, aB0, As[0], Bs[0], lb, K, wr, wc, cA, l15, acc);

    if (EPI == 4) {
        // cols 0..63 valid (B rows 64..127 are zero-padded); wc==64 waves idle.
        if (wc == 0) {
            #pragma unroll
            for (int i = 0; i < 4; i++) {
                float o0 = 0.f, o1 = 0.f;
                #pragma unroll
                for (int j = 0; j < 4; j++) {
                    int colbase = j * 16 + quad * 4;
                    float4 bv = *reinterpret_cast<const float4*>(&bias[colbase]);
                    float bb[4] = { bv.x, bv.y, bv.z, bv.w };
                    #pragma unroll
                    for (int rr = 0; rr < 4; rr++) {
                        float vv = fmaxf(acc[i][j][rr] + bb[rr], 0.f);
                        int c = colbase + rr;
                        o0 += vv * Rf[2 * c];
                        o1 += vv * Rf[2 * c + 1];
                    }
                }
                o0 += __shfl_xor(o0, 16, 64); o0 += __shfl_xor(o0, 32, 64);
                o1 += __shfl_xor(o1, 16, 64); o1 += __shfl_xor(o1, 32, 64);
                int row = m0 + wr + i * 16 + l15;
                if (quad == 0 && row < M) {
                    ((float*)out)[(size_t)row * 2]     = o0 + Sf[0];
                    ((float*)out)[(size_t)row * 2 + 1] = o1 + Sf[1];
                }
            }
        }
        return;
    }

    const int twoH = Ncols - 2 * Fs;
    #pragma unroll
    for (int i = 0; i < 4; i++) {
        int row = m0 + wr + i * 16 + l15;
        if (row >= M) continue;
        #pragma unroll
        for (int j = 0; j < 4; j++) {
            int colbase = n0 + wc + j * 16 + quad * 4;
            if (EPI == 0) {
                f32x4 v = acc[i][j];
                if (bias) {
                    float4 bv = *reinterpret_cast<const float4*>(&bias[colbase]);
                    v[0] += bv.x; v[1] += bv.y; v[2] += bv.z; v[3] += bv.w;
                }
                *reinterpret_cast<f32x4*>(&((float*)out)[(size_t)row * ldc + colbase]) = v;
            } else if (EPI == 5) {
                if (colbase + 3 < Fs) {
                    *reinterpret_cast<uint2*>(&((ushort*)out)[(size_t)row * Fs + colbase]) = pack4(acc[i][j]);
                } else if (colbase >= Fs && colbase + 3 < 2 * Fs) {
                    *reinterpret_cast<f32x4*>(&Rf[(size_t)row * Fs + (colbase - Fs)]) = acc[i][j];
                } else {
                    #pragma unroll
                    for (int rr = 0; rr < 4; rr++) {
                        int col = colbase + rr;
                        if (col < 2 * Fs || col >= Ncols) continue;
                        Sf[(size_t)row * twoH + (col - 2 * Fs)] = acc[i][j][rr];
                    }
                }
            }
        }
    }
}

// ===== fused block-1: H2 = elu(acc_h@W_h + bias1) + h1@res1_w + res1_b (bf16) ====
__global__ __launch_bounds__(512, 4) void bgemm_b1(const ushort* __restrict__ accb,  // N x 1024
                                                   const ushort* __restrict__ w1T,   // 1024 x 256
                                                   const ushort* __restrict__ h1b,   // N x 256
                                                   const ushort* __restrict__ res1T, // 1024 x 256
                                                   const float* __restrict__ bias1,
                                                   const float* __restrict__ res1b,
                                                   ushort* __restrict__ H2b, int M) {
    __shared__ ushort As[2][256 * 32];
    __shared__ ushort Bs[2][128 * 32];
    const int tid = threadIdx.x;
    int bx, by; xcd_map(bx, by);
    const int m0 = by * 256, n0 = bx * 128;
    const int h = n0 >> 8;
    const int w = tid >> 6, lane = tid & 63;
    const int wr = (w >> 1) * 64, wc = (w & 1) * 64;
    const int quad = lane >> 4, l15 = lane & 15;
    const int cA = (quad ^ ((l15 >> 1) & 3)) * 8;
    const int lb = w * 512;

    const int r = tid >> 2, g = ((tid & 3) ^ ((tid >> 3) & 3)) * 8;
    int ga0 = m0 + r;       if (ga0 >= M) ga0 = M - 1;
    int ga1 = m0 + 128 + r; if (ga1 >= M) ga1 = M - 1;

    f32x4 acc[4][4] = {};

    // phase 1: acc_h @ W_h
    mfma_loop256(accb + (size_t)ga0 * 1024 + h * 256 + g,
                 accb + (size_t)ga1 * 1024 + h * 256 + g,
                 w1T + (size_t)(n0 + r) * 256 + g,
                 As[0], Bs[0], lb, 256, wr, wc, cA, l15, acc);

    // in-register: acc = elu(acc + bias1) + res1_b
    #pragma unroll
    for (int i = 0; i < 4; i++) {
        #pragma unroll
        for (int j = 0; j < 4; j++) {
            int colbase = n0 + wc + j * 16 + quad * 4;
            float4 bv = *reinterpret_cast<const float4*>(&bias1[colbase]);
            float4 rv = *reinterpret_cast<const float4*>(&res1b[colbase]);
            float bb[4] = { bv.x, bv.y, bv.z, bv.w };
            float rr[4] = { rv.x, rv.y, rv.z, rv.w };
            #pragma unroll
            for (int q = 0; q < 4; q++) {
                float t = acc[i][j][q] + bb[q];
                t = t > 0.f ? t : (__expf(t) - 1.f);
                acc[i][j][q] = t + rr[q];
            }
        }
    }

    // phase 2: += h1 @ res1_w
    mfma_loop256(h1b + (size_t)ga0 * 256 + g,
                 h1b + (size_t)ga1 * 256 + g,
                 res1T + (size_t)(n0 + r) * 256 + g,
                 As[0], Bs[0], lb, 256, wr, wc, cA, l15, acc);

    #pragma unroll
    for (int i = 0; i < 4; i++) {
        int row = m0 + wr + i * 16 + l15;
        if (row >= M) continue;
        #pragma unroll
        for (int j = 0; j < 4; j++) {
            int colbase = n0 + wc + j * 16 + quad * 4;
            *reinterpret_cast<uint2*>(&H2b[(size_t)row * 1024 + colbase]) = pack4(acc[i][j]);
        }
    }
}

// ---------------- conversions / weight prep ----------------
__global__ void conv_pad_x_kernel(const float* __restrict__ x, ushort* __restrict__ xb, int N) {
    int t = blockIdx.x * 256 + threadIdx.x;
    if (t >= N * 448) return;
    int n = t / 448, k = t - n * 448;
    xb[t] = f2b(k < 405 ? x[(size_t)n * 405 + k] : 0.f);
}

// ---- ALL weight preps + ALL attention folds in ONE launch ----------------------
// Blocks [0,PB): bf16 transpose+pad segments (as before).
// Blocks [PB,..): wave-per-output attention folds (coalesced lane-parallel dots
// instead of 256-deep serial per-thread loops on a 32-wave grid).
#define PREP_PB 5135
__device__ __forceinline__ void prep_seg(int t, const float* src, ushort* dst,
                                         int K, int Nreal, int Kpad, int ldsrc) {
    int n = t / Kpad, k = t - n * Kpad;
    float v = (k < K && n < Nreal) ? src[(size_t)k * ldsrc + n] : 0.f;
    dst[t] = f2b(v);
}

__global__ void prep_fold_kernel(const float* __restrict__ enc_w1, const float* __restrict__ enc_w2,
                                 const float* __restrict__ w1, const float* __restrict__ res1_w,
                                 const float* __restrict__ w2, const float* __restrict__ res2_w,
                                 const float* __restrict__ w3, const float* __restrict__ res3_w,
                                 const float* __restrict__ mlp_w1,
                                 const float* __restrict__ att_s1, const float* __restrict__ att_d1,
                                 const float* __restrict__ att_s2, const float* __restrict__ att_d2,
                                 const float* __restrict__ att_s3, const float* __restrict__ att_d3,
                                 ushort* __restrict__ enc_w1T, ushort* __restrict__ enc_w2T,
                                 ushort* __restrict__ w1T, ushort* __restrict__ res1T,
                                 ushort* __restrict__ Bcat2T, ushort* __restrict__ Bcat3T,
                                 ushort* __restrict__ mlpw1T,
                                 float* __restrict__ qs, float* __restrict__ qd) {
    int blk = blockIdx.x;
    if (blk < PREP_PB) {
        int t = blk * 256 + threadIdx.x;
        const int c0 = 114688;            // enc_w1T 256x448
        const int c1 = c0 + 65536;        // enc_w2T 256x256
        const int c2 = c1 + 262144;       // w1T 1024x256
        const int c3 = c2 + 262144;       // res1T 1024x256
        const int c4 = c3 + 196608;       // Bcat2T rows 0-191 (w2)
        const int c5 = c4 + 196608;       // Bcat2T rows 192-383 (res2)
        const int c6 = c5 + 126976;       // Bcat2T rows 388-511 zero
        const int c7 = c6 + 24576;        // Bcat3T rows 0-127 (w3)
        const int c8 = c7 + 24576;        // Bcat3T rows 128-255 (res3)
        const int c9 = c8 + 24192;        // Bcat3T rows 258-383 zero
        const int c10 = c9 + 16384;       // mlpw1T 128x128
        if (t < c0)      prep_seg(t,        enc_w1, enc_w1T, 405, 256, 448, 256);
        else if (t < c1) prep_seg(t - c0,   enc_w2, enc_w2T, 256, 256, 256, 256);
        else if (t < c2) prep_seg(t - c1,   w1,     w1T,     256, 1024, 256, 1024);
        else if (t < c3) prep_seg(t - c2,   res1_w, res1T,   256, 1024, 256, 1024);
        else if (t < c4) prep_seg(t - c3,   w2,     Bcat2T,  1024, 192, 1024, 192);
        else if (t < c5) prep_seg(t - c4,   res2_w, Bcat2T + (size_t)192 * 1024, 1024, 192, 1024, 192);
        else if (t < c6) Bcat2T[(size_t)388 * 1024 + (t - c5)] = 0;
        else if (t < c7) prep_seg(t - c6,   w3,     Bcat3T,  192, 128, 192, 128);
        else if (t < c8) prep_seg(t - c7,   res3_w, Bcat3T + (size_t)128 * 192, 192, 128, 192, 128);
        else if (t < c9) Bcat3T[(size_t)258 * 192 + (t - c8)] = 0;
        else if (t < c10) prep_seg(t - c9,  mlp_w1, mlpw1T,  128, 64, 128, 64);
        return;
    }
    // ---- fold segments: one wave per output element ----
    int fw = (blk - PREP_PB) * 4 + (threadIdx.x >> 6);
    int lane = threadIdx.x & 63;
    if (fw < 1024) {
        // block-1 fold (fp32): t = h*256+k; dot over c<256 of w1[k*1024+h*256+c]*att[h*256+c]
        int h = fw >> 8, k = fw & 255;
        const float* wrow = w1 + (size_t)k * 1024 + h * 256;
        f32x4 wv = *reinterpret_cast<const f32x4*>(&wrow[lane * 4]);
        f32x4 as = *reinterpret_cast<const f32x4*>(&att_s1[h * 256 + lane * 4]);
        f32x4 ad = *reinterpret_cast<const f32x4*>(&att_d1[h * 256 + lane * 4]);
        float ss = wv[0] * as[0] + wv[1] * as[1] + wv[2] * as[2] + wv[3] * as[3];
        float sd = wv[0] * ad[0] + wv[1] * ad[1] + wv[2] * ad[2] + wv[3] * ad[3];
        ss = wave_allreduce_sum(ss);
        sd = wave_allreduce_sum(sd);
        if (lane == 0) { qs[fw] = ss; qd[fw] = sd; }
    } else if (fw < 1024 + 2048) {
        // block-2 fold (bf16 -> Bcat2T rows 384-387): t = h*1024+k; dot over c<96
        int t = fw - 1024;
        int h = t >> 10, k = t & 1023;
        const float* wrow = w2 + (size_t)k * 192 + h * 96;
        const float* as = att_s2 + h * 96;
        const float* ad = att_d2 + h * 96;
        float w0 = wrow[lane];
        float ss = w0 * as[lane], sd = w0 * ad[lane];
        if (lane < 32) {
            float w1v = wrow[64 + lane];
            ss += w1v * as[64 + lane];
            sd += w1v * ad[64 + lane];
        }
        ss = wave_allreduce_sum(ss);
        sd = wave_allreduce_sum(sd);
        if (lane == 0) {
            Bcat2T[(size_t)384 * 1024 + t] = f2b(ss);
            Bcat2T[(size_t)386 * 1024 + t] = f2b(sd);
        }
    } else {
        // block-3 fold (bf16 -> Bcat3T rows 256-257): t = k < 192; dot over c<128
        int t = fw - 3072;
        if (t < 192) {
            const float* wrow = w3 + (size_t)t * 128;
            float w0 = wrow[lane], w1v = wrow[64 + lane];
            float ss = w0 * att_s3[lane] + w1v * att_s3[64 + lane];
            float sd = w0 * att_d3[lane] + w1v * att_d3[64 + lane];
            ss = wave_allreduce_sum(ss);
            sd = wave_allreduce_sum(sd);
            if (lane == 0) {
                Bcat3T[(size_t)256 * 192 + t] = f2b(ss);
                Bcat3T[(size_t)257 * 192 + t] = f2b(sd);
            }
        }
    }
}

// ------- LayerNorm(+ReLU), WAVE-PER-ROW, 2-row ILP: fp32 in, bf16 out; C==256 ---
// Two rows per iteration: the 6-step butterfly chains of both rows interleave,
// hiding shuffle latency. No __syncthreads, no LDS.
template<int H>
__global__ __launch_bounds__(256) void ln_relu_w_kernel(const float* __restrict__ x,
                                                        const float* __restrict__ g,
                                                        const float* __restrict__ b,
                                                        const float* __restrict__ qs,
                                                        const float* __restrict__ qd,
                                                        ushort* __restrict__ out,
                                                        float* __restrict__ a_s,
                                                        float* __restrict__ a_d,
                                                        int N) {
    const int lane = threadIdx.x & 63;
    int wid = blockIdx.x * 4 + (threadIdx.x >> 6);
    const int nw = gridDim.x * 4;
    const int c4 = lane * 4;

    f32x4 gv = *reinterpret_cast<const f32x4*>(&g[c4]);
    f32x4 bv = *reinterpret_cast<const f32x4*>(&b[c4]);
    f32x4 qsv[H > 0 ? H : 1], qdv[H > 0 ? H : 1];
    if (H > 0) {
        #pragma unroll
        for (int hh = 0; hh < H; hh++) {
            qsv[hh] = *reinterpret_cast<const f32x4*>(&qs[hh * 256 + c4]);
            qdv[hh] = *reinterpret_cast<const f32x4*>(&qd[hh * 256 + c4]);
        }
    }

    for (int r0 = wid * 2; r0 < N; r0 += 2 * nw) {
        int r1 = r0 + 1;
        bool has1 = r1 < N;
        f32x4 va = *reinterpret_cast<const f32x4*>(&x[(size_t)r0 * 256 + c4]);
        f32x4 vb = has1 ? *reinterpret_cast<const f32x4*>(&x[(size_t)r1 * 256 + c4]) : va;
        float sa  = va[0] + va[1] + va[2] + va[3];
        float s2a = va[0] * va[0] + va[1] * va[1] + va[2] * va[2] + va[3] * va[3];
        float sb  = vb[0] + vb[1] + vb[2] + vb[3];
        float s2b = vb[0] * vb[0] + vb[1] * vb[1] + vb[2] * vb[2] + vb[3] * vb[3];
        #pragma unroll
        for (int off = 32; off > 0; off >>= 1) {
            sa  += __shfl_xor(sa,  off, 64);
            sb  += __shfl_xor(sb,  off, 64);
            s2a += __shfl_xor(s2a, off, 64);
            s2b += __shfl_xor(s2b, off, 64);
        }
        float ma  = sa * (1.f / 256.f);
        float mb  = sb * (1.f / 256.f);
        float rsa = rsqrtf(s2a * (1.f / 256.f) - ma * ma + LN_EPS);
        float rsb = rsqrtf(s2b * (1.f / 256.f) - mb * mb + LN_EPS);
        f32x4 oa, ob;
        #pragma unroll
        for (int k = 0; k < 4; k++) {
            oa[k] = fmaxf((va[k] - ma) * rsa * gv[k] + bv[k], 0.f);
            ob[k] = fmaxf((vb[k] - mb) * rsb * gv[k] + bv[k], 0.f);
        }
        *reinterpret_cast<uint2*>(&out[(size_t)r0 * 256 + c4]) =
            make_uint2(pack2(oa[0], oa[1]), pack2(oa[2], oa[3]));
        if (has1)
            *reinterpret_cast<uint2*>(&out[(size_t)r1 * 256 + c4]) =
                make_uint2(pack2(ob[0], ob[1]), pack2(ob[2], ob[3]));
        if (H > 0) {
            float sc[H > 0 ? 4 * H : 1];
            #pragma unroll
            for (int hh = 0; hh < H; hh++) {
                sc[hh]           = oa[0] * qsv[hh][0] + oa[1] * qsv[hh][1] + oa[2] * qsv[hh][2] + oa[3] * qsv[hh][3];
                sc[H + hh]       = oa[0] * qdv[hh][0] + oa[1] * qdv[hh][1] + oa[2] * qdv[hh][2] + oa[3] * qdv[hh][3];
                sc[2 * H + hh]   = ob[0] * qsv[hh][0] + ob[1] * qsv[hh][1] + ob[2] * qsv[hh][2] + ob[3] * qsv[hh][3];
                sc[3 * H + hh]   = ob[0] * qdv[hh][0] + ob[1] * qdv[hh][1] + ob[2] * qdv[hh][2] + ob[3] * qdv[hh][3];
            }
            #pragma unroll
            for (int off = 32; off > 0; off >>= 1)
                #pragma unroll
                for (int k = 0; k < 4 * H; k++) sc[k] += __shfl_xor(sc[k], off, 64);
            if (lane == 0) {
                #pragma unroll
                for (int k = 0; k < H; k++) a_s[(size_t)r0 * H + k] = sc[k];
                if (has1)
                    #pragma unroll
                    for (int k = 0; k < H; k++) a_s[(size_t)r1 * H + k] = sc[2 * H + k];
            } else if (lane == 1) {
                #pragma unroll
                for (int k = 0; k < H; k++) a_d[(size_t)r0 * H + k] = sc[H + k];
                if (has1)
                    #pragma unroll
                    for (int k = 0; k < H; k++) a_d[(size_t)r1 * H + k] = sc[3 * H + k];
            }
        }
    }
}

// ================= CSR construction (dst-grouped) =========
__device__ __forceinline__ void edge_sd(const int* ei, int e, int E, int& s, int& d) {
    if (e < E) { s = ei[e]; d = ei[E + e]; } else { s = d = e - E; }
}

__global__ void deg_kernel(const int* __restrict__ ei, int* __restrict__ deg, int E, int Et) {
    int e = blockIdx.x * blockDim.x + threadIdx.x;
    if (e >= Et) return;
    int s, d; edge_sd(ei, e, E, s, d);
    atomicAdd(&deg[d], 1);
}

__global__ __launch_bounds__(256) void scan1_kernel(const int* __restrict__ deg,
                                                    int* __restrict__ incl,
                                                    int* __restrict__ part, int N) {
    __shared__ int sd[256];
    int t = threadIdx.x;
    int i = blockIdx.x * 256 + t;
    int v = (i < N) ? deg[i] : 0;
    sd[t] = v; __syncthreads();
    #pragma unroll
    for (int o = 1; o < 256; o <<= 1) {
        int x = (t >= o) ? sd[t - o] : 0;
        __syncthreads();
        sd[t] += x;
        __syncthreads();
    }
    if (i < N) incl[i] = sd[t];
    if (t == 255) part[blockIdx.x] = sd[255];
}

__global__ __launch_bounds__(256) void scan2_kernel(int* __restrict__ part, int nb) {
    __shared__ int sd[256];
    int t = threadIdx.x;
    int v = (t < nb) ? part[t] : 0;
    sd[t] = v; __syncthreads();
    #pragma unroll
    for (int o = 1; o < 256; o <<= 1) {
        int x = (t >= o) ? sd[t - o] : 0;
        __syncthreads();
        sd[t] += x;
        __syncthreads();
    }
    if (t < nb) part[t] = sd[t];
}

__global__ void scan3_kernel(const int* __restrict__ incl, const int* __restrict__ deg,
                             const int* __restrict__ part, int* __restrict__ row_ptr, int N) {
    int i = blockIdx.x * blockDim.x + threadIdx.x;
    if (i >= N) return;
    int off = (blockIdx.x > 0) ? part[blockIdx.x - 1] : 0;
    row_ptr[i] = incl[i] - deg[i] + off;
}

__global__ void fill_kernel(const int* __restrict__ ei, const int* __restrict__ row_ptr,
                            int* __restrict__ cur, int* __restrict__ csr_src, int E, int Et) {
    int e = blockIdx.x * blockDim.x + threadIdx.x;
    if (e >= Et) return;
    int s, d; edge_sd(ei, e, E, s, d);
    int pos = row_ptr[d] + atomicAdd(&cur[d], 1);
    csr_src[pos] = s;
}

// Max per-dst edges cached in LDS by the fused stats+aggr kernels; degrees above
// this fall back to on-the-fly alpha recompute (random graph max-deg ~40 << 256).
#define ACAP 256

// ==== block1: FUSED softmax-stats + gather-aggregate (all 4 heads) ==============
// wave0 computes per-dst max/sum (exp stash in LDS); both waves then gather.
// Gather loop manually unrolled 2x: two independent row-gathers in flight.
__global__ __launch_bounds__(128) void aggr_b1_fused_kernel(const int* __restrict__ row_ptr,
                                                            const int* __restrict__ deg,
                                                            const int* __restrict__ csr_src,
                                                            const float* __restrict__ a_s,
                                                            const float* __restrict__ a_d,
                                                            const ushort* __restrict__ h1b,
                                                            ushort* __restrict__ accb) {
    __shared__ float alf[ACAP][4];
    __shared__ float sstat[8];     // mx[0..3], rd[4..7]
    int d = blockIdx.x, t = threadIdx.x;
    int base = row_ptr[d], dg = deg[d];
    float4 ad = *reinterpret_cast<const float4*>(&a_d[(size_t)d * 4]);
    if (t < 64) {
        float m0 = -1e30f, m1 = -1e30f, m2 = -1e30f, m3 = -1e30f;
        for (int j = t; j < dg; j += 64) {
            int s = csr_src[base + j];
            float4 sv = *reinterpret_cast<const float4*>(&a_s[(size_t)s * 4]);
            float c0 = sv.x + ad.x; c0 = c0 > 0.f ? c0 : 0.2f * c0; m0 = fmaxf(m0, c0);
            float c1 = sv.y + ad.y; c1 = c1 > 0.f ? c1 : 0.2f * c1; m1 = fmaxf(m1, c1);
            float c2 = sv.z + ad.z; c2 = c2 > 0.f ? c2 : 0.2f * c2; m2 = fmaxf(m2, c2);
            float c3 = sv.w + ad.w; c3 = c3 > 0.f ? c3 : 0.2f * c3; m3 = fmaxf(m3, c3);
        }
        m0 = wave_allreduce_max(m0); m1 = wave_allreduce_max(m1);
        m2 = wave_allreduce_max(m2); m3 = wave_allreduce_max(m3);
        float s0 = 0.f, s1 = 0.f, s2 = 0.f, s3 = 0.f;
        for (int j = t; j < dg; j += 64) {
            int s = csr_src[base + j];
            float4 sv = *reinterpret_cast<const float4*>(&a_s[(size_t)s * 4]);
            float c0 = sv.x + ad.x; c0 = c0 > 0.f ? c0 : 0.2f * c0; float e0 = __expf(c0 - m0); s0 += e0;
            float c1 = sv.y + ad.y; c1 = c1 > 0.f ? c1 : 0.2f * c1; float e1 = __expf(c1 - m1); s1 += e1;
            float c2 = sv.z + ad.z; c2 = c2 > 0.f ? c2 : 0.2f * c2; float e2 = __expf(c2 - m2); s2 += e2;
            float c3 = sv.w + ad.w; c3 = c3 > 0.f ? c3 : 0.2f * c3; float e3 = __expf(c3 - m3); s3 += e3;
            if (j < ACAP) { alf[j][0] = e0; alf[j][1] = e1; alf[j][2] = e2; alf[j][3] = e3; }
        }
        s0 = wave_allreduce_sum(s0); s1 = wave_allreduce_sum(s1);
        s2 = wave_allreduce_sum(s2); s3 = wave_allreduce_sum(s3);
        if (t == 0) {
            sstat[0] = m0; sstat[1] = m1; sstat[2] = m2; sstat[3] = m3;
            sstat[4] = 1.f / (s0 + 1e-16f); sstat[5] = 1.f / (s1 + 1e-16f);
            sstat[6] = 1.f / (s2 + 1e-16f); sstat[7] = 1.f / (s3 + 1e-16f);
        }
    }
    __syncthreads();
    float r0 = sstat[4], r1 = sstat[5], r2 = sstat[6], r3 = sstat[7];
    float a00 = 0, a01 = 0, a10 = 0, a11 = 0, a20 = 0, a21 = 0, a30 = 0, a31 = 0;

    auto alpha4 = [&](int j, int s, float& al0, float& al1, float& al2, float& al3) {
        if (j < ACAP) {
            al0 = alf[j][0] * r0; al1 = alf[j][1] * r1;
            al2 = alf[j][2] * r2; al3 = alf[j][3] * r3;
        } else {
            float4 sv = *reinterpret_cast<const float4*>(&a_s[(size_t)s * 4]);
            float c0 = sv.x + ad.x; c0 = c0 > 0.f ? c0 : 0.2f * c0; al0 = __expf(c0 - sstat[0]) * r0;
            float c1 = sv.y + ad.y; c1 = c1 > 0.f ? c1 : 0.2f * c1; al1 = __expf(c1 - sstat[1]) * r1;
            float c2 = sv.z + ad.z; c2 = c2 > 0.f ? c2 : 0.2f * c2; al2 = __expf(c2 - sstat[2]) * r2;
            float c3 = sv.w + ad.w; c3 = c3 > 0.f ? c3 : 0.2f * c3; al3 = __expf(c3 - sstat[3]) * r3;
        }
    };
    int j = 0;
    for (; j + 2 <= dg; j += 2) {
        int s0i = csr_src[base + j], s1i = csr_src[base + j + 1];
        unsigned v0 = reinterpret_cast<const unsigned*>(h1b + (size_t)s0i * 256)[t];
        unsigned v1 = reinterpret_cast<const unsigned*>(h1b + (size_t)s1i * 256)[t];
        float x0, x1, x2, x3, y0, y1, y2, y3;
        alpha4(j, s0i, x0, x1, x2, x3);
        alpha4(j + 1, s1i, y0, y1, y2, y3);
        float lo0 = b2f((ushort)(v0 & 0xffff)), hi0 = b2f((ushort)(v0 >> 16));
        float lo1 = b2f((ushort)(v1 & 0xffff)), hi1 = b2f((ushort)(v1 >> 16));
        a00 += x0 * lo0 + y0 * lo1; a01 += x0 * hi0 + y0 * hi1;
        a10 += x1 * lo0 + y1 * lo1; a11 += x1 * hi0 + y1 * hi1;
        a20 += x2 * lo0 + y2 * lo1; a21 += x2 * hi0 + y2 * hi1;
        a30 += x3 * lo0 + y3 * lo1; a31 += x3 * hi0 + y3 * hi1;
    }
    if (j < dg) {
        int s0i = csr_src[base + j];
        unsigned v0 = reinterpret_cast<const unsigned*>(h1b + (size_t)s0i * 256)[t];
        float x0, x1, x2, x3;
        alpha4(j, s0i, x0, x1, x2, x3);
        float lo0 = b2f((ushort)(v0 & 0xffff)), hi0 = b2f((ushort)(v0 >> 16));
        a00 += x0 * lo0; a01 += x0 * hi0;
        a10 += x1 * lo0; a11 += x1 * hi0;
        a20 += x2 * lo0; a21 += x2 * hi0;
        a30 += x3 * lo0; a31 += x3 * hi0;
    }
    unsigned* o = reinterpret_cast<unsigned*>(accb + (size_t)d * 1024);
    o[t]       = pack2(a00, a01);
    o[t + 128] = pack2(a10, a11);
    o[t + 256] = pack2(a20, a21);
    o[t + 384] = pack2(a30, a31);
}

// ==== blocks 2/3: FUSED stats + gather-aggregate + elu/residual epilogue ========
// scores layout: src_h = as[s*2H+h], dst_h = as[d*2H+H+h].
// Gather loop unrolled 2x. outb must NOT alias g.
template<int H, int C, int F, int NT>
__global__ __launch_bounds__(NT) void aggr_comb_fused_kernel(const int* __restrict__ row_ptr,
                                                             const int* __restrict__ deg,
                                                             const int* __restrict__ csr_src,
                                                             const float* __restrict__ as,
                                                             const ushort* __restrict__ g,
                                                             const float* __restrict__ Rf,
                                                             const float* __restrict__ gb,
                                                             const float* __restrict__ rb,
                                                             ushort* __restrict__ outb) {
    __shared__ float alf[ACAP][H];
    __shared__ float sstat[2 * H];   // mx[0..H), rd[H..2H)
    int d = blockIdx.x;
    int t = threadIdx.x;               // 0..F/2-1
    int base = row_ptr[d], dg = deg[d];
    if (t < 64) {
        float ad[H], mx[H];
        #pragma unroll
        for (int h = 0; h < H; h++) { ad[h] = as[(size_t)d * 2 * H + H + h]; mx[h] = -1e30f; }
        for (int j = t; j < dg; j += 64) {
            int s = csr_src[base + j];
            #pragma unroll
            for (int h = 0; h < H; h++) {
                float c = as[(size_t)s * 2 * H + h] + ad[h];
                c = c > 0.f ? c : 0.2f * c;
                mx[h] = fmaxf(mx[h], c);
            }
        }
        #pragma unroll
        for (int h = 0; h < H; h++) mx[h] = wave_allreduce_max(mx[h]);
        float sm[H];
        #pragma unroll
        for (int h = 0; h < H; h++) sm[h] = 0.f;
        for (int j = t; j < dg; j += 64) {
            int s = csr_src[base + j];
            #pragma unroll
            for (int h = 0; h < H; h++) {
                float c = as[(size_t)s * 2 * H + h] + ad[h];
                c = c > 0.f ? c : 0.2f * c;
                float e = __expf(c - mx[h]);
                sm[h] += e;
                if (j < ACAP) alf[j][h] = e;
            }
        }
        #pragma unroll
        for (int h = 0; h < H; h++) sm[h] = wave_allreduce_sum(sm[h]);
        if (t == 0) {
            #pragma unroll
            for (int h = 0; h < H; h++) { sstat[h] = mx[h]; sstat[H + h] = 1.f / (sm[h] + 1e-16f); }
        }
    }
    __syncthreads();
    int hd = (2 * t) / C;
    float mxv = sstat[hd], rdv = sstat[H + hd];
    float adv = as[(size_t)d * 2 * H + H + hd];
    float lo = 0.f, hi = 0.f;
    auto alpha1 = [&](int j, int s) -> float {
        if (j < ACAP) return alf[j][hd] * rdv;
        float c = as[(size_t)s * 2 * H + hd] + adv;
        c = c > 0.f ? c : 0.2f * c;
        return __expf(c - mxv) * rdv;
    };
    int j = 0;
    for (; j + 2 <= dg; j += 2) {
        int s0 = csr_src[base + j], s1 = csr_src[base + j + 1];
        unsigned v0 = reinterpret_cast<const unsigned*>(g + (size_t)s0 * F)[t];
        unsigned v1 = reinterpret_cast<const unsigned*>(g + (size_t)s1 * F)[t];
        float al0 = alpha1(j, s0), al1 = alpha1(j + 1, s1);
        lo += al0 * b2f((ushort)(v0 & 0xffff)) + al1 * b2f((ushort)(v1 & 0xffff));
        hi += al0 * b2f((ushort)(v0 >> 16))    + al1 * b2f((ushort)(v1 >> 16));
    }
    if (j < dg) {
        int s0 = csr_src[base + j];
        unsigned v0 = reinterpret_cast<const unsigned*>(g + (size_t)s0 * F)[t];
        float al0 = alpha1(j, s0);
        lo += al0 * b2f((ushort)(v0 & 0xffff));
        hi += al0 * b2f((ushort)(v0 >> 16));
    }
    int c0 = 2 * t, c1 = 2 * t + 1;
    float o0 = lo + gb[c0]; o0 = o0 > 0.f ? o0 : (__expf(o0) - 1.f);
    float o1 = hi + gb[c1]; o1 = o1 > 0.f ? o1 : (__expf(o1) - 1.f);
    o0 += Rf[(size_t)d * F + c0] + rb[c0];
    o1 += Rf[(size_t)d * F + c1] + rb[c1];
    reinterpret_cast<unsigned*>(outb)[(size_t)d * (F / 2) + t] = pack2(o0, o1);
}

extern "C" void kernel_launch(void* const* d_in, const int* in_sizes, int n_in,
                              void* d_out, int out_size, void* d_ws, size_t ws_size,
                              hipStream_t stream) {
    const float* x        = (const float*)d_in[0];
    const int*   ei       = (const int*)d_in[1];
    const float* enc_w1   = (const float*)d_in[2];
    const float* enc_b1   = (const float*)d_in[3];
    const float* ln1_g    = (const float*)d_in[4];
    const float* ln1_b    = (const float*)d_in[5];
    const float* enc_w2   = (const float*)d_in[6];
    const float* enc_b2   = (const float*)d_in[7];
    const float* ln2_g    = (const float*)d_in[8];
    const float* ln2_b    = (const float*)d_in[9];
    const float* w1       = (const float*)d_in[10];
    const float* att_src1 = (const float*)d_in[11];
    const float* att_dst1 = (const float*)d_in[12];
    const float* bias1    = (const float*)d_in[13];
    const float* res1_w   = (const float*)d_in[14];
    const float* res1_b   = (const float*)d_in[15];
    const float* w2       = (const float*)d_in[16];
    const float* att_src2 = (const float*)d_in[17];
    const float* att_dst2 = (const float*)d_in[18];
    const float* bias2    = (const float*)d_in[19];
    const float* res2_w   = (const float*)d_in[20];
    const float* res2_b   = (const float*)d_in[21];
    const float* w3       = (const float*)d_in[22];
    const float* att_src3 = (const float*)d_in[23];
    const float* att_dst3 = (const float*)d_in[24];
    const float* bias3    = (const float*)d_in[25];
    const float* res3_w   = (const float*)d_in[26];
    const float* res3_b   = (const float*)d_in[27];
    const float* mlp_w1   = (const float*)d_in[28];
    const float* mlp_b1   = (const float*)d_in[29];
    const float* mlp_w2   = (const float*)d_in[30];
    const float* mlp_b2   = (const float*)d_in[31];

    const int N  = in_sizes[0] / 405;   // 50000
    const int E  = in_sizes[1] / 2;     // 300000
    const int Et = E + N;
    const int NB = (N + 255) / 256;

    // ---------- workspace layout (bytes) ----------
    char* p = (char*)d_ws;
    char* R0 = p;                       // N*896 B : xb(448 b16) | H3b(b16 192)
    char* R1 = R0 + (size_t)N * 896;    // N*512 B : h0b | G2b
    char* R2 = R1 + (size_t)N * 512;    // N*512 B : h1b | G3b , H4b(@+N*256B)
    char* R3 = R2 + (size_t)N * 512;    // N*2048 B: F1(f32 256) | H2b(b16 1024)
    char* R4 = R3 + (size_t)N * 2048;   // N*2048 B: accb(b16 1024) | Rf(f32 192/128)
    char* T  = R4 + (size_t)N * 2048;   // tail

    ushort* xb   = (ushort*)R0;
    ushort* H3b  = (ushort*)R0;          // lives after xb is dead (enc1 done)
    ushort* h0b  = (ushort*)R1;
    ushort* G2b  = (ushort*)R1;
    ushort* h1b  = (ushort*)R2;
    ushort* G3b  = (ushort*)R2;
    ushort* H4b  = (ushort*)(R2 + (size_t)N * 256);
    float*  F1   = (float*)R3;
    ushort* H2b  = (ushort*)R3;
    ushort* accb = (ushort*)R4;
    float*  Rf   = (float*)R4;

    float* a_s   = (float*)T;                         T += (size_t)N * 4 * 4;   // also Sf2/Sf3
    float* a_d   = (float*)T;                         T += (size_t)N * 4 * 4;
    float* qs    = (float*)T;                         T += 2048 * 4;
    float* qd    = (float*)T;                         T += 2048 * 4;
    int* deg     = (int*)T;                           T += (size_t)N * 4;
    int* cur     = (int*)T;                           T += (size_t)N * 4;
    int* row_ptr = (int*)T;                           T += (size_t)N * 4;
    int* incl    = (int*)T;                           T += (size_t)N * 4;
    int* part    = (int*)T;                           T += 256 * 4;
    int* csr_src = (int*)T;                           T += (size_t)Et * 4;
    ushort* enc_w1T = (ushort*)T;                     T += (size_t)256 * 448 * 2;
    ushort* enc_w2T = (ushort*)T;                     T += (size_t)256 * 256 * 2;
    ushort* w1T     = (ushort*)T;                     T += (size_t)1024 * 256 * 2;
    ushort* res1T   = (ushort*)T;                     T += (size_t)1024 * 256 * 2;
    ushort* Bcat2T  = (ushort*)T;                     T += (size_t)512 * 1024 * 2;
    ushort* Bcat3T  = (ushort*)T;                     T += (size_t)384 * 192 * 2;
    ushort* mlpw1T  = (ushort*)T;                     T += (size_t)128 * 128 * 2;

    auto cdiv = [](int a, int b) { return (a + b - 1) / b; };
    const int MBr = cdiv(N, 256);      // 256-row blocks for all MFMA GEMMs

    // ---- CSR build ----
    (void)hipMemsetAsync(deg, 0, (size_t)N * 8, stream);   // deg + cur
    deg_kernel<<<cdiv(Et, 256), 256, 0, stream>>>(ei, deg, E, Et);
    scan1_kernel<<<NB, 256, 0, stream>>>(deg, incl, part, N);
    scan2_kernel<<<1, 256, 0, stream>>>(part, NB);
    scan3_kernel<<<NB, 256, 0, stream>>>(incl, deg, part, row_ptr, N);
    fill_kernel<<<cdiv(Et, 256), 256, 0, stream>>>(ei, row_ptr, cur, csr_src, E, Et);

    // ---- weight prep + ALL attention folds: ONE launch ----
    // fold waves: 1024 (b1, fp32 qs/qd) + 2048 (b2 -> Bcat2T rows 384-387)
    //           + 192 (b3 -> Bcat3T rows 256-257) = 3264 waves = 816 blocks
    prep_fold_kernel<<<PREP_PB + 816, 256, 0, stream>>>(
        enc_w1, enc_w2, w1, res1_w, w2, res2_w, w3, res3_w, mlp_w1,
        att_src1, att_dst1, att_src2, att_dst2, att_src3, att_dst3,
        enc_w1T, enc_w2T, w1T, res1T, Bcat2T, Bcat3T, mlpw1T, qs, qd);

    // ---- JointEncoder ----
    conv_pad_x_kernel<<<cdiv(N * 448, 256), 256, 0, stream>>>(x, xb, N);
    bgemm<0><<<dim3(2, MBr), 512, 0, stream>>>(xb, enc_w1T, enc_b1, F1, 256, nullptr, nullptr, 0, N, 256, 448, 448);
    ln_relu_w_kernel<0><<<2048, 256, 0, stream>>>(F1, ln1_g, ln1_b, nullptr, nullptr, h0b, nullptr, nullptr, N);
    bgemm<0><<<dim3(2, MBr), 512, 0, stream>>>(h0b, enc_w2T, enc_b2, F1, 256, nullptr, nullptr, 0, N, 256, 256, 256);
    // LN2 + fused block-1 attention scores (fp32, wave-per-row, 2-row ILP)
    ln_relu_w_kernel<4><<<2048, 256, 0, stream>>>(F1, ln2_g, ln2_b, qs, qd, h1b, a_s, a_d, N);

    // ---- Block 1: GAT 256 -> 4x256 concat (fused stats+aggr, fused head GEMMs) --
    aggr_b1_fused_kernel<<<N, 128, 0, stream>>>(row_ptr, deg, csr_src, a_s, a_d, h1b, accb);
    bgemm_b1<<<dim3(8, MBr), 512, 0, stream>>>(accb, w1T, h1b, res1T, bias1, res1_b, H2b, N);

    // ---- Block 2: GAT 1024 -> 2x96 concat (G/R/scores in one split-epilogue GEMM)
    {
        // cols: [0,192)=G2b bf16, [192,384)=Rf fp32, [384,388)=scores -> a_s[N,4]
        bgemm<5><<<dim3(4, MBr), 512, 0, stream>>>(H2b, Bcat2T, nullptr, G2b, 0, Rf, a_s, 192, N, 388, 1024, 1024);
        // H3b (R0) does NOT alias G2b (R1) -> fused gather+epilogue is safe
        aggr_comb_fused_kernel<2, 96, 192, 96><<<N, 96, 0, stream>>>(row_ptr, deg, csr_src, a_s,
                                                                     G2b, Rf, bias2, res2_b, H3b);
    }

    // ---- Block 3: GAT 192 -> 1x128 (no concat) ----
    {
        // cols: [0,128)=G3b bf16, [128,256)=Rf fp32, [256,258)=scores -> a_s[N,2]
        bgemm<5><<<dim3(3, MBr), 512, 0, stream>>>(H3b, Bcat3T, nullptr, G3b, 0, Rf, a_s, 128, N, 258, 192, 192);
        // H4b (R2 + N*256B) does NOT alias G3b (R2, N*256B) -> safe
        aggr_comb_fused_kernel<1, 128, 128, 64><<<N, 64, 0, stream>>>(row_ptr, deg, csr_src, a_s,
                                                                      G3b, Rf, bias3, res3_b, H4b);
    }

    // ---- MLP head: relu(H4b@mlp_w1+b1)@mlp_w2+b2 fused into ONE GEMM epilogue ---
    bgemm<4><<<dim3(1, MBr), 512, 0, stream>>>(H4b, mlpw1T, mlp_b1, d_out, 2,
                                               (float*)mlp_w2, (float*)mlp_b2, 0, N, 64, 128, 128);
}

// Round 8
// 716.642 us; speedup vs baseline: 1.2868x; 1.0106x over previous
//
#include <hip/hip_runtime.h>
#include <cstddef>

#define LN_EPS 1e-5f

typedef __bf16 bf16x8 __attribute__((ext_vector_type(8)));
typedef float  f32x4  __attribute__((ext_vector_type(4)));

typedef __attribute__((address_space(3))) unsigned int lds_u32;
typedef __attribute__((address_space(1))) unsigned int glb_u32;

__device__ __forceinline__ void gl2lds16(const void* g, void* l) {
    // 16B per lane DMA: LDS dest = wave-uniform base + lane*16
    __builtin_amdgcn_global_load_lds((const glb_u32*)g, (lds_u32*)l, 16, 0, 0);
}

__device__ __forceinline__ float b2f(ushort h) {
    return __uint_as_float(((unsigned)h) << 16);
}
__device__ __forceinline__ ushort f2b(float f) {   // RNE
    unsigned u = __float_as_uint(f);
    return (ushort)((u + 0x7fffu + ((u >> 16) & 1u)) >> 16);
}
__device__ __forceinline__ unsigned pack2(float lo, float hi) {
    return (unsigned)f2b(lo) | ((unsigned)f2b(hi) << 16);
}
__device__ __forceinline__ uint2 pack4(const f32x4 v) {
    return make_uint2(pack2(v[0], v[1]), pack2(v[2], v[3]));
}

// XCD-aware remap: all gridDim.x col-blocks of one row-block land on one XCD.
__device__ __forceinline__ void xcd_map(int& bx, int& by) {
    int NX = gridDim.x, MBr = gridDim.y;
    int L = blockIdx.y * NX + blockIdx.x;
    int G = NX * 8;
    int g = L / G;
    if (g * 8 + 8 <= MBr) {
        int r = L - g * G;
        by = g * 8 + (r & 7);
        bx = r >> 3;
    } else {
        by = L / NX;
        bx = L - by * NX;
    }
}

__device__ __forceinline__ float wave_allreduce_max(float v) {
    #pragma unroll
    for (int off = 32; off > 0; off >>= 1) v = fmaxf(v, __shfl_xor(v, off, 64));
    return v;
}
__device__ __forceinline__ float wave_allreduce_sum(float v) {
    #pragma unroll
    for (int off = 32; off > 0; off >>= 1) v += __shfl_xor(v, off, 64);
    return v;
}

// ---- BM=256 x BN=128, BK=32, 8-wave (512 thr) MFMA K-loop, 2-buffer ------------
// (Round-5 verified structure — 2-phase cadence; BN=256 variants correlate with
//  container failures and are abandoned. Do not grow LDS past 48KB or threads
//  past 512 in these GEMMs.)
__device__ __forceinline__ void stage3(const ushort* a0, const ushort* a1, const ushort* b0,
                                       ushort* __restrict__ As, ushort* __restrict__ Bs,
                                       int lb) {
    gl2lds16(a0, As + lb);           // A rows 0..127 of tile
    gl2lds16(a1, As + lb + 4096);    // A rows 128..255
    gl2lds16(b0, Bs + lb);           // B rows 0..127
}

__device__ __forceinline__ void mfma_loop256(const ushort* aA0, const ushort* aA1,
                                             const ushort* aB0,
                                             ushort* __restrict__ As, ushort* __restrict__ Bs,
                                             int lb,
                                             int K, int wr, int wc, int cA, int l15,
                                             f32x4 acc[4][4]) {
    const int BUFA = 256 * 32;         // ushorts per A buffer
    const int BUFB = 128 * 32;         // ushorts per B buffer
    const int nk = K >> 5;
    stage3(aA0, aA1, aB0, As, Bs, lb);                    // S0 -> buf0
    int p = 0;
    for (int t = 0; t < nk; t++) {
        asm volatile("s_waitcnt vmcnt(0)" ::: "memory");
        __builtin_amdgcn_s_barrier();
        __builtin_amdgcn_sched_barrier(0);   // no ds_read may hoist above barrier
        int kn = (t + 1) * 32;
        if (kn < K) stage3(aA0 + kn, aA1 + kn, aB0 + kn,
                           As + (p ^ 1) * BUFA, Bs + (p ^ 1) * BUFB, lb);
        const ushort* Ac = As + p * BUFA;
        const ushort* Bc = Bs + p * BUFB;
        bf16x8 af[4], bf[4];
        #pragma unroll
        for (int i = 0; i < 4; i++)
            af[i] = *reinterpret_cast<const bf16x8*>(&Ac[(wr + i * 16 + l15) * 32 + cA]);
        #pragma unroll
        for (int j = 0; j < 4; j++)
            bf[j] = *reinterpret_cast<const bf16x8*>(&Bc[(wc + j * 16 + l15) * 32 + cA]);
        #pragma unroll
        for (int i = 0; i < 4; i++)
            #pragma unroll
            for (int j = 0; j < 4; j++)
                acc[i][j] = __builtin_amdgcn_mfma_f32_16x16x32_bf16(bf[j], af[i], acc[i][j], 0, 0, 0);
        p ^= 1;
    }
    __syncthreads();   // protect LDS reuse (phase 2 / epilogue)
}

// ============== bf16 MFMA GEMM: C = A[M,K]@B  (B given as BT[Npad,K] bf16) =======
template<int EPI>
__global__ __launch_bounds__(512, 4) void bgemm(const ushort* __restrict__ A,
                                                const ushort* __restrict__ BT,
                                                const float* __restrict__ bias,
                                                void* __restrict__ out, int ldc,
                                                float* __restrict__ Rf,
                                                float* __restrict__ Sf, int Fs,
                                                int M, int Ncols, int K, int lda) {
    __shared__ ushort As[2][256 * 32];
    __shared__ ushort Bs[2][128 * 32];
    const int tid = threadIdx.x;
    int bx, by; xcd_map(bx, by);
    const int m0 = by * 256, n0 = bx * 128;
    const int w = tid >> 6, lane = tid & 63;
    const int wr = (w >> 1) * 64, wc = (w & 1) * 64;
    const int quad = lane >> 4, l15 = lane & 15;
    const int cA = (quad ^ ((l15 >> 1) & 3)) * 8;
    const int lb = w * 512;

    const int r = tid >> 2, g = ((tid & 3) ^ ((tid >> 3) & 3)) * 8;
    int ga0 = m0 + r;       if (ga0 >= M) ga0 = M - 1;
    int ga1 = m0 + 128 + r; if (ga1 >= M) ga1 = M - 1;
    const ushort* aA0 = A + (size_t)ga0 * lda + g;
    const ushort* aA1 = A + (size_t)ga1 * lda + g;
    const ushort* aB0 = BT + (size_t)(n0 + r) * K + g;

    f32x4 acc[4][4] = {};
    mfma_loop256(aA0, aA1, aB0, As[0], Bs[0], lb, K, wr, wc, cA, l15, acc);

    if (EPI == 4) {
        // cols 0..63 valid (B rows 64..127 are zero-padded); wc==64 waves idle.
        if (wc == 0) {
            #pragma unroll
            for (int i = 0; i < 4; i++) {
                float o0 = 0.f, o1 = 0.f;
                #pragma unroll
                for (int j = 0; j < 4; j++) {
                    int colbase = j * 16 + quad * 4;
                    float4 bv = *reinterpret_cast<const float4*>(&bias[colbase]);
                    float bb[4] = { bv.x, bv.y, bv.z, bv.w };
                    #pragma unroll
                    for (int rr = 0; rr < 4; rr++) {
                        float vv = fmaxf(acc[i][j][rr] + bb[rr], 0.f);
                        int c = colbase + rr;
                        o0 += vv * Rf[2 * c];
                        o1 += vv * Rf[2 * c + 1];
                    }
                }
                o0 += __shfl_xor(o0, 16, 64); o0 += __shfl_xor(o0, 32, 64);
                o1 += __shfl_xor(o1, 16, 64); o1 += __shfl_xor(o1, 32, 64);
                int row = m0 + wr + i * 16 + l15;
                if (quad == 0 && row < M) {
                    ((float*)out)[(size_t)row * 2]     = o0 + Sf[0];
                    ((float*)out)[(size_t)row * 2 + 1] = o1 + Sf[1];
                }
            }
        }
        return;
    }

    const int twoH = Ncols - 2 * Fs;
    #pragma unroll
    for (int i = 0; i < 4; i++) {
        int row = m0 + wr + i * 16 + l15;
        if (row >= M) continue;
        #pragma unroll
        for (int j = 0; j < 4; j++) {
            int colbase = n0 + wc + j * 16 + quad * 4;
            if (EPI == 0) {
                f32x4 v = acc[i][j];
                if (bias) {
                    float4 bv = *reinterpret_cast<const float4*>(&bias[colbase]);
                    v[0] += bv.x; v[1] += bv.y; v[2] += bv.z; v[3] += bv.w;
                }
                *reinterpret_cast<f32x4*>(&((float*)out)[(size_t)row * ldc + colbase]) = v;
            } else if (EPI == 5) {
                if (colbase + 3 < Fs) {
                    *reinterpret_cast<uint2*>(&((ushort*)out)[(size_t)row * Fs + colbase]) = pack4(acc[i][j]);
                } else if (colbase >= Fs && colbase + 3 < 2 * Fs) {
                    *reinterpret_cast<f32x4*>(&Rf[(size_t)row * Fs + (colbase - Fs)]) = acc[i][j];
                } else {
                    #pragma unroll
                    for (int rr = 0; rr < 4; rr++) {
                        int col = colbase + rr;
                        if (col < 2 * Fs || col >= Ncols) continue;
                        Sf[(size_t)row * twoH + (col - 2 * Fs)] = acc[i][j][rr];
                    }
                }
            }
        }
    }
}

// ===== fused block-1: H2 = elu(acc_h@W_h + bias1) + h1@res1_w + res1_b (bf16) ====
__global__ __launch_bounds__(512, 4) void bgemm_b1(const ushort* __restrict__ accb,  // N x 1024
                                                   const ushort* __restrict__ w1T,   // 1024 x 256
                                                   const ushort* __restrict__ h1b,   // N x 256
                                                   const ushort* __restrict__ res1T, // 1024 x 256
                                                   const float* __restrict__ bias1,
                                                   const float* __restrict__ res1b,
                                                   ushort* __restrict__ H2b, int M) {
    __shared__ ushort As[2][256 * 32];
    __shared__ ushort Bs[2][128 * 32];
    const int tid = threadIdx.x;
    int bx, by; xcd_map(bx, by);
    const int m0 = by * 256, n0 = bx * 128;
    const int h = n0 >> 8;
    const int w = tid >> 6, lane = tid & 63;
    const int wr = (w >> 1) * 64, wc = (w & 1) * 64;
    const int quad = lane >> 4, l15 = lane & 15;
    const int cA = (quad ^ ((l15 >> 1) & 3)) * 8;
    const int lb = w * 512;

    const int r = tid >> 2, g = ((tid & 3) ^ ((tid >> 3) & 3)) * 8;
    int ga0 = m0 + r;       if (ga0 >= M) ga0 = M - 1;
    int ga1 = m0 + 128 + r; if (ga1 >= M) ga1 = M - 1;

    f32x4 acc[4][4] = {};

    // phase 1: acc_h @ W_h
    mfma_loop256(accb + (size_t)ga0 * 1024 + h * 256 + g,
                 accb + (size_t)ga1 * 1024 + h * 256 + g,
                 w1T + (size_t)(n0 + r) * 256 + g,
                 As[0], Bs[0], lb, 256, wr, wc, cA, l15, acc);

    // in-register: acc = elu(acc + bias1) + res1_b
    #pragma unroll
    for (int i = 0; i < 4; i++) {
        #pragma unroll
        for (int j = 0; j < 4; j++) {
            int colbase = n0 + wc + j * 16 + quad * 4;
            float4 bv = *reinterpret_cast<const float4*>(&bias1[colbase]);
            float4 rv = *reinterpret_cast<const float4*>(&res1b[colbase]);
            float bb[4] = { bv.x, bv.y, bv.z, bv.w };
            float rr[4] = { rv.x, rv.y, rv.z, rv.w };
            #pragma unroll
            for (int q = 0; q < 4; q++) {
                float t = acc[i][j][q] + bb[q];
                t = t > 0.f ? t : (__expf(t) - 1.f);
                acc[i][j][q] = t + rr[q];
            }
        }
    }

    // phase 2: += h1 @ res1_w
    mfma_loop256(h1b + (size_t)ga0 * 256 + g,
                 h1b + (size_t)ga1 * 256 + g,
                 res1T + (size_t)(n0 + r) * 256 + g,
                 As[0], Bs[0], lb, 256, wr, wc, cA, l15, acc);

    #pragma unroll
    for (int i = 0; i < 4; i++) {
        int row = m0 + wr + i * 16 + l15;
        if (row >= M) continue;
        #pragma unroll
        for (int j = 0; j < 4; j++) {
            int colbase = n0 + wc + j * 16 + quad * 4;
            *reinterpret_cast<uint2*>(&H2b[(size_t)row * 1024 + colbase]) = pack4(acc[i][j]);
        }
    }
}

// ---------------- conversions / weight prep ----------------
__global__ void conv_pad_x_kernel(const float* __restrict__ x, ushort* __restrict__ xb, int N) {
    int t = blockIdx.x * 256 + threadIdx.x;
    if (t >= N * 448) return;
    int n = t / 448, k = t - n * 448;
    xb[t] = f2b(k < 405 ? x[(size_t)n * 405 + k] : 0.f);
}

// ---- ALL weight preps + ALL attention folds in ONE launch ----------------------
#define PREP_PB 5135
__device__ __forceinline__ void prep_seg(int t, const float* src, ushort* dst,
                                         int K, int Nreal, int Kpad, int ldsrc) {
    int n = t / Kpad, k = t - n * Kpad;
    float v = (k < K && n < Nreal) ? src[(size_t)k * ldsrc + n] : 0.f;
    dst[t] = f2b(v);
}

__global__ void prep_fold_kernel(const float* __restrict__ enc_w1, const float* __restrict__ enc_w2,
                                 const float* __restrict__ w1, const float* __restrict__ res1_w,
                                 const float* __restrict__ w2, const float* __restrict__ res2_w,
                                 const float* __restrict__ w3, const float* __restrict__ res3_w,
                                 const float* __restrict__ mlp_w1,
                                 const float* __restrict__ att_s1, const float* __restrict__ att_d1,
                                 const float* __restrict__ att_s2, const float* __restrict__ att_d2,
                                 const float* __restrict__ att_s3, const float* __restrict__ att_d3,
                                 ushort* __restrict__ enc_w1T, ushort* __restrict__ enc_w2T,
                                 ushort* __restrict__ w1T, ushort* __restrict__ res1T,
                                 ushort* __restrict__ Bcat2T, ushort* __restrict__ Bcat3T,
                                 ushort* __restrict__ mlpw1T,
                                 float* __restrict__ qs, float* __restrict__ qd) {
    int blk = blockIdx.x;
    if (blk < PREP_PB) {
        int t = blk * 256 + threadIdx.x;
        const int c0 = 114688;            // enc_w1T 256x448
        const int c1 = c0 + 65536;        // enc_w2T 256x256
        const int c2 = c1 + 262144;       // w1T 1024x256
        const int c3 = c2 + 262144;       // res1T 1024x256
        const int c4 = c3 + 196608;       // Bcat2T rows 0-191 (w2)
        const int c5 = c4 + 196608;       // Bcat2T rows 192-383 (res2)
        const int c6 = c5 + 126976;       // Bcat2T rows 388-511 zero
        const int c7 = c6 + 24576;        // Bcat3T rows 0-127 (w3)
        const int c8 = c7 + 24576;        // Bcat3T rows 128-255 (res3)
        const int c9 = c8 + 24192;        // Bcat3T rows 258-383 zero
        const int c10 = c9 + 16384;       // mlpw1T 128x128
        if (t < c0)      prep_seg(t,        enc_w1, enc_w1T, 405, 256, 448, 256);
        else if (t < c1) prep_seg(t - c0,   enc_w2, enc_w2T, 256, 256, 256, 256);
        else if (t < c2) prep_seg(t - c1,   w1,     w1T,     256, 1024, 256, 1024);
        else if (t < c3) prep_seg(t - c2,   res1_w, res1T,   256, 1024, 256, 1024);
        else if (t < c4) prep_seg(t - c3,   w2,     Bcat2T,  1024, 192, 1024, 192);
        else if (t < c5) prep_seg(t - c4,   res2_w, Bcat2T + (size_t)192 * 1024, 1024, 192, 1024, 192);
        else if (t < c6) Bcat2T[(size_t)388 * 1024 + (t - c5)] = 0;
        else if (t < c7) prep_seg(t - c6,   w3,     Bcat3T,  192, 128, 192, 128);
        else if (t < c8) prep_seg(t - c7,   res3_w, Bcat3T + (size_t)128 * 192, 192, 128, 192, 128);
        else if (t < c9) Bcat3T[(size_t)258 * 192 + (t - c8)] = 0;
        else if (t < c10) prep_seg(t - c9,  mlp_w1, mlpw1T,  128, 64, 128, 64);
        return;
    }
    // ---- fold segments: one wave per output element ----
    int fw = (blk - PREP_PB) * 4 + (threadIdx.x >> 6);
    int lane = threadIdx.x & 63;
    if (fw < 1024) {
        // block-1 fold (fp32): t = h*256+k; dot over c<256 of w1[k*1024+h*256+c]*att[h*256+c]
        int h = fw >> 8, k = fw & 255;
        const float* wrow = w1 + (size_t)k * 1024 + h * 256;
        f32x4 wv = *reinterpret_cast<const f32x4*>(&wrow[lane * 4]);
        f32x4 as = *reinterpret_cast<const f32x4*>(&att_s1[h * 256 + lane * 4]);
        f32x4 ad = *reinterpret_cast<const f32x4*>(&att_d1[h * 256 + lane * 4]);
        float ss = wv[0] * as[0] + wv[1] * as[1] + wv[2] * as[2] + wv[3] * as[3];
        float sd = wv[0] * ad[0] + wv[1] * ad[1] + wv[2] * ad[2] + wv[3] * ad[3];
        ss = wave_allreduce_sum(ss);
        sd = wave_allreduce_sum(sd);
        if (lane == 0) { qs[fw] = ss; qd[fw] = sd; }
    } else if (fw < 1024 + 2048) {
        // block-2 fold (bf16 -> Bcat2T rows 384-387): t = h*1024+k; dot over c<96
        int t = fw - 1024;
        int h = t >> 10, k = t & 1023;
        const float* wrow = w2 + (size_t)k * 192 + h * 96;
        const float* as = att_s2 + h * 96;
        const float* ad = att_d2 + h * 96;
        float w0 = wrow[lane];
        float ss = w0 * as[lane], sd = w0 * ad[lane];
        if (lane < 32) {
            float w1v = wrow[64 + lane];
            ss += w1v * as[64 + lane];
            sd += w1v * ad[64 + lane];
        }
        ss = wave_allreduce_sum(ss);
        sd = wave_allreduce_sum(sd);
        if (lane == 0) {
            Bcat2T[(size_t)384 * 1024 + t] = f2b(ss);
            Bcat2T[(size_t)386 * 1024 + t] = f2b(sd);
        }
    } else {
        // block-3 fold (bf16 -> Bcat3T rows 256-257): t = k < 192; dot over c<128
        int t = fw - 3072;
        if (t < 192) {
            const float* wrow = w3 + (size_t)t * 128;
            float w0 = wrow[lane], w1v = wrow[64 + lane];
            float ss = w0 * att_s3[lane] + w1v * att_s3[64 + lane];
            float sd = w0 * att_d3[lane] + w1v * att_d3[64 + lane];
            ss = wave_allreduce_sum(ss);
            sd = wave_allreduce_sum(sd);
            if (lane == 0) {
                Bcat3T[(size_t)256 * 192 + t] = f2b(ss);
                Bcat3T[(size_t)257 * 192 + t] = f2b(sd);
            }
        }
    }
}

// ------- LayerNorm(+ReLU), WAVE-PER-ROW, 2-row ILP: fp32 in, bf16 out; C==256 ---
template<int H>
__global__ __launch_bounds__(256) void ln_relu_w_kernel(const float* __restrict__ x,
                                                        const float* __restrict__ g,
                                                        const float* __restrict__ b,
                                                        const float* __restrict__ qs,
                                                        const float* __restrict__ qd,
                                                        ushort* __restrict__ out,
                                                        float* __restrict__ a_s,
                                                        float* __restrict__ a_d,
                                                        int N) {
    const int lane = threadIdx.x & 63;
    int wid = blockIdx.x * 4 + (threadIdx.x >> 6);
    const int nw = gridDim.x * 4;
    const int c4 = lane * 4;

    f32x4 gv = *reinterpret_cast<const f32x4*>(&g[c4]);
    f32x4 bv = *reinterpret_cast<const f32x4*>(&b[c4]);
    f32x4 qsv[H > 0 ? H : 1], qdv[H > 0 ? H : 1];
    if (H > 0) {
        #pragma unroll
        for (int hh = 0; hh < H; hh++) {
            qsv[hh] = *reinterpret_cast<const f32x4*>(&qs[hh * 256 + c4]);
            qdv[hh] = *reinterpret_cast<const f32x4*>(&qd[hh * 256 + c4]);
        }
    }

    for (int r0 = wid * 2; r0 < N; r0 += 2 * nw) {
        int r1 = r0 + 1;
        bool has1 = r1 < N;
        f32x4 va = *reinterpret_cast<const f32x4*>(&x[(size_t)r0 * 256 + c4]);
        f32x4 vb = has1 ? *reinterpret_cast<const f32x4*>(&x[(size_t)r1 * 256 + c4]) : va;
        float sa  = va[0] + va[1] + va[2] + va[3];
        float s2a = va[0] * va[0] + va[1] * va[1] + va[2] * va[2] + va[3] * va[3];
        float sb  = vb[0] + vb[1] + vb[2] + vb[3];
        float s2b = vb[0] * vb[0] + vb[1] * vb[1] + vb[2] * vb[2] + vb[3] * vb[3];
        #pragma unroll
        for (int off = 32; off > 0; off >>= 1) {
            sa  += __shfl_xor(sa,  off, 64);
            sb  += __shfl_xor(sb,  off, 64);
            s2a += __shfl_xor(s2a, off, 64);
            s2b += __shfl_xor(s2b, off, 64);
        }
        float ma  = sa * (1.f / 256.f);
        float mb  = sb * (1.f / 256.f);
        float rsa = rsqrtf(s2a * (1.f / 256.f) - ma * ma + LN_EPS);
        float rsb = rsqrtf(s2b * (1.f / 256.f) - mb * mb + LN_EPS);
        f32x4 oa, ob;
        #pragma unroll
        for (int k = 0; k < 4; k++) {
            oa[k] = fmaxf((va[k] - ma) * rsa * gv[k] + bv[k], 0.f);
            ob[k] = fmaxf((vb[k] - mb) * rsb * gv[k] + bv[k], 0.f);
        }
        *reinterpret_cast<uint2*>(&out[(size_t)r0 * 256 + c4]) =
            make_uint2(pack2(oa[0], oa[1]), pack2(oa[2], oa[3]));
        if (has1)
            *reinterpret_cast<uint2*>(&out[(size_t)r1 * 256 + c4]) =
                make_uint2(pack2(ob[0], ob[1]), pack2(ob[2], ob[3]));
        if (H > 0) {
            float sc[H > 0 ? 4 * H : 1];
            #pragma unroll
            for (int hh = 0; hh < H; hh++) {
                sc[hh]           = oa[0] * qsv[hh][0] + oa[1] * qsv[hh][1] + oa[2] * qsv[hh][2] + oa[3] * qsv[hh][3];
                sc[H + hh]       = oa[0] * qdv[hh][0] + oa[1] * qdv[hh][1] + oa[2] * qdv[hh][2] + oa[3] * qdv[hh][3];
                sc[2 * H + hh]   = ob[0] * qsv[hh][0] + ob[1] * qsv[hh][1] + ob[2] * qsv[hh][2] + ob[3] * qsv[hh][3];
                sc[3 * H + hh]   = ob[0] * qdv[hh][0] + ob[1] * qdv[hh][1] + ob[2] * qdv[hh][2] + ob[3] * qdv[hh][3];
            }
            #pragma unroll
            for (int off = 32; off > 0; off >>= 1)
                #pragma unroll
                for (int k = 0; k < 4 * H; k++) sc[k] += __shfl_xor(sc[k], off, 64);
            if (lane == 0) {
                #pragma unroll
                for (int k = 0; k < H; k++) a_s[(size_t)r0 * H + k] = sc[k];
                if (has1)
                    #pragma unroll
                    for (int k = 0; k < H; k++) a_s[(size_t)r1 * H + k] = sc[2 * H + k];
            } else if (lane == 1) {
                #pragma unroll
                for (int k = 0; k < H; k++) a_d[(size_t)r0 * H + k] = sc[H + k];
                if (has1)
                    #pragma unroll
                    for (int k = 0; k < H; k++) a_d[(size_t)r1 * H + k] = sc[3 * H + k];
            }
        }
    }
}

// ================= CSR construction (dst-grouped) =========
__device__ __forceinline__ void edge_sd(const int* ei, int e, int E, int& s, int& d) {
    if (e < E) { s = ei[e]; d = ei[E + e]; } else { s = d = e - E; }
}

__global__ void deg_kernel(const int* __restrict__ ei, int* __restrict__ deg, int E, int Et) {
    int e = blockIdx.x * blockDim.x + threadIdx.x;
    if (e >= Et) return;
    int s, d; edge_sd(ei, e, E, s, d);
    atomicAdd(&deg[d], 1);
}

__global__ __launch_bounds__(256) void scan1_kernel(const int* __restrict__ deg,
                                                    int* __restrict__ incl,
                                                    int* __restrict__ part, int N) {
    __shared__ int sd[256];
    int t = threadIdx.x;
    int i = blockIdx.x * 256 + t;
    int v = (i < N) ? deg[i] : 0;
    sd[t] = v; __syncthreads();
    #pragma unroll
    for (int o = 1; o < 256; o <<= 1) {
        int x = (t >= o) ? sd[t - o] : 0;
        __syncthreads();
        sd[t] += x;
        __syncthreads();
    }
    if (i < N) incl[i] = sd[t];
    if (t == 255) part[blockIdx.x] = sd[255];
}

__global__ __launch_bounds__(256) void scan2_kernel(int* __restrict__ part, int nb) {
    __shared__ int sd[256];
    int t = threadIdx.x;
    int v = (t < nb) ? part[t] : 0;
    sd[t] = v; __syncthreads();
    #pragma unroll
    for (int o = 1; o < 256; o <<= 1) {
        int x = (t >= o) ? sd[t - o] : 0;
        __syncthreads();
        sd[t] += x;
        __syncthreads();
    }
    if (t < nb) part[t] = sd[t];
}

__global__ void scan3_kernel(const int* __restrict__ incl, const int* __restrict__ deg,
                             const int* __restrict__ part, int* __restrict__ row_ptr, int N) {
    int i = blockIdx.x * blockDim.x + threadIdx.x;
    if (i >= N) return;
    int off = (blockIdx.x > 0) ? part[blockIdx.x - 1] : 0;
    row_ptr[i] = incl[i] - deg[i] + off;
}

__global__ void fill_kernel(const int* __restrict__ ei, const int* __restrict__ row_ptr,
                            int* __restrict__ cur, int* __restrict__ csr_src, int E, int Et) {
    int e = blockIdx.x * blockDim.x + threadIdx.x;
    if (e >= Et) return;
    int s, d; edge_sd(ei, e, E, s, d);
    int pos = row_ptr[d] + atomicAdd(&cur[d], 1);
    csr_src[pos] = s;
}

// Max per-dst edges cached in LDS by the fused stats+aggr kernels; degrees above
// this fall back to on-the-fly alpha recompute (random graph max-deg ~40 << 256).
#define ACAP 256

// ==== block1: FUSED softmax-stats + gather-aggregate (all 4 heads) ==============
// Stats split across BOTH waves (wave0: heads 0-1, wave1: heads 2-3) — halves the
// serial leaky-relu/exp chain vs the single-wave version. alf/sstat writes are
// per-wave disjoint; gather phase unchanged.
__global__ __launch_bounds__(128) void aggr_b1_fused_kernel(const int* __restrict__ row_ptr,
                                                            const int* __restrict__ deg,
                                                            const int* __restrict__ csr_src,
                                                            const float* __restrict__ a_s,
                                                            const float* __restrict__ a_d,
                                                            const ushort* __restrict__ h1b,
                                                            ushort* __restrict__ accb) {
    __shared__ float alf[ACAP][4];
    __shared__ float sstat[8];     // mx[0..3], rd[4..7]
    int d = blockIdx.x, t = threadIdx.x;
    int base = row_ptr[d], dg = deg[d];
    float4 ad = *reinterpret_cast<const float4*>(&a_d[(size_t)d * 4]);
    {
        const int hb = (t >> 6) * 2;       // head base: wave0 -> 0, wave1 -> 2
        const int l = t & 63;
        const float ad0 = hb ? ad.z : ad.x;
        const float ad1 = hb ? ad.w : ad.y;
        float m0 = -1e30f, m1 = -1e30f;
        for (int j = l; j < dg; j += 64) {
            int s = csr_src[base + j];
            float2 sv = *reinterpret_cast<const float2*>(&a_s[(size_t)s * 4 + hb]);
            float c0 = sv.x + ad0; c0 = c0 > 0.f ? c0 : 0.2f * c0; m0 = fmaxf(m0, c0);
            float c1 = sv.y + ad1; c1 = c1 > 0.f ? c1 : 0.2f * c1; m1 = fmaxf(m1, c1);
        }
        m0 = wave_allreduce_max(m0); m1 = wave_allreduce_max(m1);
        float s0 = 0.f, s1 = 0.f;
        for (int j = l; j < dg; j += 64) {
            int s = csr_src[base + j];
            float2 sv = *reinterpret_cast<const float2*>(&a_s[(size_t)s * 4 + hb]);
            float c0 = sv.x + ad0; c0 = c0 > 0.f ? c0 : 0.2f * c0; float e0 = __expf(c0 - m0); s0 += e0;
            float c1 = sv.y + ad1; c1 = c1 > 0.f ? c1 : 0.2f * c1; float e1 = __expf(c1 - m1); s1 += e1;
            if (j < ACAP) { alf[j][hb] = e0; alf[j][hb + 1] = e1; }
        }
        s0 = wave_allreduce_sum(s0); s1 = wave_allreduce_sum(s1);
        if (l == 0) {
            sstat[hb] = m0; sstat[hb + 1] = m1;
            sstat[4 + hb] = 1.f / (s0 + 1e-16f); sstat[5 + hb] = 1.f / (s1 + 1e-16f);
        }
    }
    __syncthreads();
    float r0 = sstat[4], r1 = sstat[5], r2 = sstat[6], r3 = sstat[7];
    float a00 = 0, a01 = 0, a10 = 0, a11 = 0, a20 = 0, a21 = 0, a30 = 0, a31 = 0;

    auto alpha4 = [&](int j, int s, float& al0, float& al1, float& al2, float& al3) {
        if (j < ACAP) {
            al0 = alf[j][0] * r0; al1 = alf[j][1] * r1;
            al2 = alf[j][2] * r2; al3 = alf[j][3] * r3;
        } else {
            float4 sv = *reinterpret_cast<const float4*>(&a_s[(size_t)s * 4]);
            float c0 = sv.x + ad.x; c0 = c0 > 0.f ? c0 : 0.2f * c0; al0 = __expf(c0 - sstat[0]) * r0;
            float c1 = sv.y + ad.y; c1 = c1 > 0.f ? c1 : 0.2f * c1; al1 = __expf(c1 - sstat[1]) * r1;
            float c2 = sv.z + ad.z; c2 = c2 > 0.f ? c2 : 0.2f * c2; al2 = __expf(c2 - sstat[2]) * r2;
            float c3 = sv.w + ad.w; c3 = c3 > 0.f ? c3 : 0.2f * c3; al3 = __expf(c3 - sstat[3]) * r3;
        }
    };
    int j = 0;
    for (; j + 2 <= dg; j += 2) {
        int s0i = csr_src[base + j], s1i = csr_src[base + j + 1];
        unsigned v0 = reinterpret_cast<const unsigned*>(h1b + (size_t)s0i * 256)[t];
        unsigned v1 = reinterpret_cast<const unsigned*>(h1b + (size_t)s1i * 256)[t];
        float x0, x1, x2, x3, y0, y1, y2, y3;
        alpha4(j, s0i, x0, x1, x2, x3);
        alpha4(j + 1, s1i, y0, y1, y2, y3);
        float lo0 = b2f((ushort)(v0 & 0xffff)), hi0 = b2f((ushort)(v0 >> 16));
        float lo1 = b2f((ushort)(v1 & 0xffff)), hi1 = b2f((ushort)(v1 >> 16));
        a00 += x0 * lo0 + y0 * lo1; a01 += x0 * hi0 + y0 * hi1;
        a10 += x1 * lo0 + y1 * lo1; a11 += x1 * hi0 + y1 * hi1;
        a20 += x2 * lo0 + y2 * lo1; a21 += x2 * hi0 + y2 * hi1;
        a30 += x3 * lo0 + y3 * lo1; a31 += x3 * hi0 + y3 * hi1;
    }
    if (j < dg) {
        int s0i = csr_src[base + j];
        unsigned v0 = reinterpret_cast<const unsigned*>(h1b + (size_t)s0i * 256)[t];
        float x0, x1, x2, x3;
        alpha4(j, s0i, x0, x1, x2, x3);
        float lo0 = b2f((ushort)(v0 & 0xffff)), hi0 = b2f((ushort)(v0 >> 16));
        a00 += x0 * lo0; a01 += x0 * hi0;
        a10 += x1 * lo0; a11 += x1 * hi0;
        a20 += x2 * lo0; a21 += x2 * hi0;
        a30 += x3 * lo0; a31 += x3 * hi0;
    }
    unsigned* o = reinterpret_cast<unsigned*>(accb + (size_t)d * 1024);
    o[t]       = pack2(a00, a01);
    o[t + 128] = pack2(a10, a11);
    o[t + 256] = pack2(a20, a21);
    o[t + 384] = pack2(a30, a31);
}

// ==== blocks 2/3: FUSED stats + gather-aggregate + elu/residual epilogue ========
template<int H, int C, int F, int NT>
__global__ __launch_bounds__(NT) void aggr_comb_fused_kernel(const int* __restrict__ row_ptr,
                                                             const int* __restrict__ deg,
                                                             const int* __restrict__ csr_src,
                                                             const float* __restrict__ as,
                                                             const ushort* __restrict__ g,
                                                             const float* __restrict__ Rf,
                                                             const float* __restrict__ gb,
                                                             const float* __restrict__ rb,
                                                             ushort* __restrict__ outb) {
    __shared__ float alf[ACAP][H];
    __shared__ float sstat[2 * H];   // mx[0..H), rd[H..2H)
    int d = blockIdx.x;
    int t = threadIdx.x;               // 0..F/2-1
    int base = row_ptr[d], dg = deg[d];
    if (t < 64) {
        float ad[H], mx[H];
        #pragma unroll
        for (int h = 0; h < H; h++) { ad[h] = as[(size_t)d * 2 * H + H + h]; mx[h] = -1e30f; }
        for (int j = t; j < dg; j += 64) {
            int s = csr_src[base + j];
            #pragma unroll
            for (int h = 0; h < H; h++) {
                float c = as[(size_t)s * 2 * H + h] + ad[h];
                c = c > 0.f ? c : 0.2f * c;
                mx[h] = fmaxf(mx[h], c);
            }
        }
        #pragma unroll
        for (int h = 0; h < H; h++) mx[h] = wave_allreduce_max(mx[h]);
        float sm[H];
        #pragma unroll
        for (int h = 0; h < H; h++) sm[h] = 0.f;
        for (int j = t; j < dg; j += 64) {
            int s = csr_src[base + j];
            #pragma unroll
            for (int h = 0; h < H; h++) {
                float c = as[(size_t)s * 2 * H + h] + ad[h];
                c = c > 0.f ? c : 0.2f * c;
                float e = __expf(c - mx[h]);
                sm[h] += e;
                if (j < ACAP) alf[j][h] = e;
            }
        }
        #pragma unroll
        for (int h = 0; h < H; h++) sm[h] = wave_allreduce_sum(sm[h]);
        if (t == 0) {
            #pragma unroll
            for (int h = 0; h < H; h++) { sstat[h] = mx[h]; sstat[H + h] = 1.f / (sm[h] + 1e-16f); }
        }
    }
    __syncthreads();
    int hd = (2 * t) / C;
    float mxv = sstat[hd], rdv = sstat[H + hd];
    float adv = as[(size_t)d * 2 * H + H + hd];
    float lo = 0.f, hi = 0.f;
    auto alpha1 = [&](int j, int s) -> float {
        if (j < ACAP) return alf[j][hd] * rdv;
        float c = as[(size_t)s * 2 * H + hd] + adv;
        c = c > 0.f ? c : 0.2f * c;
        return __expf(c - mxv) * rdv;
    };
    int j = 0;
    for (; j + 2 <= dg; j += 2) {
        int s0 = csr_src[base + j], s1 = csr_src[base + j + 1];
        unsigned v0 = reinterpret_cast<const unsigned*>(g + (size_t)s0 * F)[t];
        unsigned v1 = reinterpret_cast<const unsigned*>(g + (size_t)s1 * F)[t];
        float al0 = alpha1(j, s0), al1 = alpha1(j + 1, s1);
        lo += al0 * b2f((ushort)(v0 & 0xffff)) + al1 * b2f((ushort)(v1 & 0xffff));
        hi += al0 * b2f((ushort)(v0 >> 16))    + al1 * b2f((ushort)(v1 >> 16));
    }
    if (j < dg) {
        int s0 = csr_src[base + j];
        unsigned v0 = reinterpret_cast<const unsigned*>(g + (size_t)s0 * F)[t];
        float al0 = alpha1(j, s0);
        lo += al0 * b2f((ushort)(v0 & 0xffff));
        hi += al0 * b2f((ushort)(v0 >> 16));
    }
    int c0 = 2 * t, c1 = 2 * t + 1;
    float o0 = lo + gb[c0]; o0 = o0 > 0.f ? o0 : (__expf(o0) - 1.f);
    float o1 = hi + gb[c1]; o1 = o1 > 0.f ? o1 : (__expf(o1) - 1.f);
    o0 += Rf[(size_t)d * F + c0] + rb[c0];
    o1 += Rf[(size_t)d * F + c1] + rb[c1];
    reinterpret_cast<unsigned*>(outb)[(size_t)d * (F / 2) + t] = pack2(o0, o1);
}

extern "C" void kernel_launch(void* const* d_in, const int* in_sizes, int n_in,
                              void* d_out, int out_size, void* d_ws, size_t ws_size,
                              hipStream_t stream) {
    const float* x        = (const float*)d_in[0];
    const int*   ei       = (const int*)d_in[1];
    const float* enc_w1   = (const float*)d_in[2];
    const float* enc_b1   = (const float*)d_in[3];
    const float* ln1_g    = (const float*)d_in[4];
    const float* ln1_b    = (const float*)d_in[5];
    const float* enc_w2   = (const float*)d_in[6];
    const float* enc_b2   = (const float*)d_in[7];
    const float* ln2_g    = (const float*)d_in[8];
    const float* ln2_b    = (const float*)d_in[9];
    const float* w1       = (const float*)d_in[10];
    const float* att_src1 = (const float*)d_in[11];
    const float* att_dst1 = (const float*)d_in[12];
    const float* bias1    = (const float*)d_in[13];
    const float* res1_w   = (const float*)d_in[14];
    const float* res1_b   = (const float*)d_in[15];
    const float* w2       = (const float*)d_in[16];
    const float* att_src2 = (const float*)d_in[17];
    const float* att_dst2 = (const float*)d_in[18];
    const float* bias2    = (const float*)d_in[19];
    const float* res2_w   = (const float*)d_in[20];
    const float* res2_b   = (const float*)d_in[21];
    const float* w3       = (const float*)d_in[22];
    const float* att_src3 = (const float*)d_in[23];
    const float* att_dst3 = (const float*)d_in[24];
    const float* bias3    = (const float*)d_in[25];
    const float* res3_w   = (const float*)d_in[26];
    const float* res3_b   = (const float*)d_in[27];
    const float* mlp_w1   = (const float*)d_in[28];
    const float* mlp_b1   = (const float*)d_in[29];
    const float* mlp_w2   = (const float*)d_in[30];
    const float* mlp_b2   = (const float*)d_in[31];

    const int N  = in_sizes[0] / 405;   // 50000
    const int E  = in_sizes[1] / 2;     // 300000
    const int Et = E + N;
    const int NB = (N + 255) / 256;

    // ---------- workspace layout (bytes) ----------
    char* p = (char*)d_ws;
    char* R0 = p;                       // N*896 B : xb(448 b16) | H3b(b16 192)
    char* R1 = R0 + (size_t)N * 896;    // N*512 B : h0b | G2b
    char* R2 = R1 + (size_t)N * 512;    // N*512 B : h1b | G3b , H4b(@+N*256B)
    char* R3 = R2 + (size_t)N * 512;    // N*2048 B: F1(f32 256) | H2b(b16 1024)
    char* R4 = R3 + (size_t)N * 2048;   // N*2048 B: accb(b16 1024) | Rf(f32 192/128)
    char* T  = R4 + (size_t)N * 2048;   // tail

    ushort* xb   = (ushort*)R0;
    ushort* H3b  = (ushort*)R0;          // lives after xb is dead (enc1 done)
    ushort* h0b  = (ushort*)R1;
    ushort* G2b  = (ushort*)R1;
    ushort* h1b  = (ushort*)R2;
    ushort* G3b  = (ushort*)R2;
    ushort* H4b  = (ushort*)(R2 + (size_t)N * 256);
    float*  F1   = (float*)R3;
    ushort* H2b  = (ushort*)R3;
    ushort* accb = (ushort*)R4;
    float*  Rf   = (float*)R4;

    float* a_s   = (float*)T;                         T += (size_t)N * 4 * 4;   // also Sf2/Sf3
    float* a_d   = (float*)T;                         T += (size_t)N * 4 * 4;
    float* qs    = (float*)T;                         T += 2048 * 4;
    float* qd    = (float*)T;                         T += 2048 * 4;
    int* deg     = (int*)T;                           T += (size_t)N * 4;
    int* cur     = (int*)T;                           T += (size_t)N * 4;
    int* row_ptr = (int*)T;                           T += (size_t)N * 4;
    int* incl    = (int*)T;                           T += (size_t)N * 4;
    int* part    = (int*)T;                           T += 256 * 4;
    int* csr_src = (int*)T;                           T += (size_t)Et * 4;
    ushort* enc_w1T = (ushort*)T;                     T += (size_t)256 * 448 * 2;
    ushort* enc_w2T = (ushort*)T;                     T += (size_t)256 * 256 * 2;
    ushort* w1T     = (ushort*)T;                     T += (size_t)1024 * 256 * 2;
    ushort* res1T   = (ushort*)T;                     T += (size_t)1024 * 256 * 2;
    ushort* Bcat2T  = (ushort*)T;                     T += (size_t)512 * 1024 * 2;
    ushort* Bcat3T  = (ushort*)T;                     T += (size_t)384 * 192 * 2;
    ushort* mlpw1T  = (ushort*)T;                     T += (size_t)128 * 128 * 2;

    auto cdiv = [](int a, int b) { return (a + b - 1) / b; };
    const int MBr = cdiv(N, 256);      // 256-row blocks for all MFMA GEMMs

    // ---- CSR build ----
    (void)hipMemsetAsync(deg, 0, (size_t)N * 8, stream);   // deg + cur
    deg_kernel<<<cdiv(Et, 256), 256, 0, stream>>>(ei, deg, E, Et);
    scan1_kernel<<<NB, 256, 0, stream>>>(deg, incl, part, N);
    scan2_kernel<<<1, 256, 0, stream>>>(part, NB);
    scan3_kernel<<<NB, 256, 0, stream>>>(incl, deg, part, row_ptr, N);
    fill_kernel<<<cdiv(Et, 256), 256, 0, stream>>>(ei, row_ptr, cur, csr_src, E, Et);

    // ---- weight prep + ALL attention folds: ONE launch ----
    // fold waves: 1024 (b1, fp32 qs/qd) + 2048 (b2 -> Bcat2T rows 384-387)
    //           + 192 (b3 -> Bcat3T rows 256-257) = 3264 waves = 816 blocks
    prep_fold_kernel<<<PREP_PB + 816, 256, 0, stream>>>(
        enc_w1, enc_w2, w1, res1_w, w2, res2_w, w3, res3_w, mlp_w1,
        att_src1, att_dst1, att_src2, att_dst2, att_src3, att_dst3,
        enc_w1T, enc_w2T, w1T, res1T, Bcat2T, Bcat3T, mlpw1T, qs, qd);

    // ---- JointEncoder ----
    conv_pad_x_kernel<<<cdiv(N * 448, 256), 256, 0, stream>>>(x, xb, N);
    bgemm<0><<<dim3(2, MBr), 512, 0, stream>>>(xb, enc_w1T, enc_b1, F1, 256, nullptr, nullptr, 0, N, 256, 448, 448);
    ln_relu_w_kernel<0><<<2048, 256, 0, stream>>>(F1, ln1_g, ln1_b, nullptr, nullptr, h0b, nullptr, nullptr, N);
    bgemm<0><<<dim3(2, MBr), 512, 0, stream>>>(h0b, enc_w2T, enc_b2, F1, 256, nullptr, nullptr, 0, N, 256, 256, 256);
    // LN2 + fused block-1 attention scores (fp32, wave-per-row, 2-row ILP)
    ln_relu_w_kernel<4><<<2048, 256, 0, stream>>>(F1, ln2_g, ln2_b, qs, qd, h1b, a_s, a_d, N);

    // ---- Block 1: GAT 256 -> 4x256 concat (fused stats+aggr, fused head GEMMs) --
    aggr_b1_fused_kernel<<<N, 128, 0, stream>>>(row_ptr, deg, csr_src, a_s, a_d, h1b, accb);
    bgemm_b1<<<dim3(8, MBr), 512, 0, stream>>>(accb, w1T, h1b, res1T, bias1, res1_b, H2b, N);

    // ---- Block 2: GAT 1024 -> 2x96 concat (G/R/scores in one split-epilogue GEMM)
    {
        // cols: [0,192)=G2b bf16, [192,384)=Rf fp32, [384,388)=scores -> a_s[N,4]
        bgemm<5><<<dim3(4, MBr), 512, 0, stream>>>(H2b, Bcat2T, nullptr, G2b, 0, Rf, a_s, 192, N, 388, 1024, 1024);
        // H3b (R0) does NOT alias G2b (R1) -> fused gather+epilogue is safe
        aggr_comb_fused_kernel<2, 96, 192, 96><<<N, 96, 0, stream>>>(row_ptr, deg, csr_src, a_s,
                                                                     G2b, Rf, bias2, res2_b, H3b);
    }

    // ---- Block 3: GAT 192 -> 1x128 (no concat) ----
    {
        // cols: [0,128)=G3b bf16, [128,256)=Rf fp32, [256,258)=scores -> a_s[N,2]
        bgemm<5><<<dim3(3, MBr), 512, 0, stream>>>(H3b, Bcat3T, nullptr, G3b, 0, Rf, a_s, 128, N, 258, 192, 192);
        // H4b (R2 + N*256B) does NOT alias G3b (R2, N*256B) -> safe
        aggr_comb_fused_kernel<1, 128, 128, 64><<<N, 64, 0, stream>>>(row_ptr, deg, csr_src, a_s,
                                                                      G3b, Rf, bias3, res3_b, H4b);
    }

    // ---- MLP head: relu(H4b@mlp_w1+b1)@mlp_w2+b2 fused into ONE GEMM epilogue ---
    bgemm<4><<<dim3(1, MBr), 512, 0, stream>>>(H4b, mlpw1T, mlp_b1, d_out, 2,
                                               (float*)mlp_w2, (float*)mlp_b2, 0, N, 64, 128, 128);
}